// Round 2
// baseline (2937.594 us; speedup 1.0000x reference)
//
#include <hip/hip_runtime.h>
#include <hip/hip_bf16.h>

#define N_NODES 50000
#define N_EDGES 1600000
#define N_GRAPHS 16
#define K_SLOTS 8
#define LATENT 4
#define HID 32

typedef __hip_bfloat16 bf16;

__device__ __forceinline__ float b2f(bf16 v) { return __bfloat162float(v); }

// dtype-agnostic loads (flag is wave-uniform)
__device__ __forceinline__ float ldf(const void* p, long i, int isbf) {
    return isbf ? __bfloat162float(((const bf16*)p)[i]) : ((const float*)p)[i];
}
__device__ __forceinline__ int ldi(const int* p, long i, int is64) {
    return is64 ? p[2 * i] : p[i];
}

// ---- workspace layout (float32 elements) ----
#define WS_HSUM 0                                      // N*32 (edge-sum, then normalized h)
#define WS_CNT  (N_NODES * HID)                        // N
#define WS_S    (WS_CNT + N_NODES)                     // N*8
#define WS_POOL (WS_S + N_NODES * K_SLOTS)             // 16*8*32 = 4096
#define WS_Z    (WS_POOL + N_GRAPHS * K_SLOTS * HID)   // 16*8*4 = 512
#define WS_TOTAL (WS_Z + N_GRAPHS * K_SLOTS * LATENT)
// flags live right after (2 ints)

// ---------------- dtype detection ----------------
__global__ void detect_kernel(const void* x, const int* ei, int* flags) {
    if (threadIdx.x == 0) {
        const unsigned short* u = (const unsigned short*)x;
        int sane = 0;
        for (int j = 0; j < 64; j++) {
            unsigned short h = u[2 * j];       // low half of word j
            unsigned e = (h >> 7) & 0xFF;
            if ((h & 0x7FFF) == 0 || (e >= 100 && e <= 141)) sane++;
        }
        flags[0] = (sane >= 32) ? 1 : 0;       // 1: floats are bf16, 0: f32
        int zeros = 0;
        for (int j = 0; j < 64; j++) if (ei[2 * j + 1] == 0) zeros++;
        flags[1] = (zeros >= 60) ? 1 : 0;      // 1: ints are int64, 0: int32
    }
}

// ---------------- edge message + scatter-sum ----------------
__global__ __launch_bounds__(256) void edge_kernel(
    const void* __restrict__ x, const void* __restrict__ pos,
    const int* __restrict__ ei,
    const void* __restrict__ w1, const void* __restrict__ b1,
    const void* __restrict__ w2, const void* __restrict__ b2,
    float* __restrict__ hsum, float* __restrict__ cnt,
    const int* __restrict__ flags)
{
    const int fbf = flags[0], i64 = flags[1];
    __shared__ float sw1[9 * HID], sb1[HID], sw2[HID * HID], sb2[HID];
    for (int i = threadIdx.x; i < 9 * HID; i += 256) sw1[i] = ldf(w1, i, fbf);
    for (int i = threadIdx.x; i < HID * HID; i += 256) sw2[i] = ldf(w2, i, fbf);
    if (threadIdx.x < HID) {
        sb1[threadIdx.x] = ldf(b1, threadIdx.x, fbf);
        sb2[threadIdx.x] = ldf(b2, threadIdx.x, fbf);
    }
    __syncthreads();

    int e = blockIdx.x * 256 + threadIdx.x;
    if (e >= N_EDGES) return;
    int src = ldi(ei, e, i64);
    int dst = ldi(ei, (long)N_EDGES + e, i64);

    float in[9];
#pragma unroll
    for (int i = 0; i < 4; i++) in[i] = ldf(x, (long)dst * 4 + i, fbf);      // x_i
#pragma unroll
    for (int i = 0; i < 4; i++) in[4 + i] = ldf(x, (long)src * 4 + i, fbf);  // x_j
    float dx = ldf(pos, (long)src * 3 + 0, fbf) - ldf(pos, (long)dst * 3 + 0, fbf);
    float dy = ldf(pos, (long)src * 3 + 1, fbf) - ldf(pos, (long)dst * 3 + 1, fbf);
    float dz = ldf(pos, (long)src * 3 + 2, fbf) - ldf(pos, (long)dst * 3 + 2, fbf);
    in[8] = sqrtf(dx * dx + dy * dy + dz * dz);

    float h1[HID];
#pragma unroll
    for (int j = 0; j < HID; j++) h1[j] = sb1[j];
#pragma unroll
    for (int i = 0; i < 9; i++) {
        float v = in[i];
#pragma unroll
        for (int j = 0; j < HID; j++) h1[j] = fmaf(v, sw1[i * HID + j], h1[j]);
    }
#pragma unroll
    for (int j = 0; j < HID; j++) h1[j] = h1[j] / (1.f + __expf(-h1[j]));  // silu

    float m[HID];
#pragma unroll
    for (int j = 0; j < HID; j++) m[j] = sb2[j];
#pragma unroll
    for (int i = 0; i < HID; i++) {
        float v = h1[i];
#pragma unroll
        for (int j = 0; j < HID; j++) m[j] = fmaf(v, sw2[i * HID + j], m[j]);
    }

    float* hs = hsum + (size_t)dst * HID;
#pragma unroll
    for (int j = 0; j < HID; j++) atomicAdd(hs + j, m[j]);
    atomicAdd(cnt + dst, 1.0f);
}

// ---------------- normalize (scatter-mean) + pool softmax ----------------
__global__ __launch_bounds__(256) void node_kernel(
    float* __restrict__ hsum, const float* __restrict__ cnt,
    const void* __restrict__ pw, const void* __restrict__ pb,
    float* __restrict__ s, const int* __restrict__ flags)
{
    const int fbf = flags[0];
    __shared__ float spw[HID * K_SLOTS], spb[K_SLOTS];
    for (int i = threadIdx.x; i < HID * K_SLOTS; i += 256) spw[i] = ldf(pw, i, fbf);
    if (threadIdx.x < K_SLOTS) spb[threadIdx.x] = ldf(pb, threadIdx.x, fbf);
    __syncthreads();

    int n = blockIdx.x * 256 + threadIdx.x;
    if (n >= N_NODES) return;
    float inv = 1.f / fmaxf(cnt[n], 1.f);
    float h[HID];
#pragma unroll
    for (int j = 0; j < HID; j++) {
        float v = hsum[(size_t)n * HID + j] * inv;
        h[j] = v;
        hsum[(size_t)n * HID + j] = v;  // store normalized h in place
    }
    float l[K_SLOTS];
#pragma unroll
    for (int k = 0; k < K_SLOTS; k++) l[k] = spb[k];
#pragma unroll
    for (int j = 0; j < HID; j++) {
        float v = h[j];
#pragma unroll
        for (int k = 0; k < K_SLOTS; k++) l[k] = fmaf(v, spw[j * K_SLOTS + k], l[k]);
    }
    float mx = l[0];
#pragma unroll
    for (int k = 1; k < K_SLOTS; k++) mx = fmaxf(mx, l[k]);
    float sum = 0.f;
#pragma unroll
    for (int k = 0; k < K_SLOTS; k++) { l[k] = __expf(l[k] - mx); sum += l[k]; }
    float is = 1.f / sum;
#pragma unroll
    for (int k = 0; k < K_SLOTS; k++) s[(size_t)n * K_SLOTS + k] = l[k] * is;
}

// ---------------- soft pooling: pooled[b,k,c] = sum_n s[n,k]*h[n,c] ----------------
__global__ __launch_bounds__(256) void pool_kernel(
    const float* __restrict__ h, const float* __restrict__ s,
    const int* __restrict__ batch, float* __restrict__ pooled,
    const int* __restrict__ flags)
{
    const int i64 = flags[1];
    __shared__ float hL[256 * HID];      // 32 KB
    __shared__ float sL[256 * K_SLOTS];  // 8 KB
    __shared__ int gL[256];
    int n0 = blockIdx.x * 256;
    for (int i = threadIdx.x; i < 256 * HID; i += 256) {
        int n = n0 + i / HID;
        hL[i] = (n < N_NODES) ? h[(size_t)n0 * HID + i] : 0.f;
    }
    for (int i = threadIdx.x; i < 256 * K_SLOTS; i += 256) {
        int n = n0 + i / K_SLOTS;
        sL[i] = (n < N_NODES) ? s[(size_t)n0 * K_SLOTS + i] : 0.f;
    }
    {
        int n = n0 + threadIdx.x;
        gL[threadIdx.x] = ldi(batch, n < N_NODES ? n : (N_NODES - 1), i64);
    }
    __syncthreads();

    int t = threadIdx.x;
    int k = t >> 5, c = t & 31;
    float acc = 0.f;
    int curg = gL[0];
    int lim = min(256, N_NODES - n0);
    for (int i = 0; i < lim; i++) {
        int g = gL[i];                       // wave-uniform
        if (g != curg) {
            atomicAdd(&pooled[curg * 256 + t], acc);
            acc = 0.f;
            curg = g;
        }
        acc = fmaf(sL[i * K_SLOTS + k], hL[i * HID + c], acc);
    }
    atomicAdd(&pooled[curg * 256 + t], acc);
}

// ---------------- z = pooled @ toz_w + toz_b  (tiny) ----------------
__global__ __launch_bounds__(512) void z_kernel(
    const float* __restrict__ pooled, const void* __restrict__ tw,
    const void* __restrict__ tb, float* __restrict__ z,
    const int* __restrict__ flags)
{
    const int fbf = flags[0];
    int t = threadIdx.x;           // 512 = 16*8*4
    int d = t & 3;
    int k = (t >> 2) & 7;
    int b = t >> 5;
    float acc = ldf(tb, d, fbf);
    for (int c = 0; c < HID; c++)
        acc = fmaf(pooled[b * 256 + k * 32 + c], ldf(tw, c * 4 + d, fbf), acc);
    z[t] = acc;                    // layout [B][K][4], flat idx == t
}

// ---------------- decode: q=s@z -> silu MLP -> out ----------------
__global__ __launch_bounds__(256) void decode_kernel(
    const float* __restrict__ s, const float* __restrict__ z,
    const void* __restrict__ dw1, const void* __restrict__ db1,
    const void* __restrict__ dw2, const void* __restrict__ db2,
    void* __restrict__ out, const int* __restrict__ flags)
{
    const int fbf = flags[0];
    __shared__ float zb[K_SLOTS * LATENT];
    __shared__ float w1[LATENT * HID], b1s[HID], w2[HID * LATENT], b2s[LATENT];
    int b = blockIdx.y;
    int t = threadIdx.x;
    if (t < K_SLOTS * LATENT) zb[t] = z[b * 32 + t];
    if (t < LATENT * HID) w1[t] = ldf(dw1, t, fbf);
    else if (t < LATENT * HID + HID * LATENT) w2[t - LATENT * HID] = ldf(dw2, t - LATENT * HID, fbf);
    if (t < HID) b1s[t] = ldf(db1, t, fbf);
    if (t < LATENT) b2s[t] = ldf(db2, t, fbf);
    __syncthreads();

    int n = blockIdx.x * 256 + t;
    if (n >= N_NODES) return;
    float sv[K_SLOTS];
#pragma unroll
    for (int k = 0; k < K_SLOTS; k++) sv[k] = s[(size_t)n * K_SLOTS + k];
    float q[LATENT];
#pragma unroll
    for (int d = 0; d < LATENT; d++) {
        float a = 0.f;
#pragma unroll
        for (int k = 0; k < K_SLOTS; k++) a = fmaf(sv[k], zb[k * LATENT + d], a);
        q[d] = a;
    }
    float t1[HID];
#pragma unroll
    for (int j = 0; j < HID; j++) t1[j] = b1s[j];
#pragma unroll
    for (int d = 0; d < LATENT; d++) {
        float v = q[d];
#pragma unroll
        for (int j = 0; j < HID; j++) t1[j] = fmaf(v, w1[d * HID + j], t1[j]);
    }
#pragma unroll
    for (int j = 0; j < HID; j++) t1[j] = t1[j] / (1.f + __expf(-t1[j]));
    float o[LATENT];
#pragma unroll
    for (int d = 0; d < LATENT; d++) o[d] = b2s[d];
#pragma unroll
    for (int j = 0; j < HID; j++) {
        float v = t1[j];
#pragma unroll
        for (int d = 0; d < LATENT; d++) o[d] = fmaf(v, w2[j * LATENT + d], o[d]);
    }
    if (fbf) {
        union { bf16 h[4]; uint2 u; } pk;
#pragma unroll
        for (int d = 0; d < LATENT; d++) pk.h[d] = __float2bfloat16(o[d]);
        ((uint2*)out)[(size_t)b * N_NODES + n] = pk.u;
    } else {
        float4 v4 = make_float4(o[0], o[1], o[2], o[3]);
        ((float4*)out)[(size_t)b * N_NODES + n] = v4;
    }
}

extern "C" void kernel_launch(void* const* d_in, const int* in_sizes, int n_in,
                              void* d_out, int out_size, void* d_ws, size_t ws_size,
                              hipStream_t stream) {
    const void* x      = d_in[0];
    const void* pos    = d_in[1];
    const int*  ei     = (const int*)d_in[2];
    const int*  batch  = (const int*)d_in[3];
    const void* enc_w1 = d_in[4];
    const void* enc_b1 = d_in[5];
    const void* enc_w2 = d_in[6];
    const void* enc_b2 = d_in[7];
    const void* pool_w = d_in[8];
    const void* pool_b = d_in[9];
    const void* toz_w  = d_in[10];
    const void* toz_b  = d_in[11];
    const void* dec_w1 = d_in[12];
    const void* dec_b1 = d_in[13];
    const void* dec_w2 = d_in[14];
    const void* dec_b2 = d_in[15];

    float* ws = (float*)d_ws;
    float* hsum   = ws + WS_HSUM;
    float* cnt    = ws + WS_CNT;
    float* s      = ws + WS_S;
    float* pooled = ws + WS_POOL;
    float* z      = ws + WS_Z;
    int*   flags  = (int*)(ws + WS_TOTAL);

    hipMemsetAsync(d_ws, 0, (size_t)WS_TOTAL * sizeof(float), stream);
    detect_kernel<<<1, 64, 0, stream>>>(x, ei, flags);

    edge_kernel<<<(N_EDGES + 255) / 256, 256, 0, stream>>>(
        x, pos, ei, enc_w1, enc_b1, enc_w2, enc_b2, hsum, cnt, flags);
    node_kernel<<<(N_NODES + 255) / 256, 256, 0, stream>>>(
        hsum, cnt, pool_w, pool_b, s, flags);
    pool_kernel<<<(N_NODES + 255) / 256, 256, 0, stream>>>(
        hsum, s, batch, pooled, flags);
    z_kernel<<<1, 512, 0, stream>>>(pooled, toz_w, toz_b, z, flags);
    dim3 dg((N_NODES + 255) / 256, N_GRAPHS);
    decode_kernel<<<dg, 256, 0, stream>>>(
        s, z, dec_w1, dec_b1, dec_w2, dec_b2, d_out, flags);
}

// Round 3
// 1761.310 us; speedup vs baseline: 1.6678x; 1.6678x over previous
//
#include <hip/hip_runtime.h>
#include <hip/hip_bf16.h>

#define N_NODES 50000
#define N_EDGES 1600000
#define N_GRAPHS 16
#define K_SLOTS 8
#define LATENT 4
#define HID 32
#define NB_SCAN 196   // ceil(N_NODES/256)

typedef __hip_bfloat16 bf16;

__device__ __forceinline__ float b2f(bf16 v) { return __bfloat162float(v); }

// dtype-agnostic loads (flag is wave-uniform)
__device__ __forceinline__ float ldf(const void* p, long i, int isbf) {
    return isbf ? __bfloat162float(((const bf16*)p)[i]) : ((const float*)p)[i];
}
__device__ __forceinline__ int ldi(const int* p, long i, int is64) {
    return is64 ? p[2 * i] : p[i];
}

// ---- workspace layout (4-byte elements) ----
#define WS_HSUM 0                                   // N*32 f32 (normalized h)
#define WS_S    (N_NODES * HID)                     // N*8
#define WS_Z    (WS_S + N_NODES * K_SLOTS)          // 512
#define WS_POOL (WS_Z + N_GRAPHS * K_SLOTS * LATENT)       // 4096  (ZERO)
#define WS_DEG  (WS_POOL + N_GRAPHS * K_SLOTS * HID)       // N ints (ZERO) -> reused as fill
#define WS_BSUM (WS_DEG + N_NODES)                  // 256 ints
#define WS_OFFS (WS_BSUM + 256)                     // N ints
#define WS_PERM (WS_OFFS + N_NODES)                 // E ints
#define WS_FLAGS (WS_PERM + N_EDGES)                // 2 ints
#define WS_ZERO_BEG WS_POOL
#define WS_ZERO_CNT (WS_DEG + N_NODES - WS_POOL)

// ---------------- dtype detection ----------------
__global__ void detect_kernel(const void* x, const int* ei, int* flags) {
    if (threadIdx.x == 0) {
        const unsigned short* u = (const unsigned short*)x;
        int sane = 0;
        for (int j = 0; j < 64; j++) {
            unsigned short h = u[2 * j];       // low half of word j
            unsigned e = (h >> 7) & 0xFF;
            if ((h & 0x7FFF) == 0 || (e >= 100 && e <= 141)) sane++;
        }
        flags[0] = (sane >= 32) ? 1 : 0;       // 1: floats are bf16, 0: f32
        int zeros = 0;
        for (int j = 0; j < 64; j++) if (ei[2 * j + 1] == 0) zeros++;
        flags[1] = (zeros >= 60) ? 1 : 0;      // 1: ints are int64, 0: int32
    }
}

// ---------------- CSR build ----------------
__global__ __launch_bounds__(256) void hist_kernel(
    const int* __restrict__ ei, int* __restrict__ deg, const int* __restrict__ flags)
{
    const int i64 = flags[1];
    int e = blockIdx.x * 256 + threadIdx.x;
    if (e >= N_EDGES) return;
    int dst = ldi(ei, (long)N_EDGES + e, i64);
    atomicAdd(&deg[dst], 1);
}

__global__ __launch_bounds__(256) void scan1_kernel(
    const int* __restrict__ deg, int* __restrict__ bsum)
{
    __shared__ int sm[256];
    int n = blockIdx.x * 256 + threadIdx.x;
    sm[threadIdx.x] = (n < N_NODES) ? deg[n] : 0;
    __syncthreads();
    for (int s = 128; s > 0; s >>= 1) {
        if (threadIdx.x < s) sm[threadIdx.x] += sm[threadIdx.x + s];
        __syncthreads();
    }
    if (threadIdx.x == 0) bsum[blockIdx.x] = sm[0];
}

__global__ void scan2_kernel(int* bsum) {
    if (threadIdx.x == 0) {
        int run = 0;
        for (int b = 0; b < NB_SCAN; b++) { int v = bsum[b]; bsum[b] = run; run += v; }
    }
}

// exclusive scan within chunk + block offset; also re-zeros deg region as "fill"
__global__ __launch_bounds__(256) void scan3_kernel(
    int* __restrict__ degfill, const int* __restrict__ bsum, int* __restrict__ offs)
{
    __shared__ int sm[256];
    int n = blockIdx.x * 256 + threadIdx.x;
    int v = (n < N_NODES) ? degfill[n] : 0;
    sm[threadIdx.x] = v;
    __syncthreads();
    for (int s = 1; s < 256; s <<= 1) {
        int a = sm[threadIdx.x];
        int b = (threadIdx.x >= s) ? sm[threadIdx.x - s] : 0;
        __syncthreads();
        sm[threadIdx.x] = a + b;
        __syncthreads();
    }
    if (n < N_NODES) {
        offs[n] = bsum[blockIdx.x] + sm[threadIdx.x] - v;  // exclusive
        degfill[n] = 0;                                    // becomes fill counter
    }
}

__global__ __launch_bounds__(256) void scatter_kernel(
    const int* __restrict__ ei, const int* __restrict__ offs,
    int* __restrict__ fill, int* __restrict__ perm, const int* __restrict__ flags)
{
    const int i64 = flags[1];
    int e = blockIdx.x * 256 + threadIdx.x;
    if (e >= N_EDGES) return;
    int dst = ldi(ei, (long)N_EDGES + e, i64);
    int slot = atomicAdd(&fill[dst], 1);
    perm[offs[dst] + slot] = e;
}

// ---------------- fused node kernel: messages + mean-agg + pool softmax ----------------
// 4 threads per node; each processes deg/4 edges with full 32-ch accumulator.
__global__ __launch_bounds__(256) void node_fused_kernel(
    const void* __restrict__ x, const void* __restrict__ pos,
    const int* __restrict__ ei,
    const void* __restrict__ w1, const void* __restrict__ b1,
    const void* __restrict__ w2, const void* __restrict__ b2,
    const void* __restrict__ pw, const void* __restrict__ pb,
    const int* __restrict__ offs, const int* __restrict__ perm,
    float* __restrict__ hsum, float* __restrict__ s,
    const int* __restrict__ flags)
{
    const int fbf = flags[0], i64 = flags[1];
    __shared__ float sw1[9 * HID], sb1[HID], sw2[HID * HID], sb2[HID];
    __shared__ float spw[HID * K_SLOTS], spb[K_SLOTS];
    __shared__ float red[256 * 33];      // padded rows: bank-conflict-free
    int t = threadIdx.x;
    for (int i = t; i < 9 * HID; i += 256) sw1[i] = ldf(w1, i, fbf);
    for (int i = t; i < HID * HID; i += 256) sw2[i] = ldf(w2, i, fbf);
    for (int i = t; i < HID * K_SLOTS; i += 256) spw[i] = ldf(pw, i, fbf);
    if (t < HID) { sb1[t] = ldf(b1, t, fbf); sb2[t] = ldf(b2, t, fbf); }
    if (t < K_SLOTS) spb[t] = ldf(pb, t, fbf);
    __syncthreads();

    int nl = t >> 2, p = t & 3;
    int n = blockIdx.x * 64 + nl;
    bool valid = n < N_NODES;
    int beg = 0, end = 0;
    float xi0 = 0, xi1 = 0, xi2 = 0, xi3 = 0, pi0 = 0, pi1 = 0, pi2 = 0;
    if (valid) {
        beg = offs[n];
        end = (n == N_NODES - 1) ? N_EDGES : offs[n + 1];
        xi0 = ldf(x, (long)n * 4 + 0, fbf); xi1 = ldf(x, (long)n * 4 + 1, fbf);
        xi2 = ldf(x, (long)n * 4 + 2, fbf); xi3 = ldf(x, (long)n * 4 + 3, fbf);
        pi0 = ldf(pos, (long)n * 3 + 0, fbf); pi1 = ldf(pos, (long)n * 3 + 1, fbf);
        pi2 = ldf(pos, (long)n * 3 + 2, fbf);
    }
    float acc[HID];
#pragma unroll
    for (int c = 0; c < HID; c++) acc[c] = 0.f;

    for (int i = beg + p; i < end; i += 4) {
        int e = perm[i];
        int src = ldi(ei, e, i64);
        float in[9];
        in[0] = xi0; in[1] = xi1; in[2] = xi2; in[3] = xi3;
#pragma unroll
        for (int q = 0; q < 4; q++) in[4 + q] = ldf(x, (long)src * 4 + q, fbf);
        float dx = ldf(pos, (long)src * 3 + 0, fbf) - pi0;
        float dy = ldf(pos, (long)src * 3 + 1, fbf) - pi1;
        float dz = ldf(pos, (long)src * 3 + 2, fbf) - pi2;
        in[8] = sqrtf(dx * dx + dy * dy + dz * dz);

        float h1[HID];
#pragma unroll
        for (int j = 0; j < HID; j++) h1[j] = sb1[j];
#pragma unroll
        for (int q = 0; q < 9; q++) {
            float v = in[q];
#pragma unroll
            for (int j = 0; j < HID; j++) h1[j] = fmaf(v, sw1[q * HID + j], h1[j]);
        }
#pragma unroll
        for (int j = 0; j < HID; j++) h1[j] = h1[j] / (1.f + __expf(-h1[j]));
#pragma unroll
        for (int j = 0; j < HID; j++) {
            float v = h1[j];
#pragma unroll
            for (int c = 0; c < HID; c++) acc[c] = fmaf(v, sw2[j * HID + c], acc[c]);
        }
        // b2 folded in as deg*b2 at reduction
    }

    float* myrow = red + t * 33;
#pragma unroll
    for (int c = 0; c < HID; c++) myrow[c] = acc[c];
    __syncthreads();

    if (p == 0 && valid) {
        int deg = end - beg;
        float fdeg = (float)deg;
        float inv = 1.f / fmaxf(fdeg, 1.f);
        const float* r0 = red + t * 33;
        float h[HID];
#pragma unroll
        for (int c = 0; c < HID; c++) {
            float v = r0[c] + r0[33 + c] + r0[66 + c] + r0[99 + c] + fdeg * sb2[c];
            v *= inv;
            h[c] = v;
            hsum[(size_t)n * HID + c] = v;
        }
        float l[K_SLOTS];
#pragma unroll
        for (int k = 0; k < K_SLOTS; k++) l[k] = spb[k];
#pragma unroll
        for (int j = 0; j < HID; j++) {
            float v = h[j];
#pragma unroll
            for (int k = 0; k < K_SLOTS; k++) l[k] = fmaf(v, spw[j * K_SLOTS + k], l[k]);
        }
        float mx = l[0];
#pragma unroll
        for (int k = 1; k < K_SLOTS; k++) mx = fmaxf(mx, l[k]);
        float sum = 0.f;
#pragma unroll
        for (int k = 0; k < K_SLOTS; k++) { l[k] = __expf(l[k] - mx); sum += l[k]; }
        float is = 1.f / sum;
#pragma unroll
        for (int k = 0; k < K_SLOTS; k++) s[(size_t)n * K_SLOTS + k] = l[k] * is;
    }
}

// ---------------- soft pooling: pooled[b,k,c] = sum_n s[n,k]*h[n,c] ----------------
__global__ __launch_bounds__(256) void pool_kernel(
    const float* __restrict__ h, const float* __restrict__ s,
    const int* __restrict__ batch, float* __restrict__ pooled,
    const int* __restrict__ flags)
{
    const int i64 = flags[1];
    __shared__ float hL[256 * HID];
    __shared__ float sL[256 * K_SLOTS];
    __shared__ int gL[256];
    int n0 = blockIdx.x * 256;
    for (int i = threadIdx.x; i < 256 * HID; i += 256) {
        int n = n0 + i / HID;
        hL[i] = (n < N_NODES) ? h[(size_t)n0 * HID + i] : 0.f;
    }
    for (int i = threadIdx.x; i < 256 * K_SLOTS; i += 256) {
        int n = n0 + i / K_SLOTS;
        sL[i] = (n < N_NODES) ? s[(size_t)n0 * K_SLOTS + i] : 0.f;
    }
    {
        int n = n0 + threadIdx.x;
        gL[threadIdx.x] = ldi(batch, n < N_NODES ? n : (N_NODES - 1), i64);
    }
    __syncthreads();

    int t = threadIdx.x;
    int k = t >> 5, c = t & 31;
    float acc = 0.f;
    int curg = gL[0];
    int lim = min(256, N_NODES - n0);
    for (int i = 0; i < lim; i++) {
        int g = gL[i];
        if (g != curg) {
            atomicAdd(&pooled[curg * 256 + t], acc);
            acc = 0.f;
            curg = g;
        }
        acc = fmaf(sL[i * K_SLOTS + k], hL[i * HID + c], acc);
    }
    atomicAdd(&pooled[curg * 256 + t], acc);
}

// ---------------- z = pooled @ toz_w + toz_b ----------------
__global__ __launch_bounds__(512) void z_kernel(
    const float* __restrict__ pooled, const void* __restrict__ tw,
    const void* __restrict__ tb, float* __restrict__ z,
    const int* __restrict__ flags)
{
    const int fbf = flags[0];
    int t = threadIdx.x;           // 512 = 16*8*4
    int d = t & 3;
    int k = (t >> 2) & 7;
    int b = t >> 5;
    float acc = ldf(tb, d, fbf);
    for (int c = 0; c < HID; c++)
        acc = fmaf(pooled[b * 256 + k * 32 + c], ldf(tw, c * 4 + d, fbf), acc);
    z[t] = acc;
}

// ---------------- decode ----------------
__global__ __launch_bounds__(256) void decode_kernel(
    const float* __restrict__ s, const float* __restrict__ z,
    const void* __restrict__ dw1, const void* __restrict__ db1,
    const void* __restrict__ dw2, const void* __restrict__ db2,
    void* __restrict__ out, const int* __restrict__ flags)
{
    const int fbf = flags[0];
    __shared__ float zb[K_SLOTS * LATENT];
    __shared__ float w1[LATENT * HID], b1s[HID], w2[HID * LATENT], b2s[LATENT];
    int b = blockIdx.y;
    int t = threadIdx.x;
    if (t < K_SLOTS * LATENT) zb[t] = z[b * 32 + t];
    if (t < LATENT * HID) w1[t] = ldf(dw1, t, fbf);
    else if (t < LATENT * HID + HID * LATENT) w2[t - LATENT * HID] = ldf(dw2, t - LATENT * HID, fbf);
    if (t < HID) b1s[t] = ldf(db1, t, fbf);
    if (t < LATENT) b2s[t] = ldf(db2, t, fbf);
    __syncthreads();

    int n = blockIdx.x * 256 + t;
    if (n >= N_NODES) return;
    float sv[K_SLOTS];
#pragma unroll
    for (int k = 0; k < K_SLOTS; k++) sv[k] = s[(size_t)n * K_SLOTS + k];
    float q[LATENT];
#pragma unroll
    for (int d = 0; d < LATENT; d++) {
        float a = 0.f;
#pragma unroll
        for (int k = 0; k < K_SLOTS; k++) a = fmaf(sv[k], zb[k * LATENT + d], a);
        q[d] = a;
    }
    float t1[HID];
#pragma unroll
    for (int j = 0; j < HID; j++) t1[j] = b1s[j];
#pragma unroll
    for (int d = 0; d < LATENT; d++) {
        float v = q[d];
#pragma unroll
        for (int j = 0; j < HID; j++) t1[j] = fmaf(v, w1[d * HID + j], t1[j]);
    }
#pragma unroll
    for (int j = 0; j < HID; j++) t1[j] = t1[j] / (1.f + __expf(-t1[j]));
    float o[LATENT];
#pragma unroll
    for (int d = 0; d < LATENT; d++) o[d] = b2s[d];
#pragma unroll
    for (int j = 0; j < HID; j++) {
        float v = t1[j];
#pragma unroll
        for (int d = 0; d < LATENT; d++) o[d] = fmaf(v, w2[j * LATENT + d], o[d]);
    }
    if (fbf) {
        union { bf16 h[4]; uint2 u; } pk;
#pragma unroll
        for (int d = 0; d < LATENT; d++) pk.h[d] = __float2bfloat16(o[d]);
        ((uint2*)out)[(size_t)b * N_NODES + n] = pk.u;
    } else {
        float4 v4 = make_float4(o[0], o[1], o[2], o[3]);
        ((float4*)out)[(size_t)b * N_NODES + n] = v4;
    }
}

extern "C" void kernel_launch(void* const* d_in, const int* in_sizes, int n_in,
                              void* d_out, int out_size, void* d_ws, size_t ws_size,
                              hipStream_t stream) {
    const void* x      = d_in[0];
    const void* pos    = d_in[1];
    const int*  ei     = (const int*)d_in[2];
    const int*  batch  = (const int*)d_in[3];
    const void* enc_w1 = d_in[4];
    const void* enc_b1 = d_in[5];
    const void* enc_w2 = d_in[6];
    const void* enc_b2 = d_in[7];
    const void* pool_w = d_in[8];
    const void* pool_b = d_in[9];
    const void* toz_w  = d_in[10];
    const void* toz_b  = d_in[11];
    const void* dec_w1 = d_in[12];
    const void* dec_b1 = d_in[13];
    const void* dec_w2 = d_in[14];
    const void* dec_b2 = d_in[15];

    float* ws = (float*)d_ws;
    float* hsum   = ws + WS_HSUM;
    float* s      = ws + WS_S;
    float* z      = ws + WS_Z;
    float* pooled = ws + WS_POOL;
    int*   deg    = (int*)(ws + WS_DEG);    // later reused as fill
    int*   bsum   = (int*)(ws + WS_BSUM);
    int*   offs   = (int*)(ws + WS_OFFS);
    int*   perm   = (int*)(ws + WS_PERM);
    int*   flags  = (int*)(ws + WS_FLAGS);

    // zero only pooled + deg
    hipMemsetAsync((char*)d_ws + (size_t)WS_ZERO_BEG * 4, 0, (size_t)WS_ZERO_CNT * 4, stream);
    detect_kernel<<<1, 64, 0, stream>>>(x, ei, flags);

    int ge = (N_EDGES + 255) / 256;
    hist_kernel<<<ge, 256, 0, stream>>>(ei, deg, flags);
    scan1_kernel<<<NB_SCAN, 256, 0, stream>>>(deg, bsum);
    scan2_kernel<<<1, 64, 0, stream>>>(bsum);
    scan3_kernel<<<NB_SCAN, 256, 0, stream>>>(deg, bsum, offs);
    scatter_kernel<<<ge, 256, 0, stream>>>(ei, offs, deg /*fill*/, perm, flags);

    node_fused_kernel<<<(N_NODES + 63) / 64, 256, 0, stream>>>(
        x, pos, ei, enc_w1, enc_b1, enc_w2, enc_b2, pool_w, pool_b,
        offs, perm, hsum, s, flags);

    pool_kernel<<<(N_NODES + 255) / 256, 256, 0, stream>>>(
        hsum, s, batch, pooled, flags);
    z_kernel<<<1, 512, 0, stream>>>(pooled, toz_w, toz_b, z, flags);
    dim3 dg((N_NODES + 255) / 256, N_GRAPHS);
    decode_kernel<<<dg, 256, 0, stream>>>(
        s, z, dec_w1, dec_b1, dec_w2, dec_b2, d_out, flags);
}

// Round 4
// 482.273 us; speedup vs baseline: 6.0911x; 3.6521x over previous
//
#include <hip/hip_runtime.h>
#include <hip/hip_bf16.h>

#define N_NODES 50000
#define N_EDGES 1600000
#define N_GRAPHS 16
#define K_SLOTS 8
#define LATENT 4
#define HID 32
#define NB_SCAN 196   // ceil(N_NODES/256)

typedef __hip_bfloat16 bf16;

// dtype-agnostic loads (flag is wave-uniform)
__device__ __forceinline__ float ldf(const void* p, long i, int isbf) {
    return isbf ? __bfloat162float(((const bf16*)p)[i]) : ((const float*)p)[i];
}
__device__ __forceinline__ int ldi(const int* p, long i, int is64) {
    return is64 ? p[2 * i] : p[i];
}

// ---- workspace layout (4-byte elements) ----
// zeroed region first: hsum | pooled | deg
#define WS_HSUM 0                                         // N*32 f32 (ZERO)
#define WS_POOL (N_NODES * HID)                           // 4096 (ZERO)
#define WS_DEG  (WS_POOL + N_GRAPHS * K_SLOTS * HID)      // N ints (ZERO) -> reused as fill
#define WS_ZERO_CNT (WS_DEG + N_NODES)
#define WS_S    (WS_DEG + N_NODES)                        // N*8
#define WS_Z    (WS_S + N_NODES * K_SLOTS)                // 512
#define WS_BSUM (WS_Z + N_GRAPHS * K_SLOTS * LATENT)      // 256 ints
#define WS_OFFS (WS_BSUM + 256)                           // N ints
#define WS_SRCP (WS_OFFS + N_NODES)                       // E ints
#define WS_DSTP (WS_SRCP + N_EDGES)                       // E ints
#define WS_FLAGS (WS_DSTP + N_EDGES)                      // 2 ints

// ---------------- dtype detection ----------------
__global__ void detect_kernel(const void* x, const int* ei, int* flags) {
    if (threadIdx.x == 0) {
        const unsigned short* u = (const unsigned short*)x;
        int sane = 0;
        for (int j = 0; j < 64; j++) {
            unsigned short h = u[2 * j];
            unsigned e = (h >> 7) & 0xFF;
            if ((h & 0x7FFF) == 0 || (e >= 100 && e <= 141)) sane++;
        }
        flags[0] = (sane >= 32) ? 1 : 0;       // 1: floats are bf16, 0: f32
        int zeros = 0;
        for (int j = 0; j < 64; j++) if (ei[2 * j + 1] == 0) zeros++;
        flags[1] = (zeros >= 60) ? 1 : 0;      // 1: ints are int64, 0: int32
    }
}

// ---------------- CSR build ----------------
__global__ __launch_bounds__(256) void hist_kernel(
    const int* __restrict__ ei, int* __restrict__ deg, const int* __restrict__ flags)
{
    const int i64 = flags[1];
    int e = blockIdx.x * 256 + threadIdx.x;
    if (e >= N_EDGES) return;
    int dst = ldi(ei, (long)N_EDGES + e, i64);
    atomicAdd(&deg[dst], 1);
}

__global__ __launch_bounds__(256) void scan1_kernel(
    const int* __restrict__ deg, int* __restrict__ bsum)
{
    __shared__ int sm[256];
    int n = blockIdx.x * 256 + threadIdx.x;
    sm[threadIdx.x] = (n < N_NODES) ? deg[n] : 0;
    __syncthreads();
    for (int s = 128; s > 0; s >>= 1) {
        if (threadIdx.x < s) sm[threadIdx.x] += sm[threadIdx.x + s];
        __syncthreads();
    }
    if (threadIdx.x == 0) bsum[blockIdx.x] = sm[0];
}

// parallel exclusive scan of block sums (one block, NB_SCAN<=256)
__global__ __launch_bounds__(256) void scan2_kernel(int* bsum) {
    __shared__ int sm[256];
    int t = threadIdx.x;
    int v = (t < NB_SCAN) ? bsum[t] : 0;
    sm[t] = v;
    __syncthreads();
    for (int s = 1; s < 256; s <<= 1) {
        int a = sm[t];
        int b = (t >= s) ? sm[t - s] : 0;
        __syncthreads();
        sm[t] = a + b;
        __syncthreads();
    }
    if (t < NB_SCAN) bsum[t] = sm[t] - v;   // exclusive
}

// exclusive scan within chunk + block offset; re-zeros deg as "fill"
__global__ __launch_bounds__(256) void scan3_kernel(
    int* __restrict__ degfill, const int* __restrict__ bsum, int* __restrict__ offs)
{
    __shared__ int sm[256];
    int n = blockIdx.x * 256 + threadIdx.x;
    int v = (n < N_NODES) ? degfill[n] : 0;
    sm[threadIdx.x] = v;
    __syncthreads();
    for (int s = 1; s < 256; s <<= 1) {
        int a = sm[threadIdx.x];
        int b = (threadIdx.x >= s) ? sm[threadIdx.x - s] : 0;
        __syncthreads();
        sm[threadIdx.x] = a + b;
        __syncthreads();
    }
    if (n < N_NODES) {
        offs[n] = bsum[blockIdx.x] + sm[threadIdx.x] - v;
        degfill[n] = 0;
    }
}

__global__ __launch_bounds__(256) void scatter_kernel(
    const int* __restrict__ ei, const int* __restrict__ offs,
    int* __restrict__ fill, int* __restrict__ src_p, int* __restrict__ dst_p,
    const int* __restrict__ flags)
{
    const int i64 = flags[1];
    int e = blockIdx.x * 256 + threadIdx.x;
    if (e >= N_EDGES) return;
    int dst = ldi(ei, (long)N_EDGES + e, i64);
    int src = ldi(ei, e, i64);
    int slot = atomicAdd(&fill[dst], 1);
    int p = offs[dst] + slot;
    src_p[p] = src;
    dst_p[p] = dst;
}

// ---------------- fused msg + segmented LDS reduction ----------------
// 1 thread per perm-slot edge; block = 256 consecutive slots (E % 256 == 0).
// Block-local segment sums; interior runs -> plain store, boundary runs -> atomic.
__global__ __launch_bounds__(256) void msg_agg_kernel(
    const void* __restrict__ x, const void* __restrict__ pos,
    const int* __restrict__ src_p, const int* __restrict__ dst_p,
    const void* __restrict__ w1, const void* __restrict__ b1,
    const void* __restrict__ w2, const void* __restrict__ b2,
    float* __restrict__ hsum, const int* __restrict__ flags)
{
    const int fbf = flags[0];
    __shared__ float sw1[9 * HID], sb1[HID], sw2[HID * HID], sb2[HID];
    __shared__ float msgL[256 * 33];       // stride 33: conflict-free columns
    __shared__ int sdL[256];
    __shared__ int runstart[256];
    __shared__ int wcnt[4];
    int t = threadIdx.x;
    for (int i = t; i < 9 * HID; i += 256) sw1[i] = ldf(w1, i, fbf);
    for (int i = t; i < HID * HID; i += 256) sw2[i] = ldf(w2, i, fbf);
    if (t < HID) { sb1[t] = ldf(b1, t, fbf); sb2[t] = ldf(b2, t, fbf); }
    __syncthreads();

    long i = (long)blockIdx.x * 256 + t;
    int src = src_p[i];
    int dst = dst_p[i];

    float in[9];
#pragma unroll
    for (int q = 0; q < 4; q++) in[q] = ldf(x, (long)dst * 4 + q, fbf);      // x_i
#pragma unroll
    for (int q = 0; q < 4; q++) in[4 + q] = ldf(x, (long)src * 4 + q, fbf);  // x_j
    float dx = ldf(pos, (long)src * 3 + 0, fbf) - ldf(pos, (long)dst * 3 + 0, fbf);
    float dy = ldf(pos, (long)src * 3 + 1, fbf) - ldf(pos, (long)dst * 3 + 1, fbf);
    float dz = ldf(pos, (long)src * 3 + 2, fbf) - ldf(pos, (long)dst * 3 + 2, fbf);
    in[8] = sqrtf(dx * dx + dy * dy + dz * dz);

    float h1[HID];
#pragma unroll
    for (int j = 0; j < HID; j++) h1[j] = sb1[j];
#pragma unroll
    for (int q = 0; q < 9; q++) {
        float v = in[q];
#pragma unroll
        for (int j = 0; j < HID; j++) h1[j] = fmaf(v, sw1[q * HID + j], h1[j]);
    }
#pragma unroll
    for (int j = 0; j < HID; j++) h1[j] = h1[j] / (1.f + __expf(-h1[j]));  // silu

    float m[HID];
#pragma unroll
    for (int j = 0; j < HID; j++) m[j] = sb2[j];                // fold b2 per edge
#pragma unroll
    for (int j = 0; j < HID; j++) {
        float v = h1[j];
#pragma unroll
        for (int c = 0; c < HID; c++) m[c] = fmaf(v, sw2[j * HID + c], m[c]);
    }

    float* row = msgL + t * 33;
#pragma unroll
    for (int c = 0; c < HID; c++) row[c] = m[c];
    sdL[t] = dst;
    __syncthreads();

    // run detection (edges sorted by dst)
    bool head = (t == 0) || (sdL[t] != sdL[t - 1]);
    unsigned long long bal = __ballot(head);
    int lane = t & 63, w = t >> 6;
    if (lane == 0) wcnt[w] = __popcll(bal);
    __syncthreads();
    int nruns = wcnt[0] + wcnt[1] + wcnt[2] + wcnt[3];
    if (head) {
        int base = 0;
        for (int q = 0; q < w; q++) base += wcnt[q];
        int myrun = base + __popcll(bal & (((unsigned long long)1 << lane) - 1ull));
        runstart[myrun] = t;
    }
    __syncthreads();

    int g = t >> 5, c = t & 31;
    for (int r = g; r < nruns; r += 8) {
        int s0 = runstart[r];
        int s1 = (r + 1 < nruns) ? runstart[r + 1] : 256;
        float acc = 0.f;
        for (int j = s0; j < s1; j++) acc += msgL[j * 33 + c];
        int node = sdL[s0];
        if (s0 == 0 || s1 == 256) atomicAdd(&hsum[(size_t)node * HID + c], acc);
        else hsum[(size_t)node * HID + c] = acc;
    }
}

// ---------------- normalize + pool softmax ----------------
__global__ __launch_bounds__(256) void node_softmax_kernel(
    float* __restrict__ hsum, const int* __restrict__ offs,
    const void* __restrict__ pw, const void* __restrict__ pb,
    float* __restrict__ s, const int* __restrict__ flags)
{
    const int fbf = flags[0];
    __shared__ float spw[HID * K_SLOTS], spb[K_SLOTS];
    for (int i = threadIdx.x; i < HID * K_SLOTS; i += 256) spw[i] = ldf(pw, i, fbf);
    if (threadIdx.x < K_SLOTS) spb[threadIdx.x] = ldf(pb, threadIdx.x, fbf);
    __syncthreads();

    int n = blockIdx.x * 256 + threadIdx.x;
    if (n >= N_NODES) return;
    int beg = offs[n];
    int end = (n == N_NODES - 1) ? N_EDGES : offs[n + 1];
    float inv = 1.f / fmaxf((float)(end - beg), 1.f);
    float h[HID];
#pragma unroll
    for (int j = 0; j < HID; j++) {
        float v = hsum[(size_t)n * HID + j] * inv;
        h[j] = v;
        hsum[(size_t)n * HID + j] = v;
    }
    float l[K_SLOTS];
#pragma unroll
    for (int k = 0; k < K_SLOTS; k++) l[k] = spb[k];
#pragma unroll
    for (int j = 0; j < HID; j++) {
        float v = h[j];
#pragma unroll
        for (int k = 0; k < K_SLOTS; k++) l[k] = fmaf(v, spw[j * K_SLOTS + k], l[k]);
    }
    float mx = l[0];
#pragma unroll
    for (int k = 1; k < K_SLOTS; k++) mx = fmaxf(mx, l[k]);
    float sum = 0.f;
#pragma unroll
    for (int k = 0; k < K_SLOTS; k++) { l[k] = __expf(l[k] - mx); sum += l[k]; }
    float is = 1.f / sum;
#pragma unroll
    for (int k = 0; k < K_SLOTS; k++) s[(size_t)n * K_SLOTS + k] = l[k] * is;
}

// ---------------- soft pooling ----------------
__global__ __launch_bounds__(256) void pool_kernel(
    const float* __restrict__ h, const float* __restrict__ s,
    const int* __restrict__ batch, float* __restrict__ pooled,
    const int* __restrict__ flags)
{
    const int i64 = flags[1];
    __shared__ float hL[256 * HID];
    __shared__ float sL[256 * K_SLOTS];
    __shared__ int gL[256];
    int n0 = blockIdx.x * 256;
    for (int i = threadIdx.x; i < 256 * HID; i += 256) {
        int n = n0 + i / HID;
        hL[i] = (n < N_NODES) ? h[(size_t)n0 * HID + i] : 0.f;
    }
    for (int i = threadIdx.x; i < 256 * K_SLOTS; i += 256) {
        int n = n0 + i / K_SLOTS;
        sL[i] = (n < N_NODES) ? s[(size_t)n0 * K_SLOTS + i] : 0.f;
    }
    {
        int n = n0 + threadIdx.x;
        gL[threadIdx.x] = ldi(batch, n < N_NODES ? n : (N_NODES - 1), i64);
    }
    __syncthreads();

    int t = threadIdx.x;
    int k = t >> 5, c = t & 31;
    float acc = 0.f;
    int curg = gL[0];
    int lim = min(256, N_NODES - n0);
    for (int i = 0; i < lim; i++) {
        int g = gL[i];
        if (g != curg) {
            atomicAdd(&pooled[curg * 256 + t], acc);
            acc = 0.f;
            curg = g;
        }
        acc = fmaf(sL[i * K_SLOTS + k], hL[i * HID + c], acc);
    }
    atomicAdd(&pooled[curg * 256 + t], acc);
}

// ---------------- z = pooled @ toz_w + toz_b ----------------
__global__ __launch_bounds__(512) void z_kernel(
    const float* __restrict__ pooled, const void* __restrict__ tw,
    const void* __restrict__ tb, float* __restrict__ z,
    const int* __restrict__ flags)
{
    const int fbf = flags[0];
    int t = threadIdx.x;           // 512 = 16*8*4
    int d = t & 3;
    int k = (t >> 2) & 7;
    int b = t >> 5;
    float acc = ldf(tb, d, fbf);
    for (int c = 0; c < HID; c++)
        acc = fmaf(pooled[b * 256 + k * 32 + c], ldf(tw, c * 4 + d, fbf), acc);
    z[t] = acc;
}

// ---------------- decode ----------------
__global__ __launch_bounds__(256) void decode_kernel(
    const float* __restrict__ s, const float* __restrict__ z,
    const void* __restrict__ dw1, const void* __restrict__ db1,
    const void* __restrict__ dw2, const void* __restrict__ db2,
    void* __restrict__ out, const int* __restrict__ flags)
{
    const int fbf = flags[0];
    __shared__ float zb[K_SLOTS * LATENT];
    __shared__ float w1[LATENT * HID], b1s[HID], w2[HID * LATENT], b2s[LATENT];
    int b = blockIdx.y;
    int t = threadIdx.x;
    if (t < K_SLOTS * LATENT) zb[t] = z[b * 32 + t];
    if (t < LATENT * HID) w1[t] = ldf(dw1, t, fbf);
    else if (t < LATENT * HID + HID * LATENT) w2[t - LATENT * HID] = ldf(dw2, t - LATENT * HID, fbf);
    if (t < HID) b1s[t] = ldf(db1, t, fbf);
    if (t < LATENT) b2s[t] = ldf(db2, t, fbf);
    __syncthreads();

    int n = blockIdx.x * 256 + t;
    if (n >= N_NODES) return;
    float sv[K_SLOTS];
#pragma unroll
    for (int k = 0; k < K_SLOTS; k++) sv[k] = s[(size_t)n * K_SLOTS + k];
    float q[LATENT];
#pragma unroll
    for (int d = 0; d < LATENT; d++) {
        float a = 0.f;
#pragma unroll
        for (int k = 0; k < K_SLOTS; k++) a = fmaf(sv[k], zb[k * LATENT + d], a);
        q[d] = a;
    }
    float t1[HID];
#pragma unroll
    for (int j = 0; j < HID; j++) t1[j] = b1s[j];
#pragma unroll
    for (int d = 0; d < LATENT; d++) {
        float v = q[d];
#pragma unroll
        for (int j = 0; j < HID; j++) t1[j] = fmaf(v, w1[d * HID + j], t1[j]);
    }
#pragma unroll
    for (int j = 0; j < HID; j++) t1[j] = t1[j] / (1.f + __expf(-t1[j]));
    float o[LATENT];
#pragma unroll
    for (int d = 0; d < LATENT; d++) o[d] = b2s[d];
#pragma unroll
    for (int j = 0; j < HID; j++) {
        float v = t1[j];
#pragma unroll
        for (int d = 0; d < LATENT; d++) o[d] = fmaf(v, w2[j * LATENT + d], o[d]);
    }
    if (fbf) {
        union { bf16 h[4]; uint2 u; } pk;
#pragma unroll
        for (int d = 0; d < LATENT; d++) pk.h[d] = __float2bfloat16(o[d]);
        ((uint2*)out)[(size_t)b * N_NODES + n] = pk.u;
    } else {
        float4 v4 = make_float4(o[0], o[1], o[2], o[3]);
        ((float4*)out)[(size_t)b * N_NODES + n] = v4;
    }
}

extern "C" void kernel_launch(void* const* d_in, const int* in_sizes, int n_in,
                              void* d_out, int out_size, void* d_ws, size_t ws_size,
                              hipStream_t stream) {
    const void* x      = d_in[0];
    const void* pos    = d_in[1];
    const int*  ei     = (const int*)d_in[2];
    const int*  batch  = (const int*)d_in[3];
    const void* enc_w1 = d_in[4];
    const void* enc_b1 = d_in[5];
    const void* enc_w2 = d_in[6];
    const void* enc_b2 = d_in[7];
    const void* pool_w = d_in[8];
    const void* pool_b = d_in[9];
    const void* toz_w  = d_in[10];
    const void* toz_b  = d_in[11];
    const void* dec_w1 = d_in[12];
    const void* dec_b1 = d_in[13];
    const void* dec_w2 = d_in[14];
    const void* dec_b2 = d_in[15];

    float* ws = (float*)d_ws;
    float* hsum   = ws + WS_HSUM;
    float* pooled = ws + WS_POOL;
    int*   deg    = (int*)(ws + WS_DEG);   // reused as fill
    float* s      = ws + WS_S;
    float* z      = ws + WS_Z;
    int*   bsum   = (int*)(ws + WS_BSUM);
    int*   offs   = (int*)(ws + WS_OFFS);
    int*   src_p  = (int*)(ws + WS_SRCP);
    int*   dst_p  = (int*)(ws + WS_DSTP);
    int*   flags  = (int*)(ws + WS_FLAGS);

    hipMemsetAsync(d_ws, 0, (size_t)WS_ZERO_CNT * 4, stream);
    detect_kernel<<<1, 64, 0, stream>>>(x, ei, flags);

    int ge = (N_EDGES + 255) / 256;
    hist_kernel<<<ge, 256, 0, stream>>>(ei, deg, flags);
    scan1_kernel<<<NB_SCAN, 256, 0, stream>>>(deg, bsum);
    scan2_kernel<<<1, 256, 0, stream>>>(bsum);
    scan3_kernel<<<NB_SCAN, 256, 0, stream>>>(deg, bsum, offs);
    scatter_kernel<<<ge, 256, 0, stream>>>(ei, offs, deg, src_p, dst_p, flags);

    msg_agg_kernel<<<N_EDGES / 256, 256, 0, stream>>>(
        x, pos, src_p, dst_p, enc_w1, enc_b1, enc_w2, enc_b2, hsum, flags);

    node_softmax_kernel<<<(N_NODES + 255) / 256, 256, 0, stream>>>(
        hsum, offs, pool_w, pool_b, s, flags);
    pool_kernel<<<(N_NODES + 255) / 256, 256, 0, stream>>>(
        hsum, s, batch, pooled, flags);
    z_kernel<<<1, 512, 0, stream>>>(pooled, toz_w, toz_b, z, flags);
    dim3 dg((N_NODES + 255) / 256, N_GRAPHS);
    decode_kernel<<<dg, 256, 0, stream>>>(
        s, z, dec_w1, dec_b1, dec_w2, dec_b2, d_out, flags);
}

// Round 5
// 443.778 us; speedup vs baseline: 6.6195x; 1.0867x over previous
//
#include <hip/hip_runtime.h>
#include <hip/hip_bf16.h>

#define N_NODES 50000
#define N_EDGES 1600000
#define N_GRAPHS 16
#define K_SLOTS 8
#define LATENT 4
#define HID 32
#define NB_SCAN 196   // ceil(N_NODES/256)

typedef __hip_bfloat16 bf16;
typedef __attribute__((ext_vector_type(8))) short short8;
typedef __attribute__((ext_vector_type(4))) float f32x4;

// dtype-agnostic loads (flag is wave-uniform)
__device__ __forceinline__ float ldf(const void* p, long i, int isbf) {
    return isbf ? __bfloat162float(((const bf16*)p)[i]) : ((const float*)p)[i];
}
__device__ __forceinline__ int ldi(const int* p, long i, int is64) {
    return is64 ? p[2 * i] : p[i];
}
__device__ __forceinline__ short f2bs(float f) {
    bf16 h = __float2bfloat16(f);
    return *reinterpret_cast<short*>(&h);
}
__device__ __forceinline__ float bs2f(short s) {
    union { unsigned u; float f; } cv;
    cv.u = ((unsigned)(unsigned short)s) << 16;
    return cv.f;
}

// ---- workspace layout (4-byte elements) ----
#define WS_HSUM 0                                      // N*32 f32 (ZERO)
#define WS_POOL (N_NODES * HID)                        // 4096 (ZERO)
#define WS_DEG8 (WS_POOL + N_GRAPHS * K_SLOTS * HID)   // 8*N ints (ZERO) -> fill8
#define WS_ZERO_CNT (WS_DEG8 + 8 * N_NODES)
#define WS_CBASE (WS_DEG8 + 8 * N_NODES)               // 8*N ints
#define WS_S    (WS_CBASE + 8 * N_NODES)               // N*8
#define WS_Z    (WS_S + N_NODES * K_SLOTS)             // 512
#define WS_BSUM (WS_Z + N_GRAPHS * K_SLOTS * LATENT)   // 256
#define WS_OFFS (WS_BSUM + 256)                        // N
#define WS_SRCP (WS_OFFS + N_NODES)                    // E/2 ints (E ushorts)
#define WS_FLAGS (WS_SRCP + N_EDGES / 2)               // 2

// ---------------- dtype detection ----------------
__global__ void detect_kernel(const void* x, const int* ei, int* flags) {
    if (threadIdx.x == 0) {
        const unsigned short* u = (const unsigned short*)x;
        int sane = 0;
        for (int j = 0; j < 64; j++) {
            unsigned short h = u[2 * j];
            unsigned e = (h >> 7) & 0xFF;
            if ((h & 0x7FFF) == 0 || (e >= 100 && e <= 141)) sane++;
        }
        flags[0] = (sane >= 32) ? 1 : 0;       // 1: floats are bf16, 0: f32
        int zeros = 0;
        for (int j = 0; j < 64; j++) if (ei[2 * j + 1] == 0) zeros++;
        flags[1] = (zeros >= 60) ? 1 : 0;      // 1: ints are int64, 0: int32
    }
}

// ---------------- CSR build (8-way replicated counters) ----------------
__global__ __launch_bounds__(256) void hist_kernel(
    const int* __restrict__ ei, int* __restrict__ deg8, const int* __restrict__ flags)
{
    const int i64 = flags[1];
    int e = blockIdx.x * 256 + threadIdx.x;
    if (e >= N_EDGES) return;
    int dst = ldi(ei, (long)N_EDGES + e, i64);
    int c = blockIdx.x & 7;
    atomicAdd(&deg8[c * N_NODES + dst], 1);
}

__global__ __launch_bounds__(256) void scan1_kernel(
    const int* __restrict__ deg8, int* __restrict__ bsum)
{
    __shared__ int sm[256];
    int n = blockIdx.x * 256 + threadIdx.x;
    int v = 0;
    if (n < N_NODES) {
#pragma unroll
        for (int c = 0; c < 8; c++) v += deg8[c * N_NODES + n];
    }
    sm[threadIdx.x] = v;
    __syncthreads();
    for (int s = 128; s > 0; s >>= 1) {
        if (threadIdx.x < s) sm[threadIdx.x] += sm[threadIdx.x + s];
        __syncthreads();
    }
    if (threadIdx.x == 0) bsum[blockIdx.x] = sm[0];
}

__global__ __launch_bounds__(256) void scan2_kernel(int* bsum) {
    __shared__ int sm[256];
    int t = threadIdx.x;
    int v = (t < NB_SCAN) ? bsum[t] : 0;
    sm[t] = v;
    __syncthreads();
    for (int s = 1; s < 256; s <<= 1) {
        int a = sm[t];
        int b = (t >= s) ? sm[t - s] : 0;
        __syncthreads();
        sm[t] = a + b;
        __syncthreads();
    }
    if (t < NB_SCAN) bsum[t] = sm[t] - v;   // exclusive
}

// per-node offs + per-copy bases; re-zeros deg8 as fill8
__global__ __launch_bounds__(256) void scan3_kernel(
    int* __restrict__ deg8, const int* __restrict__ bsum,
    int* __restrict__ offs, int* __restrict__ cbase)
{
    __shared__ int sm[256];
    int n = blockIdx.x * 256 + threadIdx.x;
    int d8[8];
    int v = 0;
    if (n < N_NODES) {
#pragma unroll
        for (int c = 0; c < 8; c++) { d8[c] = deg8[c * N_NODES + n]; v += d8[c]; }
    }
    sm[threadIdx.x] = v;
    __syncthreads();
    for (int s = 1; s < 256; s <<= 1) {
        int a = sm[threadIdx.x];
        int b = (threadIdx.x >= s) ? sm[threadIdx.x - s] : 0;
        __syncthreads();
        sm[threadIdx.x] = a + b;
        __syncthreads();
    }
    if (n < N_NODES) {
        int off = bsum[blockIdx.x] + sm[threadIdx.x] - v;
        offs[n] = off;
        int run = off;
#pragma unroll
        for (int c = 0; c < 8; c++) {
            cbase[c * N_NODES + n] = run;
            run += d8[c];
            deg8[c * N_NODES + n] = 0;   // becomes fill8
        }
    }
}

__global__ __launch_bounds__(256) void scatter_kernel(
    const int* __restrict__ ei, const int* __restrict__ cbase,
    int* __restrict__ fill8, unsigned short* __restrict__ srcp16,
    const int* __restrict__ flags)
{
    const int i64 = flags[1];
    int e = blockIdx.x * 256 + threadIdx.x;
    if (e >= N_EDGES) return;
    int dst = ldi(ei, (long)N_EDGES + e, i64);
    int src = ldi(ei, e, i64);
    int c = blockIdx.x & 7;
    int slot = atomicAdd(&fill8[c * N_NODES + dst], 1);
    int p = cbase[c * N_NODES + dst] + slot;
    srcp16[p] = (unsigned short)src;
}

// ---------------- MFMA msg MLP + segmented reduction ----------------
// Block = 256 perm-slots (edges sorted by dst). Two bf16 16x16x32 MFMA GEMMs,
// weights live in B-fragments (VGPRs), silu between, run-reduction at the end.
__global__ __launch_bounds__(256) void msg_agg_kernel(
    const void* __restrict__ x, const void* __restrict__ pos,
    const unsigned short* __restrict__ srcp16, const int* __restrict__ offs,
    const void* __restrict__ w1, const void* __restrict__ b1,
    const void* __restrict__ w2, const void* __restrict__ b2,
    float* __restrict__ hsum, const int* __restrict__ flags)
{
    const int fbf = flags[0];
    __shared__ short bufA[256 * 40];   // A1 bf16 (stride 40), later msgL (stride 34)
    __shared__ short bufB[256 * 40];   // A2 bf16
    __shared__ int sdL[256];
    __shared__ int runstart[256];
    __shared__ int wcnt[4];

    int t = threadIdx.x;
    int lane = t & 63, wv = t >> 6;
    int nl = lane & 15, quad = lane >> 4;

    // weight B-fragments: B[k][n], lane: n = nl, k = quad*8+j
    short8 w1f0, w1f1, w2f0, w2f1;
#pragma unroll
    for (int j = 0; j < 8; j++) {
        int k = quad * 8 + j;
        w1f0[j] = (k < 9) ? f2bs(ldf(w1, k * 32 + nl, fbf)) : (short)0;
        w1f1[j] = (k < 9) ? f2bs(ldf(w1, k * 32 + 16 + nl, fbf)) : (short)0;
        w2f0[j] = f2bs(ldf(w2, k * 32 + nl, fbf));
        w2f1[j] = f2bs(ldf(w2, k * 32 + 16 + nl, fbf));
    }
    float b1c0 = ldf(b1, nl, fbf), b1c1 = ldf(b1, 16 + nl, fbf);
    float b2c0 = ldf(b2, nl, fbf), b2c1 = ldf(b2, 16 + nl, fbf);

    // ---- stage A1: in[9] per edge, zero-padded to K=32 ----
    long i = (long)blockIdx.x * 256 + t;
    int src = srcp16[i];
    int lo = 0, hi = N_NODES;                 // binary search: offs[lo] <= i < offs[hi]
    while (hi - lo > 1) { int mid = (lo + hi) >> 1; if (offs[mid] <= (int)i) lo = mid; else hi = mid; }
    int dst = lo;
    sdL[t] = dst;

    float in[9];
#pragma unroll
    for (int q = 0; q < 4; q++) in[q] = ldf(x, (long)dst * 4 + q, fbf);      // x_i
#pragma unroll
    for (int q = 0; q < 4; q++) in[4 + q] = ldf(x, (long)src * 4 + q, fbf);  // x_j
    float dx = ldf(pos, (long)src * 3 + 0, fbf) - ldf(pos, (long)dst * 3 + 0, fbf);
    float dy = ldf(pos, (long)src * 3 + 1, fbf) - ldf(pos, (long)dst * 3 + 1, fbf);
    float dz = ldf(pos, (long)src * 3 + 2, fbf) - ldf(pos, (long)dst * 3 + 2, fbf);
    in[8] = sqrtf(dx * dx + dy * dy + dz * dz);

    {
        short va[32];
#pragma unroll
        for (int q = 0; q < 9; q++) va[q] = f2bs(in[q]);
#pragma unroll
        for (int q = 9; q < 32; q++) va[q] = 0;
        unsigned* rowp = (unsigned*)&bufA[t * 40];
#pragma unroll
        for (int p = 0; p < 16; p++)
            rowp[p] = (unsigned)(unsigned short)va[2 * p] |
                      ((unsigned)(unsigned short)va[2 * p + 1] << 16);
    }
    __syncthreads();

    // ---- load all A1 fragments, then bufA is free ----
    int rb = wv * 64;
    short8 af[4];
#pragma unroll
    for (int mt = 0; mt < 4; mt++) {
        int row = rb + mt * 16 + nl;
        af[mt] = *(short8*)&bufA[row * 40 + quad * 8];
    }
    __syncthreads();

    // ---- layer1 MFMA + silu -> A2 (bf16, A-layout) ----
    f32x4 zero = {0.f, 0.f, 0.f, 0.f};
#pragma unroll
    for (int mt = 0; mt < 4; mt++) {
        f32x4 c0 = __builtin_amdgcn_mfma_f32_16x16x32_bf16(af[mt], w1f0, zero, 0, 0, 0);
        f32x4 c1 = __builtin_amdgcn_mfma_f32_16x16x32_bf16(af[mt], w1f1, zero, 0, 0, 0);
#pragma unroll
        for (int r = 0; r < 4; r++) {
            int row = rb + mt * 16 + quad * 4 + r;
            float v0 = c0[r] + b1c0; v0 = v0 / (1.f + __expf(-v0));
            float v1 = c1[r] + b1c1; v1 = v1 / (1.f + __expf(-v1));
            bufB[row * 40 + nl] = f2bs(v0);
            bufB[row * 40 + 16 + nl] = f2bs(v1);
        }
    }
    __syncthreads();

    // ---- layer2 MFMA -> msgL (bf16, stride 34) in bufA ----
    short* msgLb = bufA;
#pragma unroll
    for (int mt = 0; mt < 4; mt++) {
        int row = rb + mt * 16 + nl;
        short8 a2 = *(short8*)&bufB[row * 40 + quad * 8];
        f32x4 d0 = __builtin_amdgcn_mfma_f32_16x16x32_bf16(a2, w2f0, zero, 0, 0, 0);
        f32x4 d1 = __builtin_amdgcn_mfma_f32_16x16x32_bf16(a2, w2f1, zero, 0, 0, 0);
#pragma unroll
        for (int r = 0; r < 4; r++) {
            int orow = rb + mt * 16 + quad * 4 + r;
            msgLb[orow * 34 + nl] = f2bs(d0[r] + b2c0);
            msgLb[orow * 34 + 16 + nl] = f2bs(d1[r] + b2c1);
        }
    }
    __syncthreads();

    // ---- run detection + segmented reduction ----
    bool head = (t == 0) || (sdL[t] != sdL[t - 1]);
    unsigned long long bal = __ballot(head);
    if (lane == 0) wcnt[wv] = __popcll(bal);
    __syncthreads();
    int nruns = wcnt[0] + wcnt[1] + wcnt[2] + wcnt[3];
    if (head) {
        int base = 0;
        for (int q = 0; q < wv; q++) base += wcnt[q];
        int myrun = base + __popcll(bal & (((unsigned long long)1 << lane) - 1ull));
        runstart[myrun] = t;
    }
    __syncthreads();

    int g = t >> 5, c = t & 31;
    for (int r = g; r < nruns; r += 8) {
        int s0 = runstart[r];
        int s1 = (r + 1 < nruns) ? runstart[r + 1] : 256;
        float acc = 0.f;
        for (int j = s0; j < s1; j++) acc += bs2f(msgLb[j * 34 + c]);
        int node = sdL[s0];
        if (s0 == 0 || s1 == 256) atomicAdd(&hsum[(size_t)node * HID + c], acc);
        else hsum[(size_t)node * HID + c] = acc;
    }
}

// ---------------- normalize + pool softmax ----------------
__global__ __launch_bounds__(256) void node_softmax_kernel(
    float* __restrict__ hsum, const int* __restrict__ offs,
    const void* __restrict__ pw, const void* __restrict__ pb,
    float* __restrict__ s, const int* __restrict__ flags)
{
    const int fbf = flags[0];
    __shared__ float spw[HID * K_SLOTS], spb[K_SLOTS];
    for (int i = threadIdx.x; i < HID * K_SLOTS; i += 256) spw[i] = ldf(pw, i, fbf);
    if (threadIdx.x < K_SLOTS) spb[threadIdx.x] = ldf(pb, threadIdx.x, fbf);
    __syncthreads();

    int n = blockIdx.x * 256 + threadIdx.x;
    if (n >= N_NODES) return;
    int beg = offs[n];
    int end = (n == N_NODES - 1) ? N_EDGES : offs[n + 1];
    float inv = 1.f / fmaxf((float)(end - beg), 1.f);
    float h[HID];
#pragma unroll
    for (int j = 0; j < HID; j++) {
        float v = hsum[(size_t)n * HID + j] * inv;
        h[j] = v;
        hsum[(size_t)n * HID + j] = v;
    }
    float l[K_SLOTS];
#pragma unroll
    for (int k = 0; k < K_SLOTS; k++) l[k] = spb[k];
#pragma unroll
    for (int j = 0; j < HID; j++) {
        float v = h[j];
#pragma unroll
        for (int k = 0; k < K_SLOTS; k++) l[k] = fmaf(v, spw[j * K_SLOTS + k], l[k]);
    }
    float mx = l[0];
#pragma unroll
    for (int k = 1; k < K_SLOTS; k++) mx = fmaxf(mx, l[k]);
    float sum = 0.f;
#pragma unroll
    for (int k = 0; k < K_SLOTS; k++) { l[k] = __expf(l[k] - mx); sum += l[k]; }
    float is = 1.f / sum;
#pragma unroll
    for (int k = 0; k < K_SLOTS; k++) s[(size_t)n * K_SLOTS + k] = l[k] * is;
}

// ---------------- soft pooling ----------------
__global__ __launch_bounds__(256) void pool_kernel(
    const float* __restrict__ h, const float* __restrict__ s,
    const int* __restrict__ batch, float* __restrict__ pooled,
    const int* __restrict__ flags)
{
    const int i64 = flags[1];
    __shared__ float hL[256 * HID];
    __shared__ float sL[256 * K_SLOTS];
    __shared__ int gL[256];
    int n0 = blockIdx.x * 256;
    for (int i = threadIdx.x; i < 256 * HID; i += 256) {
        int n = n0 + i / HID;
        hL[i] = (n < N_NODES) ? h[(size_t)n0 * HID + i] : 0.f;
    }
    for (int i = threadIdx.x; i < 256 * K_SLOTS; i += 256) {
        int n = n0 + i / K_SLOTS;
        sL[i] = (n < N_NODES) ? s[(size_t)n0 * K_SLOTS + i] : 0.f;
    }
    {
        int n = n0 + threadIdx.x;
        gL[threadIdx.x] = ldi(batch, n < N_NODES ? n : (N_NODES - 1), i64);
    }
    __syncthreads();

    int t = threadIdx.x;
    int k = t >> 5, c = t & 31;
    float acc = 0.f;
    int curg = gL[0];
    int lim = min(256, N_NODES - n0);
    for (int i = 0; i < lim; i++) {
        int g = gL[i];
        if (g != curg) {
            atomicAdd(&pooled[curg * 256 + t], acc);
            acc = 0.f;
            curg = g;
        }
        acc = fmaf(sL[i * K_SLOTS + k], hL[i * HID + c], acc);
    }
    atomicAdd(&pooled[curg * 256 + t], acc);
}

// ---------------- z = pooled @ toz_w + toz_b ----------------
__global__ __launch_bounds__(512) void z_kernel(
    const float* __restrict__ pooled, const void* __restrict__ tw,
    const void* __restrict__ tb, float* __restrict__ z,
    const int* __restrict__ flags)
{
    const int fbf = flags[0];
    int t = threadIdx.x;           // 512 = 16*8*4
    int d = t & 3;
    int k = (t >> 2) & 7;
    int b = t >> 5;
    float acc = ldf(tb, d, fbf);
    for (int c = 0; c < HID; c++)
        acc = fmaf(pooled[b * 256 + k * 32 + c], ldf(tw, c * 4 + d, fbf), acc);
    z[t] = acc;
}

// ---------------- decode ----------------
__global__ __launch_bounds__(256) void decode_kernel(
    const float* __restrict__ s, const float* __restrict__ z,
    const void* __restrict__ dw1, const void* __restrict__ db1,
    const void* __restrict__ dw2, const void* __restrict__ db2,
    void* __restrict__ out, const int* __restrict__ flags)
{
    const int fbf = flags[0];
    __shared__ float zb[K_SLOTS * LATENT];
    __shared__ float w1[LATENT * HID], b1s[HID], w2[HID * LATENT], b2s[LATENT];
    int b = blockIdx.y;
    int t = threadIdx.x;
    if (t < K_SLOTS * LATENT) zb[t] = z[b * 32 + t];
    if (t < LATENT * HID) w1[t] = ldf(dw1, t, fbf);
    else if (t < LATENT * HID + HID * LATENT) w2[t - LATENT * HID] = ldf(dw2, t - LATENT * HID, fbf);
    if (t < HID) b1s[t] = ldf(db1, t, fbf);
    if (t < LATENT) b2s[t] = ldf(db2, t, fbf);
    __syncthreads();

    int n = blockIdx.x * 256 + t;
    if (n >= N_NODES) return;
    float sv[K_SLOTS];
#pragma unroll
    for (int k = 0; k < K_SLOTS; k++) sv[k] = s[(size_t)n * K_SLOTS + k];
    float q[LATENT];
#pragma unroll
    for (int d = 0; d < LATENT; d++) {
        float a = 0.f;
#pragma unroll
        for (int k = 0; k < K_SLOTS; k++) a = fmaf(sv[k], zb[k * LATENT + d], a);
        q[d] = a;
    }
    float t1[HID];
#pragma unroll
    for (int j = 0; j < HID; j++) t1[j] = b1s[j];
#pragma unroll
    for (int d = 0; d < LATENT; d++) {
        float v = q[d];
#pragma unroll
        for (int j = 0; j < HID; j++) t1[j] = fmaf(v, w1[d * HID + j], t1[j]);
    }
#pragma unroll
    for (int j = 0; j < HID; j++) t1[j] = t1[j] / (1.f + __expf(-t1[j]));
    float o[LATENT];
#pragma unroll
    for (int d = 0; d < LATENT; d++) o[d] = b2s[d];
#pragma unroll
    for (int j = 0; j < HID; j++) {
        float v = t1[j];
#pragma unroll
        for (int d = 0; d < LATENT; d++) o[d] = fmaf(v, w2[j * LATENT + d], o[d]);
    }
    if (fbf) {
        union { bf16 h[4]; uint2 u; } pk;
#pragma unroll
        for (int d = 0; d < LATENT; d++) pk.h[d] = __float2bfloat16(o[d]);
        ((uint2*)out)[(size_t)b * N_NODES + n] = pk.u;
    } else {
        float4 v4 = make_float4(o[0], o[1], o[2], o[3]);
        ((float4*)out)[(size_t)b * N_NODES + n] = v4;
    }
}

extern "C" void kernel_launch(void* const* d_in, const int* in_sizes, int n_in,
                              void* d_out, int out_size, void* d_ws, size_t ws_size,
                              hipStream_t stream) {
    const void* x      = d_in[0];
    const void* pos    = d_in[1];
    const int*  ei     = (const int*)d_in[2];
    const int*  batch  = (const int*)d_in[3];
    const void* enc_w1 = d_in[4];
    const void* enc_b1 = d_in[5];
    const void* enc_w2 = d_in[6];
    const void* enc_b2 = d_in[7];
    const void* pool_w = d_in[8];
    const void* pool_b = d_in[9];
    const void* toz_w  = d_in[10];
    const void* toz_b  = d_in[11];
    const void* dec_w1 = d_in[12];
    const void* dec_b1 = d_in[13];
    const void* dec_w2 = d_in[14];
    const void* dec_b2 = d_in[15];

    float* ws = (float*)d_ws;
    float* hsum   = ws + WS_HSUM;
    float* pooled = ws + WS_POOL;
    int*   deg8   = (int*)(ws + WS_DEG8);   // reused as fill8
    int*   cbase  = (int*)(ws + WS_CBASE);
    float* s      = ws + WS_S;
    float* z      = ws + WS_Z;
    int*   bsum   = (int*)(ws + WS_BSUM);
    int*   offs   = (int*)(ws + WS_OFFS);
    unsigned short* srcp16 = (unsigned short*)(ws + WS_SRCP);
    int*   flags  = (int*)(ws + WS_FLAGS);

    hipMemsetAsync(d_ws, 0, (size_t)WS_ZERO_CNT * 4, stream);
    detect_kernel<<<1, 64, 0, stream>>>(x, ei, flags);

    int ge = (N_EDGES + 255) / 256;
    hist_kernel<<<ge, 256, 0, stream>>>(ei, deg8, flags);
    scan1_kernel<<<NB_SCAN, 256, 0, stream>>>(deg8, bsum);
    scan2_kernel<<<1, 256, 0, stream>>>(bsum);
    scan3_kernel<<<NB_SCAN, 256, 0, stream>>>(deg8, bsum, offs, cbase);
    scatter_kernel<<<ge, 256, 0, stream>>>(ei, cbase, deg8, srcp16, flags);

    msg_agg_kernel<<<N_EDGES / 256, 256, 0, stream>>>(
        x, pos, srcp16, offs, enc_w1, enc_b1, enc_w2, enc_b2, hsum, flags);

    node_softmax_kernel<<<(N_NODES + 255) / 256, 256, 0, stream>>>(
        hsum, offs, pool_w, pool_b, s, flags);
    pool_kernel<<<(N_NODES + 255) / 256, 256, 0, stream>>>(
        hsum, s, batch, pooled, flags);
    z_kernel<<<1, 512, 0, stream>>>(pooled, toz_w, toz_b, z, flags);
    dim3 dg((N_NODES + 255) / 256, N_GRAPHS);
    decode_kernel<<<dg, 256, 0, stream>>>(
        s, z, dec_w1, dec_b1, dec_w2, dec_b2, d_out, flags);
}

// Round 6
// 417.026 us; speedup vs baseline: 7.0441x; 1.0641x over previous
//
#include <hip/hip_runtime.h>
#include <hip/hip_bf16.h>

#define N_NODES 50000
#define N_EDGES 1600000
#define N_GRAPHS 16
#define K_SLOTS 8
#define LATENT 4
#define HID 32
#define NB_SCAN 196   // ceil(N_NODES/256)

typedef __hip_bfloat16 bf16;
typedef __attribute__((ext_vector_type(8))) short short8;
typedef __attribute__((ext_vector_type(4))) float f32x4;

// dtype-agnostic loads (flag is wave-uniform)
__device__ __forceinline__ float ldf(const void* p, long i, int isbf) {
    return isbf ? __bfloat162float(((const bf16*)p)[i]) : ((const float*)p)[i];
}
__device__ __forceinline__ int ldi(const int* p, long i, int is64) {
    return is64 ? p[2 * i] : p[i];
}
__device__ __forceinline__ short f2bs(float f) {
    bf16 h = __float2bfloat16(f);
    return *reinterpret_cast<short*>(&h);
}
__device__ __forceinline__ float bs2f(short s) {
    union { unsigned u; float f; } cv;
    cv.u = ((unsigned)(unsigned short)s) << 16;
    return cv.f;
}

// ---- workspace layout (4-byte elements) ----
#define WS_HSUM 0                                      // N*32 f32 (ZERO)
#define WS_POOL (N_NODES * HID)                        // 4096 (ZERO)
#define WS_DEG8 (WS_POOL + N_GRAPHS * K_SLOTS * HID)   // 8*N ints (ZERO) -> fill8 (offset-init)
#define WS_ZERO_CNT (WS_DEG8 + 8 * N_NODES)
#define WS_S    (WS_DEG8 + 8 * N_NODES)                // N*8
#define WS_Z    (WS_S + N_NODES * K_SLOTS)             // 512
#define WS_BSUM (WS_Z + N_GRAPHS * K_SLOTS * LATENT)   // 256
#define WS_OFFS (WS_BSUM + 256)                        // N
#define WS_EDAT (WS_OFFS + N_NODES)                    // E uints (src | dst<<16)
#define WS_FLAGS (WS_EDAT + N_EDGES)                   // 2

// ---------------- dtype detection ----------------
__global__ void detect_kernel(const void* x, const int* ei, int* flags) {
    if (threadIdx.x == 0) {
        const unsigned short* u = (const unsigned short*)x;
        int sane = 0;
        for (int j = 0; j < 64; j++) {
            unsigned short h = u[2 * j];
            unsigned e = (h >> 7) & 0xFF;
            if ((h & 0x7FFF) == 0 || (e >= 100 && e <= 141)) sane++;
        }
        flags[0] = (sane >= 32) ? 1 : 0;       // 1: floats are bf16, 0: f32
        int zeros = 0;
        for (int j = 0; j < 64; j++) if (ei[2 * j + 1] == 0) zeros++;
        flags[1] = (zeros >= 60) ? 1 : 0;      // 1: ints are int64, 0: int32
    }
}

// ---------------- CSR build (8-way replicated, 4 edges/thread) ----------------
__global__ __launch_bounds__(256) void hist_kernel(
    const int* __restrict__ ei, int* __restrict__ deg8, const int* __restrict__ flags)
{
    const int i64 = flags[1];
    int e4 = (blockIdx.x * 256 + threadIdx.x) * 4;
    if (e4 >= N_EDGES) return;
    int c = blockIdx.x & 7;
    int d0, d1, d2, d3;
    if (i64) {
        const int4* p = (const int4*)(ei + 2 * ((long)N_EDGES + e4));
        int4 a = p[0], b = p[1];
        d0 = a.x; d1 = a.z; d2 = b.x; d3 = b.z;
    } else {
        int4 a = *(const int4*)(ei + N_EDGES + e4);
        d0 = a.x; d1 = a.y; d2 = a.z; d3 = a.w;
    }
    atomicAdd(&deg8[c * N_NODES + d0], 1);
    atomicAdd(&deg8[c * N_NODES + d1], 1);
    atomicAdd(&deg8[c * N_NODES + d2], 1);
    atomicAdd(&deg8[c * N_NODES + d3], 1);
}

__global__ __launch_bounds__(256) void scan1_kernel(
    const int* __restrict__ deg8, int* __restrict__ bsum)
{
    __shared__ int sm[256];
    int n = blockIdx.x * 256 + threadIdx.x;
    int v = 0;
    if (n < N_NODES) {
#pragma unroll
        for (int c = 0; c < 8; c++) v += deg8[c * N_NODES + n];
    }
    sm[threadIdx.x] = v;
    __syncthreads();
    for (int s = 128; s > 0; s >>= 1) {
        if (threadIdx.x < s) sm[threadIdx.x] += sm[threadIdx.x + s];
        __syncthreads();
    }
    if (threadIdx.x == 0) bsum[blockIdx.x] = sm[0];
}

__global__ __launch_bounds__(256) void scan2_kernel(int* bsum) {
    __shared__ int sm[256];
    int t = threadIdx.x;
    int v = (t < NB_SCAN) ? bsum[t] : 0;
    sm[t] = v;
    __syncthreads();
    for (int s = 1; s < 256; s <<= 1) {
        int a = sm[t];
        int b = (t >= s) ? sm[t - s] : 0;
        __syncthreads();
        sm[t] = a + b;
        __syncthreads();
    }
    if (t < NB_SCAN) bsum[t] = sm[t] - v;   // exclusive
}

// offs + fill8 initialized directly to per-copy running offsets
__global__ __launch_bounds__(256) void scan3_kernel(
    int* __restrict__ deg8, const int* __restrict__ bsum, int* __restrict__ offs)
{
    __shared__ int sm[256];
    int n = blockIdx.x * 256 + threadIdx.x;
    int d8[8];
    int v = 0;
    if (n < N_NODES) {
#pragma unroll
        for (int c = 0; c < 8; c++) { d8[c] = deg8[c * N_NODES + n]; v += d8[c]; }
    }
    sm[threadIdx.x] = v;
    __syncthreads();
    for (int s = 1; s < 256; s <<= 1) {
        int a = sm[threadIdx.x];
        int b = (threadIdx.x >= s) ? sm[threadIdx.x - s] : 0;
        __syncthreads();
        sm[threadIdx.x] = a + b;
        __syncthreads();
    }
    if (n < N_NODES) {
        int run = bsum[blockIdx.x] + sm[threadIdx.x] - v;
        offs[n] = run;
#pragma unroll
        for (int c = 0; c < 8; c++) {
            int dc = d8[c];
            deg8[c * N_NODES + n] = run;   // fill counter starts at slot base
            run += dc;
        }
    }
}

__global__ __launch_bounds__(256) void scatter_kernel(
    const int* __restrict__ ei, int* __restrict__ fill8,
    unsigned* __restrict__ edat, const int* __restrict__ flags)
{
    const int i64 = flags[1];
    int e4 = (blockIdx.x * 256 + threadIdx.x) * 4;
    if (e4 >= N_EDGES) return;
    int c = blockIdx.x & 7;
    int s0, s1, s2, s3, d0, d1, d2, d3;
    if (i64) {
        const int4* ps = (const int4*)(ei + 2 * (long)e4);
        int4 a = ps[0], b = ps[1];
        s0 = a.x; s1 = a.z; s2 = b.x; s3 = b.z;
        const int4* pd = (const int4*)(ei + 2 * ((long)N_EDGES + e4));
        int4 e = pd[0], f = pd[1];
        d0 = e.x; d1 = e.z; d2 = f.x; d3 = f.z;
    } else {
        int4 a = *(const int4*)(ei + e4);
        s0 = a.x; s1 = a.y; s2 = a.z; s3 = a.w;
        int4 b = *(const int4*)(ei + N_EDGES + e4);
        d0 = b.x; d1 = b.y; d2 = b.z; d3 = b.w;
    }
    int p0 = atomicAdd(&fill8[c * N_NODES + d0], 1);
    int p1 = atomicAdd(&fill8[c * N_NODES + d1], 1);
    int p2 = atomicAdd(&fill8[c * N_NODES + d2], 1);
    int p3 = atomicAdd(&fill8[c * N_NODES + d3], 1);
    edat[p0] = (unsigned)s0 | ((unsigned)d0 << 16);
    edat[p1] = (unsigned)s1 | ((unsigned)d1 << 16);
    edat[p2] = (unsigned)s2 | ((unsigned)d2 << 16);
    edat[p3] = (unsigned)s3 | ((unsigned)d3 << 16);
}

// ---------------- MFMA msg MLP + segmented reduction ----------------
// Block = 256 perm-slots (sorted by dst). Single LDS buffer (stride 34 shorts =
// 17 dwords, odd -> conflict-free); all staging<->fragment sharing is intra-wave
// (wave wv owns rows [64wv, 64wv+64)), barriers guard compiler ordering only.
__global__ __launch_bounds__(256) void msg_agg_kernel(
    const void* __restrict__ x, const void* __restrict__ pos,
    const unsigned* __restrict__ edat,
    const void* __restrict__ w1, const void* __restrict__ b1,
    const void* __restrict__ w2, const void* __restrict__ b2,
    float* __restrict__ hsum, const int* __restrict__ flags)
{
    const int fbf = flags[0];
    __shared__ short buf[256 * 34];    // 17 KB, reused: A1 -> A2 -> msgL
    __shared__ int sdL[256];
    __shared__ int runstart[256];
    __shared__ int wcnt[4];

    int t = threadIdx.x;
    int lane = t & 63, wv = t >> 6;
    int nl = lane & 15, quad = lane >> 4;

    // weight B-fragments: B[k][n], lane: n = nl, k = quad*8+j
    short8 w1f0, w1f1, w2f0, w2f1;
#pragma unroll
    for (int j = 0; j < 8; j++) {
        int k = quad * 8 + j;
        w1f0[j] = (k < 9) ? f2bs(ldf(w1, k * 32 + nl, fbf)) : (short)0;
        w1f1[j] = (k < 9) ? f2bs(ldf(w1, k * 32 + 16 + nl, fbf)) : (short)0;
        w2f0[j] = f2bs(ldf(w2, k * 32 + nl, fbf));
        w2f1[j] = f2bs(ldf(w2, k * 32 + 16 + nl, fbf));
    }
    float b1c0 = ldf(b1, nl, fbf), b1c1 = ldf(b1, 16 + nl, fbf);
    float b2c0 = ldf(b2, nl, fbf), b2c1 = ldf(b2, 16 + nl, fbf);

    // ---- decode edge, gather inputs ----
    long i = (long)blockIdx.x * 256 + t;
    unsigned ed = edat[i];
    int src = (int)(ed & 0xFFFFu);
    int dst = (int)(ed >> 16);
    sdL[t] = dst;

    float in[9];
#pragma unroll
    for (int q = 0; q < 4; q++) in[q] = ldf(x, (long)dst * 4 + q, fbf);      // x_i
#pragma unroll
    for (int q = 0; q < 4; q++) in[4 + q] = ldf(x, (long)src * 4 + q, fbf);  // x_j
    float dx = ldf(pos, (long)src * 3 + 0, fbf) - ldf(pos, (long)dst * 3 + 0, fbf);
    float dy = ldf(pos, (long)src * 3 + 1, fbf) - ldf(pos, (long)dst * 3 + 1, fbf);
    float dz = ldf(pos, (long)src * 3 + 2, fbf) - ldf(pos, (long)dst * 3 + 2, fbf);
    in[8] = sqrtf(dx * dx + dy * dy + dz * dz);

    // ---- stage A1 (K=32, zero-padded) ----
    {
        short va[32];
#pragma unroll
        for (int q = 0; q < 9; q++) va[q] = f2bs(in[q]);
#pragma unroll
        for (int q = 9; q < 32; q++) va[q] = 0;
        unsigned* rowp = (unsigned*)&buf[t * 34];
#pragma unroll
        for (int p = 0; p < 16; p++)
            rowp[p] = (unsigned)(unsigned short)va[2 * p] |
                      ((unsigned)(unsigned short)va[2 * p + 1] << 16);
    }
    __syncthreads();

    int rb = wv * 64;
    short8 af[4];
#pragma unroll
    for (int mt = 0; mt < 4; mt++) {
        int row = rb + mt * 16 + nl;
        af[mt] = *(short8*)&buf[row * 34 + quad * 8];
    }
    __syncthreads();

    // ---- layer1 MFMA + silu -> A2 back into buf ----
    f32x4 zero = {0.f, 0.f, 0.f, 0.f};
#pragma unroll
    for (int mt = 0; mt < 4; mt++) {
        f32x4 c0 = __builtin_amdgcn_mfma_f32_16x16x32_bf16(af[mt], w1f0, zero, 0, 0, 0);
        f32x4 c1 = __builtin_amdgcn_mfma_f32_16x16x32_bf16(af[mt], w1f1, zero, 0, 0, 0);
#pragma unroll
        for (int r = 0; r < 4; r++) {
            int row = rb + mt * 16 + quad * 4 + r;
            float v0 = c0[r] + b1c0; v0 = v0 / (1.f + __expf(-v0));
            float v1 = c1[r] + b1c1; v1 = v1 / (1.f + __expf(-v1));
            buf[row * 34 + nl] = f2bs(v0);
            buf[row * 34 + 16 + nl] = f2bs(v1);
        }
    }
    __syncthreads();

    short8 a2f[4];
#pragma unroll
    for (int mt = 0; mt < 4; mt++) {
        int row = rb + mt * 16 + nl;
        a2f[mt] = *(short8*)&buf[row * 34 + quad * 8];
    }
    __syncthreads();

    // ---- layer2 MFMA -> msgL back into buf ----
#pragma unroll
    for (int mt = 0; mt < 4; mt++) {
        f32x4 d0 = __builtin_amdgcn_mfma_f32_16x16x32_bf16(a2f[mt], w2f0, zero, 0, 0, 0);
        f32x4 d1 = __builtin_amdgcn_mfma_f32_16x16x32_bf16(a2f[mt], w2f1, zero, 0, 0, 0);
#pragma unroll
        for (int r = 0; r < 4; r++) {
            int orow = rb + mt * 16 + quad * 4 + r;
            buf[orow * 34 + nl] = f2bs(d0[r] + b2c0);
            buf[orow * 34 + 16 + nl] = f2bs(d1[r] + b2c1);
        }
    }
    __syncthreads();

    // ---- run detection + segmented reduction ----
    bool head = (t == 0) || (sdL[t] != sdL[t - 1]);
    unsigned long long bal = __ballot(head);
    if (lane == 0) wcnt[wv] = __popcll(bal);
    __syncthreads();
    int nruns = wcnt[0] + wcnt[1] + wcnt[2] + wcnt[3];
    if (head) {
        int base = 0;
        for (int q = 0; q < wv; q++) base += wcnt[q];
        int myrun = base + __popcll(bal & (((unsigned long long)1 << lane) - 1ull));
        runstart[myrun] = t;
    }
    __syncthreads();

    int g = t >> 5, c = t & 31;
    for (int r = g; r < nruns; r += 8) {
        int s0 = runstart[r];
        int s1 = (r + 1 < nruns) ? runstart[r + 1] : 256;
        float acc = 0.f;
        for (int j = s0; j < s1; j++) acc += bs2f(buf[j * 34 + c]);
        int node = sdL[s0];
        if (s0 == 0 || s1 == 256) atomicAdd(&hsum[(size_t)node * HID + c], acc);
        else hsum[(size_t)node * HID + c] = acc;
    }
}

// ---------------- normalize + pool softmax ----------------
__global__ __launch_bounds__(256) void node_softmax_kernel(
    float* __restrict__ hsum, const int* __restrict__ offs,
    const void* __restrict__ pw, const void* __restrict__ pb,
    float* __restrict__ s, const int* __restrict__ flags)
{
    const int fbf = flags[0];
    __shared__ float spw[HID * K_SLOTS], spb[K_SLOTS];
    for (int i = threadIdx.x; i < HID * K_SLOTS; i += 256) spw[i] = ldf(pw, i, fbf);
    if (threadIdx.x < K_SLOTS) spb[threadIdx.x] = ldf(pb, threadIdx.x, fbf);
    __syncthreads();

    int n = blockIdx.x * 256 + threadIdx.x;
    if (n >= N_NODES) return;
    int beg = offs[n];
    int end = (n == N_NODES - 1) ? N_EDGES : offs[n + 1];
    float inv = 1.f / fmaxf((float)(end - beg), 1.f);
    float h[HID];
#pragma unroll
    for (int j = 0; j < HID; j++) {
        float v = hsum[(size_t)n * HID + j] * inv;
        h[j] = v;
        hsum[(size_t)n * HID + j] = v;
    }
    float l[K_SLOTS];
#pragma unroll
    for (int k = 0; k < K_SLOTS; k++) l[k] = spb[k];
#pragma unroll
    for (int j = 0; j < HID; j++) {
        float v = h[j];
#pragma unroll
        for (int k = 0; k < K_SLOTS; k++) l[k] = fmaf(v, spw[j * K_SLOTS + k], l[k]);
    }
    float mx = l[0];
#pragma unroll
    for (int k = 1; k < K_SLOTS; k++) mx = fmaxf(mx, l[k]);
    float sum = 0.f;
#pragma unroll
    for (int k = 0; k < K_SLOTS; k++) { l[k] = __expf(l[k] - mx); sum += l[k]; }
    float is = 1.f / sum;
#pragma unroll
    for (int k = 0; k < K_SLOTS; k++) s[(size_t)n * K_SLOTS + k] = l[k] * is;
}

// ---------------- soft pooling ----------------
__global__ __launch_bounds__(256) void pool_kernel(
    const float* __restrict__ h, const float* __restrict__ s,
    const int* __restrict__ batch, float* __restrict__ pooled,
    const int* __restrict__ flags)
{
    const int i64 = flags[1];
    __shared__ float hL[256 * HID];
    __shared__ float sL[256 * K_SLOTS];
    __shared__ int gL[256];
    int n0 = blockIdx.x * 256;
    for (int i = threadIdx.x; i < 256 * HID; i += 256) {
        int n = n0 + i / HID;
        hL[i] = (n < N_NODES) ? h[(size_t)n0 * HID + i] : 0.f;
    }
    for (int i = threadIdx.x; i < 256 * K_SLOTS; i += 256) {
        int n = n0 + i / K_SLOTS;
        sL[i] = (n < N_NODES) ? s[(size_t)n0 * K_SLOTS + i] : 0.f;
    }
    {
        int n = n0 + threadIdx.x;
        gL[threadIdx.x] = ldi(batch, n < N_NODES ? n : (N_NODES - 1), i64);
    }
    __syncthreads();

    int t = threadIdx.x;
    int k = t >> 5, c = t & 31;
    float acc = 0.f;
    int curg = gL[0];
    int lim = min(256, N_NODES - n0);
    for (int i = 0; i < lim; i++) {
        int g = gL[i];
        if (g != curg) {
            atomicAdd(&pooled[curg * 256 + t], acc);
            acc = 0.f;
            curg = g;
        }
        acc = fmaf(sL[i * K_SLOTS + k], hL[i * HID + c], acc);
    }
    atomicAdd(&pooled[curg * 256 + t], acc);
}

// ---------------- z = pooled @ toz_w + toz_b ----------------
__global__ __launch_bounds__(512) void z_kernel(
    const float* __restrict__ pooled, const void* __restrict__ tw,
    const void* __restrict__ tb, float* __restrict__ z,
    const int* __restrict__ flags)
{
    const int fbf = flags[0];
    int t = threadIdx.x;           // 512 = 16*8*4
    int d = t & 3;
    int k = (t >> 2) & 7;
    int b = t >> 5;
    float acc = ldf(tb, d, fbf);
    for (int c = 0; c < HID; c++)
        acc = fmaf(pooled[b * 256 + k * 32 + c], ldf(tw, c * 4 + d, fbf), acc);
    z[t] = acc;
}

// ---------------- decode ----------------
__global__ __launch_bounds__(256) void decode_kernel(
    const float* __restrict__ s, const float* __restrict__ z,
    const void* __restrict__ dw1, const void* __restrict__ db1,
    const void* __restrict__ dw2, const void* __restrict__ db2,
    void* __restrict__ out, const int* __restrict__ flags)
{
    const int fbf = flags[0];
    __shared__ float zb[K_SLOTS * LATENT];
    __shared__ float w1[LATENT * HID], b1s[HID], w2[HID * LATENT], b2s[LATENT];
    int b = blockIdx.y;
    int t = threadIdx.x;
    if (t < K_SLOTS * LATENT) zb[t] = z[b * 32 + t];
    if (t < LATENT * HID) w1[t] = ldf(dw1, t, fbf);
    else if (t < LATENT * HID + HID * LATENT) w2[t - LATENT * HID] = ldf(dw2, t - LATENT * HID, fbf);
    if (t < HID) b1s[t] = ldf(db1, t, fbf);
    if (t < LATENT) b2s[t] = ldf(db2, t, fbf);
    __syncthreads();

    int n = blockIdx.x * 256 + t;
    if (n >= N_NODES) return;
    float sv[K_SLOTS];
#pragma unroll
    for (int k = 0; k < K_SLOTS; k++) sv[k] = s[(size_t)n * K_SLOTS + k];
    float q[LATENT];
#pragma unroll
    for (int d = 0; d < LATENT; d++) {
        float a = 0.f;
#pragma unroll
        for (int k = 0; k < K_SLOTS; k++) a = fmaf(sv[k], zb[k * LATENT + d], a);
        q[d] = a;
    }
    float t1[HID];
#pragma unroll
    for (int j = 0; j < HID; j++) t1[j] = b1s[j];
#pragma unroll
    for (int d = 0; d < LATENT; d++) {
        float v = q[d];
#pragma unroll
        for (int j = 0; j < HID; j++) t1[j] = fmaf(v, w1[d * HID + j], t1[j]);
    }
#pragma unroll
    for (int j = 0; j < HID; j++) t1[j] = t1[j] / (1.f + __expf(-t1[j]));
    float o[LATENT];
#pragma unroll
    for (int d = 0; d < LATENT; d++) o[d] = b2s[d];
#pragma unroll
    for (int j = 0; j < HID; j++) {
        float v = t1[j];
#pragma unroll
        for (int d = 0; d < LATENT; d++) o[d] = fmaf(v, w2[j * LATENT + d], o[d]);
    }
    if (fbf) {
        union { bf16 h[4]; uint2 u; } pk;
#pragma unroll
        for (int d = 0; d < LATENT; d++) pk.h[d] = __float2bfloat16(o[d]);
        ((uint2*)out)[(size_t)b * N_NODES + n] = pk.u;
    } else {
        float4 v4 = make_float4(o[0], o[1], o[2], o[3]);
        ((float4*)out)[(size_t)b * N_NODES + n] = v4;
    }
}

extern "C" void kernel_launch(void* const* d_in, const int* in_sizes, int n_in,
                              void* d_out, int out_size, void* d_ws, size_t ws_size,
                              hipStream_t stream) {
    const void* x      = d_in[0];
    const void* pos    = d_in[1];
    const int*  ei     = (const int*)d_in[2];
    const int*  batch  = (const int*)d_in[3];
    const void* enc_w1 = d_in[4];
    const void* enc_b1 = d_in[5];
    const void* enc_w2 = d_in[6];
    const void* enc_b2 = d_in[7];
    const void* pool_w = d_in[8];
    const void* pool_b = d_in[9];
    const void* toz_w  = d_in[10];
    const void* toz_b  = d_in[11];
    const void* dec_w1 = d_in[12];
    const void* dec_b1 = d_in[13];
    const void* dec_w2 = d_in[14];
    const void* dec_b2 = d_in[15];

    float* ws = (float*)d_ws;
    float* hsum   = ws + WS_HSUM;
    float* pooled = ws + WS_POOL;
    int*   deg8   = (int*)(ws + WS_DEG8);   // becomes fill8 (offset-initialized)
    float* s      = ws + WS_S;
    float* z      = ws + WS_Z;
    int*   bsum   = (int*)(ws + WS_BSUM);
    int*   offs   = (int*)(ws + WS_OFFS);
    unsigned* edat = (unsigned*)(ws + WS_EDAT);
    int*   flags  = (int*)(ws + WS_FLAGS);

    hipMemsetAsync(d_ws, 0, (size_t)WS_ZERO_CNT * 4, stream);
    detect_kernel<<<1, 64, 0, stream>>>(x, ei, flags);

    int ge4 = (N_EDGES / 4 + 255) / 256;
    hist_kernel<<<ge4, 256, 0, stream>>>(ei, deg8, flags);
    scan1_kernel<<<NB_SCAN, 256, 0, stream>>>(deg8, bsum);
    scan2_kernel<<<1, 256, 0, stream>>>(bsum);
    scan3_kernel<<<NB_SCAN, 256, 0, stream>>>(deg8, bsum, offs);
    scatter_kernel<<<ge4, 256, 0, stream>>>(ei, deg8, edat, flags);

    msg_agg_kernel<<<N_EDGES / 256, 256, 0, stream>>>(
        x, pos, edat, enc_w1, enc_b1, enc_w2, enc_b2, hsum, flags);

    node_softmax_kernel<<<(N_NODES + 255) / 256, 256, 0, stream>>>(
        hsum, offs, pool_w, pool_b, s, flags);
    pool_kernel<<<(N_NODES + 255) / 256, 256, 0, stream>>>(
        hsum, s, batch, pooled, flags);
    z_kernel<<<1, 512, 0, stream>>>(pooled, toz_w, toz_b, z, flags);
    dim3 dg((N_NODES + 255) / 256, N_GRAPHS);
    decode_kernel<<<dg, 256, 0, stream>>>(
        s, z, dec_w1, dec_b1, dec_w2, dec_b2, d_out, flags);
}

// Round 7
// 269.264 us; speedup vs baseline: 10.9097x; 1.5488x over previous
//
#include <hip/hip_runtime.h>
#include <hip/hip_bf16.h>

#define N_NODES 50000
#define N_EDGES 1600000
#define N_GRAPHS 16
#define K_SLOTS 8
#define LATENT 4
#define HID 32
#define NBUCKET 196      // ceil(N_NODES/256), bucket = dst>>8
#define BCAP 10240       // bucket capacity (mean 8192, sigma ~90 -> 22 sigma)
#define BIN_EPB 4096     // edges per bin block

typedef __hip_bfloat16 bf16;
typedef __attribute__((ext_vector_type(8))) short short8;
typedef __attribute__((ext_vector_type(4))) float f32x4;

// dtype-agnostic loads (flag is wave-uniform)
__device__ __forceinline__ float ldf(const void* p, long i, int isbf) {
    return isbf ? __bfloat162float(((const bf16*)p)[i]) : ((const float*)p)[i];
}
__device__ __forceinline__ int ldi(const int* p, long i, int is64) {
    return is64 ? p[2 * i] : p[i];
}
__device__ __forceinline__ short f2bs(float f) {
    bf16 h = __float2bfloat16(f);
    return *reinterpret_cast<short*>(&h);
}
__device__ __forceinline__ float bs2f(short s) {
    union { unsigned u; float f; } cv;
    cv.u = ((unsigned)(unsigned short)s) << 16;
    return cv.f;
}

// ---- workspace layout (4-byte elements) ----
#define WS_HSUM 0                                      // N*32 f32 (ZERO)
#define WS_POOL (N_NODES * HID)                        // 4096 (ZERO)
#define WS_GFILL (WS_POOL + N_GRAPHS * K_SLOTS * HID)  // 256 (ZERO)
#define WS_ZERO_CNT (WS_GFILL + 256)
#define WS_S    (WS_GFILL + 256)                       // N*8
#define WS_Z    (WS_S + N_NODES * K_SLOTS)             // 512
#define WS_BBASE (WS_Z + N_GRAPHS * K_SLOTS * LATENT)  // 256
#define WS_DEG  (WS_BBASE + 256)                       // N
#define WS_BINNED (WS_DEG + N_NODES)                   // NBUCKET*BCAP
#define WS_EDAT (WS_BINNED + NBUCKET * BCAP)           // E uints (src | dst<<16)
#define WS_FLAGS (WS_EDAT + N_EDGES)                   // 2

// ---------------- dtype detection ----------------
__global__ void detect_kernel(const void* x, const int* ei, int* flags) {
    if (threadIdx.x == 0) {
        const unsigned short* u = (const unsigned short*)x;
        int sane = 0;
        for (int j = 0; j < 64; j++) {
            unsigned short h = u[2 * j];
            unsigned e = (h >> 7) & 0xFF;
            if ((h & 0x7FFF) == 0 || (e >= 100 && e <= 141)) sane++;
        }
        flags[0] = (sane >= 32) ? 1 : 0;       // 1: floats are bf16, 0: f32
        int zeros = 0;
        for (int j = 0; j < 64; j++) if (ei[2 * j + 1] == 0) zeros++;
        flags[1] = (zeros >= 60) ? 1 : 0;      // 1: ints are int64, 0: int32
    }
}

// ---------------- pass 1: bin edges by dst>>8 ----------------
__global__ __launch_bounds__(256) void bin_kernel(
    const int* __restrict__ ei, int* __restrict__ gfill,
    unsigned* __restrict__ binned, const int* __restrict__ flags)
{
    const int i64 = flags[1];
    __shared__ int cnt[NBUCKET];
    __shared__ int cur[NBUCKET];
    int t = threadIdx.x;
    for (int i = t; i < NBUCKET; i += 256) cnt[i] = 0;
    __syncthreads();

    long e0 = (long)blockIdx.x * BIN_EPB;
    unsigned pk[16];
#pragma unroll
    for (int k = 0; k < 16; k++) {
        long e = e0 + k * 256 + t;           // coalesced per k-iteration
        if (e < N_EDGES) {
            int src = ldi(ei, e, i64);
            int dst = ldi(ei, N_EDGES + e, i64);
            pk[k] = (unsigned)src | ((unsigned)dst << 16);
            atomicAdd(&cnt[dst >> 8], 1);
        } else pk[k] = 0xFFFFFFFFu;          // src never 0xFFFF (src < 50000)
    }
    __syncthreads();
    for (int i = t; i < NBUCKET; i += 256)
        cur[i] = atomicAdd(&gfill[i], cnt[i]);   // reserve append range
    __syncthreads();
#pragma unroll
    for (int k = 0; k < 16; k++) {
        if (pk[k] != 0xFFFFFFFFu) {
            int b = pk[k] >> 24;             // dst>>8
            int pos = atomicAdd(&cur[b], 1);
            binned[(long)b * BCAP + pos] = pk[k];
        }
    }
}

// ---------------- bucket base offsets (exclusive prefix of counts) ----------------
__global__ __launch_bounds__(256) void bucket_scan_kernel(
    const int* __restrict__ gfill, int* __restrict__ bbase)
{
    __shared__ int sm[256];
    int t = threadIdx.x;
    int v = (t < NBUCKET) ? gfill[t] : 0;
    sm[t] = v;
    __syncthreads();
    for (int s = 1; s < 256; s <<= 1) {
        int a = sm[t];
        int b = (t >= s) ? sm[t - s] : 0;
        __syncthreads();
        sm[t] = a + b;
        __syncthreads();
    }
    if (t < NBUCKET) bbase[t] = sm[t] - v;
}

// ---------------- pass 2: per-bucket counting sort -> edat + deg ----------------
__global__ __launch_bounds__(256) void csr_kernel(
    const int* __restrict__ gfill, const int* __restrict__ bbase,
    const unsigned* __restrict__ binned, unsigned* __restrict__ edat,
    int* __restrict__ deg)
{
    __shared__ int lcnt[256];
    __shared__ int lcur[256];
    __shared__ int sm[256];
    int b = blockIdx.x;
    int t = threadIdx.x;
    int cnt = gfill[b];
    int base = bbase[b];
    lcnt[t] = 0;
    __syncthreads();
    const unsigned* bp = binned + (long)b * BCAP;
    for (int i = t; i < cnt; i += 256)
        atomicAdd(&lcnt[(bp[i] >> 16) & 255], 1);
    __syncthreads();
    int v = lcnt[t];
    sm[t] = v;
    __syncthreads();
    for (int s = 1; s < 256; s <<= 1) {
        int a = sm[t];
        int bb = (t >= s) ? sm[t - s] : 0;
        __syncthreads();
        sm[t] = a + bb;
        __syncthreads();
    }
    lcur[t] = sm[t] - v;    // exclusive local offset -> cursor
    int n = b * 256 + t;
    if (n < N_NODES) deg[n] = v;
    __syncthreads();
    for (int i = t; i < cnt; i += 256) {
        unsigned pk = bp[i];
        int pos = base + atomicAdd(&lcur[(pk >> 16) & 255], 1);
        edat[pos] = pk;      // scattered only within a <=40KB single-XCD window
    }
}

// ---------------- MFMA msg MLP + segmented reduction ----------------
__global__ __launch_bounds__(256) void msg_agg_kernel(
    const void* __restrict__ x, const void* __restrict__ pos,
    const unsigned* __restrict__ edat,
    const void* __restrict__ w1, const void* __restrict__ b1,
    const void* __restrict__ w2, const void* __restrict__ b2,
    float* __restrict__ hsum, const int* __restrict__ flags)
{
    const int fbf = flags[0];
    __shared__ short buf[256 * 34];    // 17 KB, reused: A1 -> A2 -> msgL
    __shared__ int sdL[256];
    __shared__ int runstart[256];
    __shared__ int wcnt[4];

    int t = threadIdx.x;
    int lane = t & 63, wv = t >> 6;
    int nl = lane & 15, quad = lane >> 4;

    // weight B-fragments: B[k][n], lane: n = nl, k = quad*8+j
    short8 w1f0, w1f1, w2f0, w2f1;
#pragma unroll
    for (int j = 0; j < 8; j++) {
        int k = quad * 8 + j;
        w1f0[j] = (k < 9) ? f2bs(ldf(w1, k * 32 + nl, fbf)) : (short)0;
        w1f1[j] = (k < 9) ? f2bs(ldf(w1, k * 32 + 16 + nl, fbf)) : (short)0;
        w2f0[j] = f2bs(ldf(w2, k * 32 + nl, fbf));
        w2f1[j] = f2bs(ldf(w2, k * 32 + 16 + nl, fbf));
    }
    float b1c0 = ldf(b1, nl, fbf), b1c1 = ldf(b1, 16 + nl, fbf);
    float b2c0 = ldf(b2, nl, fbf), b2c1 = ldf(b2, 16 + nl, fbf);

    // ---- decode edge, gather inputs ----
    long i = (long)blockIdx.x * 256 + t;
    unsigned ed = edat[i];
    int src = (int)(ed & 0xFFFFu);
    int dst = (int)(ed >> 16);
    sdL[t] = dst;

    float in[9];
#pragma unroll
    for (int q = 0; q < 4; q++) in[q] = ldf(x, (long)dst * 4 + q, fbf);      // x_i
#pragma unroll
    for (int q = 0; q < 4; q++) in[4 + q] = ldf(x, (long)src * 4 + q, fbf);  // x_j
    float dx = ldf(pos, (long)src * 3 + 0, fbf) - ldf(pos, (long)dst * 3 + 0, fbf);
    float dy = ldf(pos, (long)src * 3 + 1, fbf) - ldf(pos, (long)dst * 3 + 1, fbf);
    float dz = ldf(pos, (long)src * 3 + 2, fbf) - ldf(pos, (long)dst * 3 + 2, fbf);
    in[8] = sqrtf(dx * dx + dy * dy + dz * dz);

    // ---- stage A1 (K=32, zero-padded) ----
    {
        short va[32];
#pragma unroll
        for (int q = 0; q < 9; q++) va[q] = f2bs(in[q]);
#pragma unroll
        for (int q = 9; q < 32; q++) va[q] = 0;
        unsigned* rowp = (unsigned*)&buf[t * 34];
#pragma unroll
        for (int p = 0; p < 16; p++)
            rowp[p] = (unsigned)(unsigned short)va[2 * p] |
                      ((unsigned)(unsigned short)va[2 * p + 1] << 16);
    }
    __syncthreads();

    int rb = wv * 64;
    short8 af[4];
#pragma unroll
    for (int mt = 0; mt < 4; mt++) {
        int row = rb + mt * 16 + nl;
        af[mt] = *(short8*)&buf[row * 34 + quad * 8];
    }
    __syncthreads();

    // ---- layer1 MFMA + silu -> A2 back into buf ----
    f32x4 zero = {0.f, 0.f, 0.f, 0.f};
#pragma unroll
    for (int mt = 0; mt < 4; mt++) {
        f32x4 c0 = __builtin_amdgcn_mfma_f32_16x16x32_bf16(af[mt], w1f0, zero, 0, 0, 0);
        f32x4 c1 = __builtin_amdgcn_mfma_f32_16x16x32_bf16(af[mt], w1f1, zero, 0, 0, 0);
#pragma unroll
        for (int r = 0; r < 4; r++) {
            int row = rb + mt * 16 + quad * 4 + r;
            float v0 = c0[r] + b1c0; v0 = v0 / (1.f + __expf(-v0));
            float v1 = c1[r] + b1c1; v1 = v1 / (1.f + __expf(-v1));
            buf[row * 34 + nl] = f2bs(v0);
            buf[row * 34 + 16 + nl] = f2bs(v1);
        }
    }
    __syncthreads();

    short8 a2f[4];
#pragma unroll
    for (int mt = 0; mt < 4; mt++) {
        int row = rb + mt * 16 + nl;
        a2f[mt] = *(short8*)&buf[row * 34 + quad * 8];
    }
    __syncthreads();

    // ---- layer2 MFMA -> msgL back into buf ----
#pragma unroll
    for (int mt = 0; mt < 4; mt++) {
        f32x4 d0 = __builtin_amdgcn_mfma_f32_16x16x32_bf16(a2f[mt], w2f0, zero, 0, 0, 0);
        f32x4 d1 = __builtin_amdgcn_mfma_f32_16x16x32_bf16(a2f[mt], w2f1, zero, 0, 0, 0);
#pragma unroll
        for (int r = 0; r < 4; r++) {
            int orow = rb + mt * 16 + quad * 4 + r;
            buf[orow * 34 + nl] = f2bs(d0[r] + b2c0);
            buf[orow * 34 + 16 + nl] = f2bs(d1[r] + b2c1);
        }
    }
    __syncthreads();

    // ---- run detection + segmented reduction ----
    bool head = (t == 0) || (sdL[t] != sdL[t - 1]);
    unsigned long long bal = __ballot(head);
    if (lane == 0) wcnt[wv] = __popcll(bal);
    __syncthreads();
    int nruns = wcnt[0] + wcnt[1] + wcnt[2] + wcnt[3];
    if (head) {
        int base = 0;
        for (int q = 0; q < wv; q++) base += wcnt[q];
        int myrun = base + __popcll(bal & (((unsigned long long)1 << lane) - 1ull));
        runstart[myrun] = t;
    }
    __syncthreads();

    int g = t >> 5, c = t & 31;
    for (int r = g; r < nruns; r += 8) {
        int s0 = runstart[r];
        int s1 = (r + 1 < nruns) ? runstart[r + 1] : 256;
        float acc = 0.f;
        for (int j = s0; j < s1; j++) acc += bs2f(buf[j * 34 + c]);
        int node = sdL[s0];
        if (s0 == 0 || s1 == 256) atomicAdd(&hsum[(size_t)node * HID + c], acc);
        else hsum[(size_t)node * HID + c] = acc;
    }
}

// ---------------- normalize + pool softmax ----------------
__global__ __launch_bounds__(256) void node_softmax_kernel(
    float* __restrict__ hsum, const int* __restrict__ deg,
    const void* __restrict__ pw, const void* __restrict__ pb,
    float* __restrict__ s, const int* __restrict__ flags)
{
    const int fbf = flags[0];
    __shared__ float spw[HID * K_SLOTS], spb[K_SLOTS];
    for (int i = threadIdx.x; i < HID * K_SLOTS; i += 256) spw[i] = ldf(pw, i, fbf);
    if (threadIdx.x < K_SLOTS) spb[threadIdx.x] = ldf(pb, threadIdx.x, fbf);
    __syncthreads();

    int n = blockIdx.x * 256 + threadIdx.x;
    if (n >= N_NODES) return;
    float inv = 1.f / fmaxf((float)deg[n], 1.f);
    float h[HID];
#pragma unroll
    for (int j = 0; j < HID; j++) {
        float v = hsum[(size_t)n * HID + j] * inv;
        h[j] = v;
        hsum[(size_t)n * HID + j] = v;
    }
    float l[K_SLOTS];
#pragma unroll
    for (int k = 0; k < K_SLOTS; k++) l[k] = spb[k];
#pragma unroll
    for (int j = 0; j < HID; j++) {
        float v = h[j];
#pragma unroll
        for (int k = 0; k < K_SLOTS; k++) l[k] = fmaf(v, spw[j * K_SLOTS + k], l[k]);
    }
    float mx = l[0];
#pragma unroll
    for (int k = 1; k < K_SLOTS; k++) mx = fmaxf(mx, l[k]);
    float sum = 0.f;
#pragma unroll
    for (int k = 0; k < K_SLOTS; k++) { l[k] = __expf(l[k] - mx); sum += l[k]; }
    float is = 1.f / sum;
#pragma unroll
    for (int k = 0; k < K_SLOTS; k++) s[(size_t)n * K_SLOTS + k] = l[k] * is;
}

// ---------------- soft pooling ----------------
__global__ __launch_bounds__(256) void pool_kernel(
    const float* __restrict__ h, const float* __restrict__ s,
    const int* __restrict__ batch, float* __restrict__ pooled,
    const int* __restrict__ flags)
{
    const int i64 = flags[1];
    __shared__ float hL[256 * HID];
    __shared__ float sL[256 * K_SLOTS];
    __shared__ int gL[256];
    int n0 = blockIdx.x * 256;
    for (int i = threadIdx.x; i < 256 * HID; i += 256) {
        int n = n0 + i / HID;
        hL[i] = (n < N_NODES) ? h[(size_t)n0 * HID + i] : 0.f;
    }
    for (int i = threadIdx.x; i < 256 * K_SLOTS; i += 256) {
        int n = n0 + i / K_SLOTS;
        sL[i] = (n < N_NODES) ? s[(size_t)n0 * K_SLOTS + i] : 0.f;
    }
    {
        int n = n0 + threadIdx.x;
        gL[threadIdx.x] = ldi(batch, n < N_NODES ? n : (N_NODES - 1), i64);
    }
    __syncthreads();

    int t = threadIdx.x;
    int k = t >> 5, c = t & 31;
    float acc = 0.f;
    int curg = gL[0];
    int lim = min(256, N_NODES - n0);
    for (int i = 0; i < lim; i++) {
        int g = gL[i];
        if (g != curg) {
            atomicAdd(&pooled[curg * 256 + t], acc);
            acc = 0.f;
            curg = g;
        }
        acc = fmaf(sL[i * K_SLOTS + k], hL[i * HID + c], acc);
    }
    atomicAdd(&pooled[curg * 256 + t], acc);
}

// ---------------- z = pooled @ toz_w + toz_b ----------------
__global__ __launch_bounds__(512) void z_kernel(
    const float* __restrict__ pooled, const void* __restrict__ tw,
    const void* __restrict__ tb, float* __restrict__ z,
    const int* __restrict__ flags)
{
    const int fbf = flags[0];
    int t = threadIdx.x;           // 512 = 16*8*4
    int d = t & 3;
    int k = (t >> 2) & 7;
    int b = t >> 5;
    float acc = ldf(tb, d, fbf);
    for (int c = 0; c < HID; c++)
        acc = fmaf(pooled[b * 256 + k * 32 + c], ldf(tw, c * 4 + d, fbf), acc);
    z[t] = acc;
}

// ---------------- decode ----------------
__global__ __launch_bounds__(256) void decode_kernel(
    const float* __restrict__ s, const float* __restrict__ z,
    const void* __restrict__ dw1, const void* __restrict__ db1,
    const void* __restrict__ dw2, const void* __restrict__ db2,
    void* __restrict__ out, const int* __restrict__ flags)
{
    const int fbf = flags[0];
    __shared__ float zb[K_SLOTS * LATENT];
    __shared__ float w1[LATENT * HID], b1s[HID], w2[HID * LATENT], b2s[LATENT];
    int b = blockIdx.y;
    int t = threadIdx.x;
    if (t < K_SLOTS * LATENT) zb[t] = z[b * 32 + t];
    if (t < LATENT * HID) w1[t] = ldf(dw1, t, fbf);
    else if (t < LATENT * HID + HID * LATENT) w2[t - LATENT * HID] = ldf(dw2, t - LATENT * HID, fbf);
    if (t < HID) b1s[t] = ldf(db1, t, fbf);
    if (t < LATENT) b2s[t] = ldf(db2, t, fbf);
    __syncthreads();

    int n = blockIdx.x * 256 + t;
    if (n >= N_NODES) return;
    float sv[K_SLOTS];
#pragma unroll
    for (int k = 0; k < K_SLOTS; k++) sv[k] = s[(size_t)n * K_SLOTS + k];
    float q[LATENT];
#pragma unroll
    for (int d = 0; d < LATENT; d++) {
        float a = 0.f;
#pragma unroll
        for (int k = 0; k < K_SLOTS; k++) a = fmaf(sv[k], zb[k * LATENT + d], a);
        q[d] = a;
    }
    float t1[HID];
#pragma unroll
    for (int j = 0; j < HID; j++) t1[j] = b1s[j];
#pragma unroll
    for (int d = 0; d < LATENT; d++) {
        float v = q[d];
#pragma unroll
        for (int j = 0; j < HID; j++) t1[j] = fmaf(v, w1[d * HID + j], t1[j]);
    }
#pragma unroll
    for (int j = 0; j < HID; j++) t1[j] = t1[j] / (1.f + __expf(-t1[j]));
    float o[LATENT];
#pragma unroll
    for (int d = 0; d < LATENT; d++) o[d] = b2s[d];
#pragma unroll
    for (int j = 0; j < HID; j++) {
        float v = t1[j];
#pragma unroll
        for (int d = 0; d < LATENT; d++) o[d] = fmaf(v, w2[j * LATENT + d], o[d]);
    }
    if (fbf) {
        union { bf16 h[4]; uint2 u; } pk;
#pragma unroll
        for (int d = 0; d < LATENT; d++) pk.h[d] = __float2bfloat16(o[d]);
        ((uint2*)out)[(size_t)b * N_NODES + n] = pk.u;
    } else {
        float4 v4 = make_float4(o[0], o[1], o[2], o[3]);
        ((float4*)out)[(size_t)b * N_NODES + n] = v4;
    }
}

extern "C" void kernel_launch(void* const* d_in, const int* in_sizes, int n_in,
                              void* d_out, int out_size, void* d_ws, size_t ws_size,
                              hipStream_t stream) {
    const void* x      = d_in[0];
    const void* pos    = d_in[1];
    const int*  ei     = (const int*)d_in[2];
    const int*  batch  = (const int*)d_in[3];
    const void* enc_w1 = d_in[4];
    const void* enc_b1 = d_in[5];
    const void* enc_w2 = d_in[6];
    const void* enc_b2 = d_in[7];
    const void* pool_w = d_in[8];
    const void* pool_b = d_in[9];
    const void* toz_w  = d_in[10];
    const void* toz_b  = d_in[11];
    const void* dec_w1 = d_in[12];
    const void* dec_b1 = d_in[13];
    const void* dec_w2 = d_in[14];
    const void* dec_b2 = d_in[15];

    float* ws = (float*)d_ws;
    float* hsum   = ws + WS_HSUM;
    float* pooled = ws + WS_POOL;
    int*   gfill  = (int*)(ws + WS_GFILL);
    float* s      = ws + WS_S;
    float* z      = ws + WS_Z;
    int*   bbase  = (int*)(ws + WS_BBASE);
    int*   deg    = (int*)(ws + WS_DEG);
    unsigned* binned = (unsigned*)(ws + WS_BINNED);
    unsigned* edat   = (unsigned*)(ws + WS_EDAT);
    int*   flags  = (int*)(ws + WS_FLAGS);

    hipMemsetAsync(d_ws, 0, (size_t)WS_ZERO_CNT * 4, stream);
    detect_kernel<<<1, 64, 0, stream>>>(x, ei, flags);

    int gbin = (N_EDGES + BIN_EPB - 1) / BIN_EPB;
    bin_kernel<<<gbin, 256, 0, stream>>>(ei, gfill, binned, flags);
    bucket_scan_kernel<<<1, 256, 0, stream>>>(gfill, bbase);
    csr_kernel<<<NBUCKET, 256, 0, stream>>>(gfill, bbase, binned, edat, deg);

    msg_agg_kernel<<<N_EDGES / 256, 256, 0, stream>>>(
        x, pos, edat, enc_w1, enc_b1, enc_w2, enc_b2, hsum, flags);

    node_softmax_kernel<<<(N_NODES + 255) / 256, 256, 0, stream>>>(
        hsum, deg, pool_w, pool_b, s, flags);
    pool_kernel<<<(N_NODES + 255) / 256, 256, 0, stream>>>(
        hsum, s, batch, pooled, flags);
    z_kernel<<<1, 512, 0, stream>>>(pooled, toz_w, toz_b, z, flags);
    dim3 dg((N_NODES + 255) / 256, N_GRAPHS);
    decode_kernel<<<dg, 256, 0, stream>>>(
        s, z, dec_w1, dec_b1, dec_w2, dec_b2, d_out, flags);
}

// Round 9
// 229.753 us; speedup vs baseline: 12.7859x; 1.1720x over previous
//
#include <hip/hip_runtime.h>
#include <hip/hip_bf16.h>

#define N_NODES 50000
#define N_EDGES 1600000
#define N_GRAPHS 16
#define K_SLOTS 8
#define LATENT 4
#define HID 32
#define NBUCKET 196      // ceil(N_NODES/256), bucket = dst>>8
#define BCAP 10240       // bucket capacity (mean 8192, sigma ~90 -> 22 sigma)
#define BIN_EPB 4096     // edges per bin block

typedef __hip_bfloat16 bf16;
typedef __attribute__((ext_vector_type(8))) short short8;
typedef __attribute__((ext_vector_type(4))) float f32x4;

// dtype-agnostic loads (flag is wave-uniform)
__device__ __forceinline__ float ldf(const void* p, long i, int isbf) {
    return isbf ? __bfloat162float(((const bf16*)p)[i]) : ((const float*)p)[i];
}
__device__ __forceinline__ int ldi(const int* p, long i, int is64) {
    return is64 ? p[2 * i] : p[i];
}
__device__ __forceinline__ short f2bs(float f) {
    bf16 h = __float2bfloat16(f);
    return *reinterpret_cast<short*>(&h);
}
__device__ __forceinline__ float bs2f(unsigned s) {
    union { unsigned u; float f; } cv;
    cv.u = (s & 0xFFFFu) << 16;
    return cv.f;
}
__device__ __forceinline__ float fast_silu(float v) {
    return v * __builtin_amdgcn_rcpf(1.f + __expf(-v));
}

// ---- workspace layout (4-byte elements) ----
#define WS_HSUM 0                                      // N*32 f32 (ZERO)
#define WS_POOL (N_NODES * HID)                        // 4096 (ZERO)
#define WS_GFILL (WS_POOL + N_GRAPHS * K_SLOTS * HID)  // 256 (ZERO)
#define WS_ZERO_CNT (WS_GFILL + 256)
#define WS_S    (WS_GFILL + 256)                       // N*8
#define WS_FRAGS (WS_S + N_NODES * K_SLOTS)            // 1024 dwords (4 frags * 64 lanes * 8 bf16 = 2048 shorts)
#define WS_DEG  (WS_FRAGS + 1024)                      // N   (FIX: was +512 -> deg clobbered w2 fragments)
#define WS_BINNED (WS_DEG + N_NODES)                   // NBUCKET*BCAP
#define WS_EDAT (WS_BINNED + NBUCKET * BCAP)           // E uints (src | dst<<16)
#define WS_FLAGS (WS_EDAT + N_EDGES)                   // 2

// ---------------- prep: dtype detection + weight fragment build ----------------
__global__ void prep_kernel(const void* x, const int* ei,
                            const void* w1, const void* w2,
                            int* flags, short* frags)
{
    __shared__ int sf[2];
    int t = threadIdx.x;   // 64
    if (t == 0) {
        const unsigned short* u = (const unsigned short*)x;
        int sane = 0;
        for (int j = 0; j < 64; j++) {
            unsigned short h = u[2 * j];
            unsigned e = (h >> 7) & 0xFF;
            if ((h & 0x7FFF) == 0 || (e >= 100 && e <= 141)) sane++;
        }
        int f0 = (sane >= 32) ? 1 : 0;         // 1: floats are bf16, 0: f32
        int zeros = 0;
        for (int j = 0; j < 64; j++) if (ei[2 * j + 1] == 0) zeros++;
        int f1 = (zeros >= 60) ? 1 : 0;        // 1: ints are int64, 0: int32
        flags[0] = f0; flags[1] = f1;
        sf[0] = f0; sf[1] = f1;
    }
    __syncthreads();
    int fbf = sf[0];
    int nl = t & 15, quad = (t >> 4) & 3;
#pragma unroll
    for (int j = 0; j < 8; j++) {
        int k = quad * 8 + j;
        frags[(0 * 64 + t) * 8 + j] = (k < 9) ? f2bs(ldf(w1, k * 32 + nl, fbf)) : (short)0;
        frags[(1 * 64 + t) * 8 + j] = (k < 9) ? f2bs(ldf(w1, k * 32 + 16 + nl, fbf)) : (short)0;
        frags[(2 * 64 + t) * 8 + j] = f2bs(ldf(w2, k * 32 + nl, fbf));
        frags[(3 * 64 + t) * 8 + j] = f2bs(ldf(w2, k * 32 + 16 + nl, fbf));
    }
}

// ---------------- pass 1: bin edges by dst>>8 ----------------
__global__ __launch_bounds__(256) void bin_kernel(
    const int* __restrict__ ei, int* __restrict__ gfill,
    unsigned* __restrict__ binned, const int* __restrict__ flags)
{
    const int i64 = flags[1];
    __shared__ int cnt[NBUCKET];
    __shared__ int cur[NBUCKET];
    int t = threadIdx.x;
    for (int i = t; i < NBUCKET; i += 256) cnt[i] = 0;
    __syncthreads();

    long e0 = (long)blockIdx.x * BIN_EPB;
    unsigned pk[16];
#pragma unroll
    for (int k = 0; k < 16; k++) {
        long e = e0 + k * 256 + t;
        if (e < N_EDGES) {
            int src = ldi(ei, e, i64);
            int dst = ldi(ei, N_EDGES + e, i64);
            pk[k] = (unsigned)src | ((unsigned)dst << 16);
            atomicAdd(&cnt[dst >> 8], 1);
        } else pk[k] = 0xFFFFFFFFu;
    }
    __syncthreads();
    for (int i = t; i < NBUCKET; i += 256)
        cur[i] = atomicAdd(&gfill[i], cnt[i]);
    __syncthreads();
#pragma unroll
    for (int k = 0; k < 16; k++) {
        if (pk[k] != 0xFFFFFFFFu) {
            int b = pk[k] >> 24;
            int pos = atomicAdd(&cur[b], 1);
            binned[(long)b * BCAP + pos] = pk[k];
        }
    }
}

// ---------------- pass 2: per-bucket counting sort (with inline bucket scan) ----------------
__global__ __launch_bounds__(1024) void csr_kernel(
    const int* __restrict__ gfill, const unsigned* __restrict__ binned,
    unsigned* __restrict__ edat, int* __restrict__ deg)
{
    __shared__ int gsm[256];
    __shared__ int lcnt[256], lcur[256], sm[256];
    int b = blockIdx.x, t = threadIdx.x;
    if (t < 256) gsm[t] = (t < NBUCKET) ? gfill[t] : 0;
    if (t < 256) lcnt[t] = 0;
    __syncthreads();
    for (int s = 1; s < 256; s <<= 1) {
        int v = 0;
        if (t < 256) v = gsm[t] + ((t >= s) ? gsm[t - s] : 0);
        __syncthreads();
        if (t < 256) gsm[t] = v;
        __syncthreads();
    }
    int cnt = gfill[b];
    int base = gsm[b] - cnt;   // exclusive prefix
    const unsigned* bp = binned + (long)b * BCAP;
    for (int i = t; i < cnt; i += 1024)
        atomicAdd(&lcnt[(bp[i] >> 16) & 255], 1);
    __syncthreads();
    if (t < 256) sm[t] = lcnt[t];
    __syncthreads();
    for (int s = 1; s < 256; s <<= 1) {
        int v = 0;
        if (t < 256) v = sm[t] + ((t >= s) ? sm[t - s] : 0);
        __syncthreads();
        if (t < 256) sm[t] = v;
        __syncthreads();
    }
    if (t < 256) {
        lcur[t] = sm[t] - lcnt[t];
        int n = b * 256 + t;
        if (n < N_NODES) deg[n] = lcnt[t];
    }
    __syncthreads();
    for (int i = t; i < cnt; i += 1024) {
        unsigned pk = bp[i];
        int pos = base + atomicAdd(&lcur[(pk >> 16) & 255], 1);
        edat[pos] = pk;
    }
}

// ---------------- MFMA msg MLP + segmented reduction ----------------
__global__ __launch_bounds__(256) void msg_agg_kernel(
    const void* __restrict__ x, const void* __restrict__ pos,
    const unsigned* __restrict__ edat, const short* __restrict__ frags,
    const void* __restrict__ b1, const void* __restrict__ b2,
    float* __restrict__ hsum, const int* __restrict__ flags)
{
    const int fbf = flags[0];
    __shared__ short buf[256 * 34];    // 17 KB, reused: A1 -> A2 -> msgL
    __shared__ int sdL[256];
    __shared__ int runstart[256];
    __shared__ int wcnt[4];

    int t = threadIdx.x;
    int lane = t & 63, wv = t >> 6;
    int nl = lane & 15, quad = lane >> 4;

    // weight B-fragments: precomputed, 4 coalesced 16B loads
    const short8 w1f0 = *(const short8*)&frags[(0 * 64 + lane) * 8];
    const short8 w1f1 = *(const short8*)&frags[(1 * 64 + lane) * 8];
    const short8 w2f0 = *(const short8*)&frags[(2 * 64 + lane) * 8];
    const short8 w2f1 = *(const short8*)&frags[(3 * 64 + lane) * 8];
    float b1c0 = ldf(b1, nl, fbf), b1c1 = ldf(b1, 16 + nl, fbf);
    float b2c0 = ldf(b2, nl, fbf), b2c1 = ldf(b2, 16 + nl, fbf);

    // ---- decode edge, gather inputs (vectorized where layout permits) ----
    long i = (long)blockIdx.x * 256 + t;
    unsigned ed = edat[i];
    int src = (int)(ed & 0xFFFFu);
    int dst = (int)(ed >> 16);
    sdL[t] = dst;

    float in[9];
    if (fbf) {
        const unsigned* xb = (const unsigned*)x;
        unsigned d0 = xb[dst * 2], d1 = xb[dst * 2 + 1];
        unsigned s0 = xb[src * 2], s1 = xb[src * 2 + 1];
        in[0] = bs2f(d0); in[1] = bs2f(d0 >> 16);
        in[2] = bs2f(d1); in[3] = bs2f(d1 >> 16);
        in[4] = bs2f(s0); in[5] = bs2f(s0 >> 16);
        in[6] = bs2f(s1); in[7] = bs2f(s1 >> 16);
        const unsigned short* pp = (const unsigned short*)pos;
        float dx = bs2f(pp[3 * src + 0]) - bs2f(pp[3 * dst + 0]);
        float dy = bs2f(pp[3 * src + 1]) - bs2f(pp[3 * dst + 1]);
        float dz = bs2f(pp[3 * src + 2]) - bs2f(pp[3 * dst + 2]);
        in[8] = sqrtf(dx * dx + dy * dy + dz * dz);
    } else {
        float4 xd = ((const float4*)x)[dst];
        float4 xs = ((const float4*)x)[src];
        in[0] = xd.x; in[1] = xd.y; in[2] = xd.z; in[3] = xd.w;
        in[4] = xs.x; in[5] = xs.y; in[6] = xs.z; in[7] = xs.w;
        const float* pf = (const float*)pos;
        float dx = pf[3 * src + 0] - pf[3 * dst + 0];
        float dy = pf[3 * src + 1] - pf[3 * dst + 1];
        float dz = pf[3 * src + 2] - pf[3 * dst + 2];
        in[8] = sqrtf(dx * dx + dy * dy + dz * dz);
    }

    // ---- stage A1 (K=32, zero-padded) ----
    {
        short va[32];
#pragma unroll
        for (int q = 0; q < 9; q++) va[q] = f2bs(in[q]);
#pragma unroll
        for (int q = 9; q < 32; q++) va[q] = 0;
        unsigned* rowp = (unsigned*)&buf[t * 34];
#pragma unroll
        for (int p = 0; p < 16; p++)
            rowp[p] = (unsigned)(unsigned short)va[2 * p] |
                      ((unsigned)(unsigned short)va[2 * p + 1] << 16);
    }
    __syncthreads();

    int rb = wv * 64;
    short8 af[4];
#pragma unroll
    for (int mt = 0; mt < 4; mt++) {
        int row = rb + mt * 16 + nl;
        af[mt] = *(short8*)&buf[row * 34 + quad * 8];
    }
    __syncthreads();

    // ---- layer1 MFMA + silu -> A2 back into buf ----
    f32x4 zero = {0.f, 0.f, 0.f, 0.f};
#pragma unroll
    for (int mt = 0; mt < 4; mt++) {
        f32x4 c0 = __builtin_amdgcn_mfma_f32_16x16x32_bf16(af[mt], w1f0, zero, 0, 0, 0);
        f32x4 c1 = __builtin_amdgcn_mfma_f32_16x16x32_bf16(af[mt], w1f1, zero, 0, 0, 0);
#pragma unroll
        for (int r = 0; r < 4; r++) {
            int row = rb + mt * 16 + quad * 4 + r;
            buf[row * 34 + nl] = f2bs(fast_silu(c0[r] + b1c0));
            buf[row * 34 + 16 + nl] = f2bs(fast_silu(c1[r] + b1c1));
        }
    }
    __syncthreads();

    short8 a2f[4];
#pragma unroll
    for (int mt = 0; mt < 4; mt++) {
        int row = rb + mt * 16 + nl;
        a2f[mt] = *(short8*)&buf[row * 34 + quad * 8];
    }
    __syncthreads();

    // ---- layer2 MFMA -> msgL back into buf ----
#pragma unroll
    for (int mt = 0; mt < 4; mt++) {
        f32x4 d0 = __builtin_amdgcn_mfma_f32_16x16x32_bf16(a2f[mt], w2f0, zero, 0, 0, 0);
        f32x4 d1 = __builtin_amdgcn_mfma_f32_16x16x32_bf16(a2f[mt], w2f1, zero, 0, 0, 0);
#pragma unroll
        for (int r = 0; r < 4; r++) {
            int orow = rb + mt * 16 + quad * 4 + r;
            buf[orow * 34 + nl] = f2bs(d0[r] + b2c0);
            buf[orow * 34 + 16 + nl] = f2bs(d1[r] + b2c1);
        }
    }
    __syncthreads();

    // ---- run detection + segmented reduction ----
    bool head = (t == 0) || (sdL[t] != sdL[t - 1]);
    unsigned long long bal = __ballot(head);
    if (lane == 0) wcnt[wv] = __popcll(bal);
    __syncthreads();
    int nruns = wcnt[0] + wcnt[1] + wcnt[2] + wcnt[3];
    if (head) {
        int base = 0;
        for (int q = 0; q < wv; q++) base += wcnt[q];
        int myrun = base + __popcll(bal & (((unsigned long long)1 << lane) - 1ull));
        runstart[myrun] = t;
    }
    __syncthreads();

    int g = t >> 5, c = t & 31;
    for (int r = g; r < nruns; r += 8) {
        int s0 = runstart[r];
        int s1 = (r + 1 < nruns) ? runstart[r + 1] : 256;
        float acc = 0.f;
        for (int j = s0; j < s1; j++) acc += bs2f((unsigned)(unsigned short)buf[j * 34 + c]);
        int node = sdL[s0];
        if (s0 == 0 || s1 == 256) atomicAdd(&hsum[(size_t)node * HID + c], acc);
        else hsum[(size_t)node * HID + c] = acc;
    }
}

// ---------------- fused normalize + pool softmax + soft pooling ----------------
__global__ __launch_bounds__(256) void pool_softmax_kernel(
    const float* __restrict__ hsum, const int* __restrict__ deg,
    const int* __restrict__ batch,
    const void* __restrict__ pw, const void* __restrict__ pb,
    float* __restrict__ s, float* __restrict__ pooled,
    const int* __restrict__ flags)
{
    const int fbf = flags[0], i64 = flags[1];
    __shared__ float spw[HID * K_SLOTS], spb[K_SLOTS];
    __shared__ float hL[256 * 33];   // padded stride 33
    __shared__ float sL[256 * 9];    // padded stride 9
    __shared__ float invL[256];
    __shared__ int gL[256];
    int t = threadIdx.x;
    int n0 = blockIdx.x * 256;
    spw[t] = ldf(pw, t, fbf);
    if (t < K_SLOTS) spb[t] = ldf(pb, t, fbf);
    {
        int n = n0 + t;
        gL[t] = ldi(batch, (n < N_NODES) ? n : (N_NODES - 1), i64);
        invL[t] = (n < N_NODES) ? __builtin_amdgcn_rcpf(fmaxf((float)deg[n], 1.f)) : 0.f;
    }
    __syncthreads();
    for (int i = t; i < 256 * HID; i += 256) {
        int row = i >> 5, col = i & 31;
        int n = n0 + row;
        hL[row * 33 + col] = (n < N_NODES) ? hsum[(size_t)n0 * HID + i] * invL[row] : 0.f;
    }
    __syncthreads();

    // softmax per node
    if (n0 + t < N_NODES) {
        float l[K_SLOTS];
#pragma unroll
        for (int k = 0; k < K_SLOTS; k++) l[k] = spb[k];
#pragma unroll
        for (int j = 0; j < HID; j++) {
            float v = hL[t * 33 + j];
#pragma unroll
            for (int k = 0; k < K_SLOTS; k++) l[k] = fmaf(v, spw[j * K_SLOTS + k], l[k]);
        }
        float mx = l[0];
#pragma unroll
        for (int k = 1; k < K_SLOTS; k++) mx = fmaxf(mx, l[k]);
        float sum = 0.f;
#pragma unroll
        for (int k = 0; k < K_SLOTS; k++) { l[k] = __expf(l[k] - mx); sum += l[k]; }
        float is = __builtin_amdgcn_rcpf(sum);
#pragma unroll
        for (int k = 0; k < K_SLOTS; k++) { l[k] *= is; sL[t * 9 + k] = l[k]; }
        float4 v0 = make_float4(l[0], l[1], l[2], l[3]);
        float4 v1 = make_float4(l[4], l[5], l[6], l[7]);
        float4* sp = (float4*)(s + (size_t)(n0 + t) * K_SLOTS);
        sp[0] = v0; sp[1] = v1;
    } else {
#pragma unroll
        for (int k = 0; k < K_SLOTS; k++) sL[t * 9 + k] = 0.f;
    }
    __syncthreads();

    // pooling: thread t owns (k,c)
    int k = t >> 5, c = t & 31;
    float acc = 0.f;
    int curg = gL[0];
    int lim = min(256, N_NODES - n0);
    for (int i = 0; i < lim; i++) {
        int g = gL[i];
        if (g != curg) {
            atomicAdd(&pooled[curg * 256 + t], acc);
            acc = 0.f;
            curg = g;
        }
        acc = fmaf(sL[i * 9 + k], hL[i * 33 + c], acc);
    }
    atomicAdd(&pooled[curg * 256 + t], acc);
}

// ---------------- decode (with fused z) ----------------
__global__ __launch_bounds__(256) void decode_kernel(
    const float* __restrict__ s, const float* __restrict__ pooled,
    const void* __restrict__ tw, const void* __restrict__ tb,
    const void* __restrict__ dw1, const void* __restrict__ db1,
    const void* __restrict__ dw2, const void* __restrict__ db2,
    void* __restrict__ out, const int* __restrict__ flags)
{
    const int fbf = flags[0];
    __shared__ float zb[K_SLOTS * LATENT];
    __shared__ float w1[LATENT * HID], b1s[HID], w2[HID * LATENT], b2s[LATENT];
    int b = blockIdx.y;
    int t = threadIdx.x;
    if (t < K_SLOTS * LATENT) {        // z = pooled @ toz_w + toz_b (inline)
        int k = t >> 2, d = t & 3;
        float acc = ldf(tb, d, fbf);
        for (int c = 0; c < HID; c++)
            acc = fmaf(pooled[b * 256 + k * 32 + c], ldf(tw, c * 4 + d, fbf), acc);
        zb[t] = acc;
    }
    if (t < LATENT * HID) w1[t] = ldf(dw1, t, fbf);
    else if (t < LATENT * HID + HID * LATENT) w2[t - LATENT * HID] = ldf(dw2, t - LATENT * HID, fbf);
    if (t < HID) b1s[t] = ldf(db1, t, fbf);
    if (t < LATENT) b2s[t] = ldf(db2, t, fbf);
    __syncthreads();

    int n = blockIdx.x * 256 + t;
    if (n >= N_NODES) return;
    float sv[K_SLOTS];
#pragma unroll
    for (int k = 0; k < K_SLOTS; k++) sv[k] = s[(size_t)n * K_SLOTS + k];
    float q[LATENT];
#pragma unroll
    for (int d = 0; d < LATENT; d++) {
        float a = 0.f;
#pragma unroll
        for (int k = 0; k < K_SLOTS; k++) a = fmaf(sv[k], zb[k * LATENT + d], a);
        q[d] = a;
    }
    float t1[HID];
#pragma unroll
    for (int j = 0; j < HID; j++) t1[j] = b1s[j];
#pragma unroll
    for (int d = 0; d < LATENT; d++) {
        float v = q[d];
#pragma unroll
        for (int j = 0; j < HID; j++) t1[j] = fmaf(v, w1[d * HID + j], t1[j]);
    }
#pragma unroll
    for (int j = 0; j < HID; j++) t1[j] = fast_silu(t1[j]);
    float o[LATENT];
#pragma unroll
    for (int d = 0; d < LATENT; d++) o[d] = b2s[d];
#pragma unroll
    for (int j = 0; j < HID; j++) {
        float v = t1[j];
#pragma unroll
        for (int d = 0; d < LATENT; d++) o[d] = fmaf(v, w2[j * LATENT + d], o[d]);
    }
    if (fbf) {
        union { bf16 h[4]; uint2 u; } pk;
#pragma unroll
        for (int d = 0; d < LATENT; d++) pk.h[d] = __float2bfloat16(o[d]);
        ((uint2*)out)[(size_t)b * N_NODES + n] = pk.u;
    } else {
        float4 v4 = make_float4(o[0], o[1], o[2], o[3]);
        ((float4*)out)[(size_t)b * N_NODES + n] = v4;
    }
}

extern "C" void kernel_launch(void* const* d_in, const int* in_sizes, int n_in,
                              void* d_out, int out_size, void* d_ws, size_t ws_size,
                              hipStream_t stream) {
    const void* x      = d_in[0];
    const void* pos    = d_in[1];
    const int*  ei     = (const int*)d_in[2];
    const int*  batch  = (const int*)d_in[3];
    const void* enc_w1 = d_in[4];
    const void* enc_b1 = d_in[5];
    const void* enc_w2 = d_in[6];
    const void* enc_b2 = d_in[7];
    const void* pool_w = d_in[8];
    const void* pool_b = d_in[9];
    const void* toz_w  = d_in[10];
    const void* toz_b  = d_in[11];
    const void* dec_w1 = d_in[12];
    const void* dec_b1 = d_in[13];
    const void* dec_w2 = d_in[14];
    const void* dec_b2 = d_in[15];

    float* ws = (float*)d_ws;
    float* hsum   = ws + WS_HSUM;
    float* pooled = ws + WS_POOL;
    int*   gfill  = (int*)(ws + WS_GFILL);
    float* s      = ws + WS_S;
    short* frags  = (short*)(ws + WS_FRAGS);
    int*   deg    = (int*)(ws + WS_DEG);
    unsigned* binned = (unsigned*)(ws + WS_BINNED);
    unsigned* edat   = (unsigned*)(ws + WS_EDAT);
    int*   flags  = (int*)(ws + WS_FLAGS);

    hipMemsetAsync(d_ws, 0, (size_t)WS_ZERO_CNT * 4, stream);
    prep_kernel<<<1, 64, 0, stream>>>(x, ei, enc_w1, enc_w2, flags, frags);

    int gbin = (N_EDGES + BIN_EPB - 1) / BIN_EPB;
    bin_kernel<<<gbin, 256, 0, stream>>>(ei, gfill, binned, flags);
    csr_kernel<<<NBUCKET, 1024, 0, stream>>>(gfill, binned, edat, deg);

    msg_agg_kernel<<<N_EDGES / 256, 256, 0, stream>>>(
        x, pos, edat, frags, enc_b1, enc_b2, hsum, flags);

    pool_softmax_kernel<<<NBUCKET, 256, 0, stream>>>(
        hsum, deg, batch, pool_w, pool_b, s, pooled, flags);
    dim3 dg((N_NODES + 255) / 256, N_GRAPHS);
    decode_kernel<<<dg, 256, 0, stream>>>(
        s, pooled, toz_w, toz_b, dec_w1, dec_b1, dec_w2, dec_b2, d_out, flags);
}

// Round 10
// 214.498 us; speedup vs baseline: 13.6952x; 1.0711x over previous
//
#include <hip/hip_runtime.h>
#include <hip/hip_bf16.h>

#define N_NODES 50000
#define N_EDGES 1600000
#define N_GRAPHS 16
#define K_SLOTS 8
#define LATENT 4
#define HID 32
#define NBUCKET 196      // ceil(N_NODES/256), bucket = dst>>8
#define BCAP 10240       // bucket capacity (mean 8192, sigma ~90 -> 22 sigma)
#define BIN_EPB 4096     // edges per bin block

typedef __hip_bfloat16 bf16;
typedef __attribute__((ext_vector_type(8))) short short8;
typedef __attribute__((ext_vector_type(4))) float f32x4;

// dtype-agnostic loads (flag is wave-uniform)
__device__ __forceinline__ float ldf(const void* p, long i, int isbf) {
    return isbf ? __bfloat162float(((const bf16*)p)[i]) : ((const float*)p)[i];
}
__device__ __forceinline__ int ldi(const int* p, long i, int is64) {
    return is64 ? p[2 * i] : p[i];
}
__device__ __forceinline__ short f2bs(float f) {
    bf16 h = __float2bfloat16(f);
    return *reinterpret_cast<short*>(&h);
}
__device__ __forceinline__ float bs2f(unsigned s) {
    union { unsigned u; float f; } cv;
    cv.u = (s & 0xFFFFu) << 16;
    return cv.f;
}
__device__ __forceinline__ float fast_silu(float v) {
    return v * __builtin_amdgcn_rcpf(1.f + __expf(-v));
}

// ---- workspace layout (4-byte elements) ----
#define WS_HSUM 0                                      // N*32 f32 (ZERO)
#define WS_POOL (N_NODES * HID)                        // 4096 (ZERO)
#define WS_GFILL (WS_POOL + N_GRAPHS * K_SLOTS * HID)  // 256 (ZERO)
#define WS_ZERO_CNT (WS_GFILL + 256)
#define WS_S    (WS_GFILL + 256)                       // N*8
#define WS_FRAGS (WS_S + N_NODES * K_SLOTS)            // 1024 dwords (2048 shorts)
#define WS_DEG  (WS_FRAGS + 1024)                      // N
#define WS_BINNED (WS_DEG + N_NODES)                   // NBUCKET*BCAP
#define WS_EDAT (WS_BINNED + NBUCKET * BCAP)           // E uints (src | dst<<16)
#define WS_FLAGS (WS_EDAT + N_EDGES)                   // 2

// ---------------- prep: lane-parallel dtype detection + weight fragment build ----------------
__global__ void prep_kernel(const void* x, const int* ei,
                            const void* w1, const void* w2,
                            int* flags, short* frags)
{
    int t = threadIdx.x;   // 64
    // detection, one sample per lane
    unsigned short h = ((const unsigned short*)x)[2 * t];
    unsigned e = (h >> 7) & 0xFF;
    bool sane = ((h & 0x7FFF) == 0 || (e >= 100 && e <= 141));
    unsigned long long bs = __ballot(sane);
    int f0 = (__popcll(bs) >= 32) ? 1 : 0;     // 1: floats are bf16
    bool z = (ei[2 * t + 1] == 0);
    unsigned long long bz = __ballot(z);
    int f1 = (__popcll(bz) >= 60) ? 1 : 0;     // 1: ints are int64
    if (t == 0) { flags[0] = f0; flags[1] = f1; }

    int fbf = f0;
    int nl = t & 15, quad = (t >> 4) & 3;
#pragma unroll
    for (int j = 0; j < 8; j++) {
        int k = quad * 8 + j;
        frags[(0 * 64 + t) * 8 + j] = (k < 9) ? f2bs(ldf(w1, k * 32 + nl, fbf)) : (short)0;
        frags[(1 * 64 + t) * 8 + j] = (k < 9) ? f2bs(ldf(w1, k * 32 + 16 + nl, fbf)) : (short)0;
        frags[(2 * 64 + t) * 8 + j] = f2bs(ldf(w2, k * 32 + nl, fbf));
        frags[(3 * 64 + t) * 8 + j] = f2bs(ldf(w2, k * 32 + 16 + nl, fbf));
    }
}

// ---------------- pass 1: bin edges by dst>>8 (vectorized loads) ----------------
__global__ __launch_bounds__(256) void bin_kernel(
    const int* __restrict__ ei, int* __restrict__ gfill,
    unsigned* __restrict__ binned, const int* __restrict__ flags)
{
    const int i64 = flags[1];
    __shared__ int cnt[NBUCKET];
    __shared__ int cur[NBUCKET];
    int t = threadIdx.x;
    for (int i = t; i < NBUCKET; i += 256) cnt[i] = 0;
    __syncthreads();

    long e0 = (long)blockIdx.x * BIN_EPB;
    unsigned pk[16];
    if (!i64) {
        // N_EDGES % 4 == 0: int4 at e (multiple of 4) fully in-bounds iff e < N_EDGES
#pragma unroll
        for (int kk = 0; kk < 4; kk++) {
            long e = e0 + kk * 1024 + t * 4;
            if (e < N_EDGES) {
                int4 sv = *(const int4*)(ei + e);
                int4 dv = *(const int4*)(ei + N_EDGES + e);
                pk[kk * 4 + 0] = (unsigned)sv.x | ((unsigned)dv.x << 16);
                pk[kk * 4 + 1] = (unsigned)sv.y | ((unsigned)dv.y << 16);
                pk[kk * 4 + 2] = (unsigned)sv.z | ((unsigned)dv.z << 16);
                pk[kk * 4 + 3] = (unsigned)sv.w | ((unsigned)dv.w << 16);
                atomicAdd(&cnt[dv.x >> 8], 1);
                atomicAdd(&cnt[dv.y >> 8], 1);
                atomicAdd(&cnt[dv.z >> 8], 1);
                atomicAdd(&cnt[dv.w >> 8], 1);
            } else {
                pk[kk * 4 + 0] = pk[kk * 4 + 1] = pk[kk * 4 + 2] = pk[kk * 4 + 3] = 0xFFFFFFFFu;
            }
        }
    } else {
        // int64: int4 = 2 edges (lo,hi,lo,hi); N_EDGES % 2 == 0
#pragma unroll
        for (int kk = 0; kk < 8; kk++) {
            long e = e0 + kk * 512 + t * 2;
            if (e < N_EDGES) {
                int4 sv = *(const int4*)(ei + 2 * e);
                int4 dv = *(const int4*)(ei + 2 * (N_EDGES + e));
                pk[kk * 2 + 0] = (unsigned)sv.x | ((unsigned)dv.x << 16);
                pk[kk * 2 + 1] = (unsigned)sv.z | ((unsigned)dv.z << 16);
                atomicAdd(&cnt[dv.x >> 8], 1);
                atomicAdd(&cnt[dv.z >> 8], 1);
            } else {
                pk[kk * 2 + 0] = pk[kk * 2 + 1] = 0xFFFFFFFFu;
            }
        }
    }
    __syncthreads();
    for (int i = t; i < NBUCKET; i += 256)
        cur[i] = atomicAdd(&gfill[i], cnt[i]);
    __syncthreads();
    int nk = i64 ? 16 : 16;
#pragma unroll
    for (int k = 0; k < 16; k++) {
        if (k < nk && pk[k] != 0xFFFFFFFFu) {
            int b = pk[k] >> 24;
            int pos = atomicAdd(&cur[b], 1);
            binned[(long)b * BCAP + pos] = pk[k];
        }
    }
}

// ---------------- pass 2: per-bucket counting sort (with inline bucket scan) ----------------
__global__ __launch_bounds__(1024) void csr_kernel(
    const int* __restrict__ gfill, const unsigned* __restrict__ binned,
    unsigned* __restrict__ edat, int* __restrict__ deg)
{
    __shared__ int gsm[256];
    __shared__ int lcnt[256], lcur[256], sm[256];
    int b = blockIdx.x, t = threadIdx.x;
    if (t < 256) gsm[t] = (t < NBUCKET) ? gfill[t] : 0;
    if (t < 256) lcnt[t] = 0;
    __syncthreads();
    for (int s = 1; s < 256; s <<= 1) {
        int v = 0;
        if (t < 256) v = gsm[t] + ((t >= s) ? gsm[t - s] : 0);
        __syncthreads();
        if (t < 256) gsm[t] = v;
        __syncthreads();
    }
    int cnt = gfill[b];
    int base = gsm[b] - cnt;   // exclusive prefix
    const unsigned* bp = binned + (long)b * BCAP;
    for (int i = t; i < cnt; i += 1024)
        atomicAdd(&lcnt[(bp[i] >> 16) & 255], 1);
    __syncthreads();
    if (t < 256) sm[t] = lcnt[t];
    __syncthreads();
    for (int s = 1; s < 256; s <<= 1) {
        int v = 0;
        if (t < 256) v = sm[t] + ((t >= s) ? sm[t - s] : 0);
        __syncthreads();
        if (t < 256) sm[t] = v;
        __syncthreads();
    }
    if (t < 256) {
        lcur[t] = sm[t] - lcnt[t];
        int n = b * 256 + t;
        if (n < N_NODES) deg[n] = lcnt[t];
    }
    __syncthreads();
    for (int i = t; i < cnt; i += 1024) {
        unsigned pk = bp[i];
        int pos = base + atomicAdd(&lcur[(pk >> 16) & 255], 1);
        edat[pos] = pk;
    }
}

// ---------------- MFMA msg MLP + transposed segmented reduction ----------------
__global__ __launch_bounds__(256) void msg_agg_kernel(
    const void* __restrict__ x, const void* __restrict__ pos,
    const unsigned* __restrict__ edat, const short* __restrict__ frags,
    const void* __restrict__ b1, const void* __restrict__ b2,
    float* __restrict__ hsum, const int* __restrict__ flags)
{
    const int fbf = flags[0];
    __shared__ short buf[256 * 34];    // 17 KB: A1 (stride 34) -> A2 -> msgT (32 x stride 258)
    __shared__ int sdL[256];
    __shared__ int runstart[256];
    __shared__ int wcnt[4];

    int t = threadIdx.x;
    int lane = t & 63, wv = t >> 6;
    int nl = lane & 15, quad = lane >> 4;

    // weight B-fragments: precomputed, 4 coalesced 16B loads
    const short8 w1f0 = *(const short8*)&frags[(0 * 64 + lane) * 8];
    const short8 w1f1 = *(const short8*)&frags[(1 * 64 + lane) * 8];
    const short8 w2f0 = *(const short8*)&frags[(2 * 64 + lane) * 8];
    const short8 w2f1 = *(const short8*)&frags[(3 * 64 + lane) * 8];
    float b1c0 = ldf(b1, nl, fbf), b1c1 = ldf(b1, 16 + nl, fbf);
    float b2c0 = ldf(b2, nl, fbf), b2c1 = ldf(b2, 16 + nl, fbf);

    // ---- decode edge, gather inputs ----
    long i = (long)blockIdx.x * 256 + t;
    unsigned ed = edat[i];
    int src = (int)(ed & 0xFFFFu);
    int dst = (int)(ed >> 16);
    sdL[t] = dst;

    float in[9];
    if (fbf) {
        const unsigned* xb = (const unsigned*)x;
        unsigned d0 = xb[dst * 2], d1 = xb[dst * 2 + 1];
        unsigned s0 = xb[src * 2], s1 = xb[src * 2 + 1];
        in[0] = bs2f(d0); in[1] = bs2f(d0 >> 16);
        in[2] = bs2f(d1); in[3] = bs2f(d1 >> 16);
        in[4] = bs2f(s0); in[5] = bs2f(s0 >> 16);
        in[6] = bs2f(s1); in[7] = bs2f(s1 >> 16);
        const unsigned short* pp = (const unsigned short*)pos;
        float dx = bs2f(pp[3 * src + 0]) - bs2f(pp[3 * dst + 0]);
        float dy = bs2f(pp[3 * src + 1]) - bs2f(pp[3 * dst + 1]);
        float dz = bs2f(pp[3 * src + 2]) - bs2f(pp[3 * dst + 2]);
        in[8] = sqrtf(dx * dx + dy * dy + dz * dz);
    } else {
        float4 xd = ((const float4*)x)[dst];
        float4 xs = ((const float4*)x)[src];
        in[0] = xd.x; in[1] = xd.y; in[2] = xd.z; in[3] = xd.w;
        in[4] = xs.x; in[5] = xs.y; in[6] = xs.z; in[7] = xs.w;
        const float* pf = (const float*)pos;
        float dx = pf[3 * src + 0] - pf[3 * dst + 0];
        float dy = pf[3 * src + 1] - pf[3 * dst + 1];
        float dz = pf[3 * src + 2] - pf[3 * dst + 2];
        in[8] = sqrtf(dx * dx + dy * dy + dz * dz);
    }

    // ---- stage A1 (K=32; 5 data dwords + 11 zero dwords) ----
    {
        unsigned* rowp = (unsigned*)&buf[t * 34];
        short v9 = f2bs(in[8]);
        rowp[0] = (unsigned)(unsigned short)f2bs(in[0]) | ((unsigned)(unsigned short)f2bs(in[1]) << 16);
        rowp[1] = (unsigned)(unsigned short)f2bs(in[2]) | ((unsigned)(unsigned short)f2bs(in[3]) << 16);
        rowp[2] = (unsigned)(unsigned short)f2bs(in[4]) | ((unsigned)(unsigned short)f2bs(in[5]) << 16);
        rowp[3] = (unsigned)(unsigned short)f2bs(in[6]) | ((unsigned)(unsigned short)f2bs(in[7]) << 16);
        rowp[4] = (unsigned)(unsigned short)v9;
#pragma unroll
        for (int p = 5; p < 16; p++) rowp[p] = 0;
    }
    __syncthreads();

    int rb = wv * 64;
    short8 af[4];
#pragma unroll
    for (int mt = 0; mt < 4; mt++) {
        int row = rb + mt * 16 + nl;
        af[mt] = *(short8*)&buf[row * 34 + quad * 8];
    }
    __syncthreads();

    // ---- layer1 MFMA + silu -> A2 back into buf ----
    f32x4 zero = {0.f, 0.f, 0.f, 0.f};
#pragma unroll
    for (int mt = 0; mt < 4; mt++) {
        f32x4 c0 = __builtin_amdgcn_mfma_f32_16x16x32_bf16(af[mt], w1f0, zero, 0, 0, 0);
        f32x4 c1 = __builtin_amdgcn_mfma_f32_16x16x32_bf16(af[mt], w1f1, zero, 0, 0, 0);
#pragma unroll
        for (int r = 0; r < 4; r++) {
            int row = rb + mt * 16 + quad * 4 + r;
            buf[row * 34 + nl] = f2bs(fast_silu(c0[r] + b1c0));
            buf[row * 34 + 16 + nl] = f2bs(fast_silu(c1[r] + b1c1));
        }
    }
    __syncthreads();

    short8 a2f[4];
#pragma unroll
    for (int mt = 0; mt < 4; mt++) {
        int row = rb + mt * 16 + nl;
        a2f[mt] = *(short8*)&buf[row * 34 + quad * 8];
    }
    __syncthreads();

    // ---- layer2 MFMA -> TRANSPOSED msgT[c*258 + row] (overlays buf) ----
    short* msgT = buf;   // 32*258 = 8256 <= 8704 shorts
#pragma unroll
    for (int mt = 0; mt < 4; mt++) {
        f32x4 d0 = __builtin_amdgcn_mfma_f32_16x16x32_bf16(a2f[mt], w2f0, zero, 0, 0, 0);
        f32x4 d1 = __builtin_amdgcn_mfma_f32_16x16x32_bf16(a2f[mt], w2f1, zero, 0, 0, 0);
#pragma unroll
        for (int r = 0; r < 4; r++) {
            int orow = rb + mt * 16 + quad * 4 + r;
            msgT[nl * 258 + orow] = f2bs(d0[r] + b2c0);
            msgT[(nl + 16) * 258 + orow] = f2bs(d1[r] + b2c1);
        }
    }
    __syncthreads();

    // ---- run detection + segmented reduction (consecutive-address reads) ----
    bool head = (t == 0) || (sdL[t] != sdL[t - 1]);
    unsigned long long bal = __ballot(head);
    if (lane == 0) wcnt[wv] = __popcll(bal);
    __syncthreads();
    int nruns = wcnt[0] + wcnt[1] + wcnt[2] + wcnt[3];
    if (head) {
        int base = 0;
        for (int q = 0; q < wv; q++) base += wcnt[q];
        int myrun = base + __popcll(bal & (((unsigned long long)1 << lane) - 1ull));
        runstart[myrun] = t;
    }
    __syncthreads();

    int g = t >> 5, c = t & 31;
    const short* col = &msgT[c * 258];
    const unsigned* colu = (const unsigned*)col;   // c*258 even -> dword aligned
    for (int r = g; r < nruns; r += 8) {
        int s0 = runstart[r];
        int s1 = (r + 1 < nruns) ? runstart[r + 1] : 256;
        float acc = 0.f;
        int j = s0;
        if (j & 1) { acc += bs2f((unsigned)(unsigned short)col[j]); j++; }
        for (; j + 1 < s1; j += 2) {
            unsigned d = colu[j >> 1];
            acc += bs2f(d) + bs2f(d >> 16);
        }
        if (j < s1) acc += bs2f((unsigned)(unsigned short)col[j]);
        int node = sdL[s0];
        if (s0 == 0 || s1 == 256) atomicAdd(&hsum[(size_t)node * HID + c], acc);
        else hsum[(size_t)node * HID + c] = acc;
    }
}

// ---------------- fused normalize + pool softmax + soft pooling ----------------
__global__ __launch_bounds__(256) void pool_softmax_kernel(
    const float* __restrict__ hsum, const int* __restrict__ deg,
    const int* __restrict__ batch,
    const void* __restrict__ pw, const void* __restrict__ pb,
    float* __restrict__ s, float* __restrict__ pooled,
    const int* __restrict__ flags)
{
    const int fbf = flags[0], i64 = flags[1];
    __shared__ float spw[HID * K_SLOTS], spb[K_SLOTS];
    __shared__ float hL[256 * 33];   // padded stride 33
    __shared__ float sL[256 * 9];    // padded stride 9
    __shared__ float invL[256];
    __shared__ int gL[256];
    int t = threadIdx.x;
    int n0 = blockIdx.x * 256;
    spw[t] = ldf(pw, t, fbf);
    if (t < K_SLOTS) spb[t] = ldf(pb, t, fbf);
    {
        int n = n0 + t;
        gL[t] = ldi(batch, (n < N_NODES) ? n : (N_NODES - 1), i64);
        invL[t] = (n < N_NODES) ? __builtin_amdgcn_rcpf(fmaxf((float)deg[n], 1.f)) : 0.f;
    }
    __syncthreads();
    for (int i = t; i < 256 * HID; i += 256) {
        int row = i >> 5, col = i & 31;
        int n = n0 + row;
        hL[row * 33 + col] = (n < N_NODES) ? hsum[(size_t)n0 * HID + i] * invL[row] : 0.f;
    }
    __syncthreads();

    // softmax per node
    if (n0 + t < N_NODES) {
        float l[K_SLOTS];
#pragma unroll
        for (int k = 0; k < K_SLOTS; k++) l[k] = spb[k];
#pragma unroll
        for (int j = 0; j < HID; j++) {
            float v = hL[t * 33 + j];
#pragma unroll
            for (int k = 0; k < K_SLOTS; k++) l[k] = fmaf(v, spw[j * K_SLOTS + k], l[k]);
        }
        float mx = l[0];
#pragma unroll
        for (int k = 1; k < K_SLOTS; k++) mx = fmaxf(mx, l[k]);
        float sum = 0.f;
#pragma unroll
        for (int k = 0; k < K_SLOTS; k++) { l[k] = __expf(l[k] - mx); sum += l[k]; }
        float is = __builtin_amdgcn_rcpf(sum);
#pragma unroll
        for (int k = 0; k < K_SLOTS; k++) { l[k] *= is; sL[t * 9 + k] = l[k]; }
        float4 v0 = make_float4(l[0], l[1], l[2], l[3]);
        float4 v1 = make_float4(l[4], l[5], l[6], l[7]);
        float4* sp = (float4*)(s + (size_t)(n0 + t) * K_SLOTS);
        sp[0] = v0; sp[1] = v1;
    } else {
#pragma unroll
        for (int k = 0; k < K_SLOTS; k++) sL[t * 9 + k] = 0.f;
    }
    __syncthreads();

    // pooling: thread t owns (k,c)
    int k = t >> 5, c = t & 31;
    float acc = 0.f;
    int curg = gL[0];
    int lim = min(256, N_NODES - n0);
    for (int i = 0; i < lim; i++) {
        int g = gL[i];
        if (g != curg) {
            atomicAdd(&pooled[curg * 256 + t], acc);
            acc = 0.f;
            curg = g;
        }
        acc = fmaf(sL[i * 9 + k], hL[i * 33 + c], acc);
    }
    atomicAdd(&pooled[curg * 256 + t], acc);
}

// ---------------- decode (with fused z) ----------------
__global__ __launch_bounds__(256) void decode_kernel(
    const float* __restrict__ s, const float* __restrict__ pooled,
    const void* __restrict__ tw, const void* __restrict__ tb,
    const void* __restrict__ dw1, const void* __restrict__ db1,
    const void* __restrict__ dw2, const void* __restrict__ db2,
    void* __restrict__ out, const int* __restrict__ flags)
{
    const int fbf = flags[0];
    __shared__ float zb[K_SLOTS * LATENT];
    __shared__ float w1[LATENT * HID], b1s[HID], w2[HID * LATENT], b2s[LATENT];
    int b = blockIdx.y;
    int t = threadIdx.x;
    if (t < K_SLOTS * LATENT) {        // z = pooled @ toz_w + toz_b (inline)
        int k = t >> 2, d = t & 3;
        float acc = ldf(tb, d, fbf);
        for (int c = 0; c < HID; c++)
            acc = fmaf(pooled[b * 256 + k * 32 + c], ldf(tw, c * 4 + d, fbf), acc);
        zb[t] = acc;
    }
    if (t < LATENT * HID) w1[t] = ldf(dw1, t, fbf);
    else if (t < LATENT * HID + HID * LATENT) w2[t - LATENT * HID] = ldf(dw2, t - LATENT * HID, fbf);
    if (t < HID) b1s[t] = ldf(db1, t, fbf);
    if (t < LATENT) b2s[t] = ldf(db2, t, fbf);
    __syncthreads();

    int n = blockIdx.x * 256 + t;
    if (n >= N_NODES) return;
    float sv[K_SLOTS];
#pragma unroll
    for (int k = 0; k < K_SLOTS; k++) sv[k] = s[(size_t)n * K_SLOTS + k];
    float q[LATENT];
#pragma unroll
    for (int d = 0; d < LATENT; d++) {
        float a = 0.f;
#pragma unroll
        for (int k = 0; k < K_SLOTS; k++) a = fmaf(sv[k], zb[k * LATENT + d], a);
        q[d] = a;
    }
    float t1[HID];
#pragma unroll
    for (int j = 0; j < HID; j++) t1[j] = b1s[j];
#pragma unroll
    for (int d = 0; d < LATENT; d++) {
        float v = q[d];
#pragma unroll
        for (int j = 0; j < HID; j++) t1[j] = fmaf(v, w1[d * HID + j], t1[j]);
    }
#pragma unroll
    for (int j = 0; j < HID; j++) t1[j] = fast_silu(t1[j]);
    float o[LATENT];
#pragma unroll
    for (int d = 0; d < LATENT; d++) o[d] = b2s[d];
#pragma unroll
    for (int j = 0; j < HID; j++) {
        float v = t1[j];
#pragma unroll
        for (int d = 0; d < LATENT; d++) o[d] = fmaf(v, w2[j * LATENT + d], o[d]);
    }
    if (fbf) {
        union { bf16 h[4]; uint2 u; } pk;
#pragma unroll
        for (int d = 0; d < LATENT; d++) pk.h[d] = __float2bfloat16(o[d]);
        ((uint2*)out)[(size_t)b * N_NODES + n] = pk.u;
    } else {
        float4 v4 = make_float4(o[0], o[1], o[2], o[3]);
        ((float4*)out)[(size_t)b * N_NODES + n] = v4;
    }
}

extern "C" void kernel_launch(void* const* d_in, const int* in_sizes, int n_in,
                              void* d_out, int out_size, void* d_ws, size_t ws_size,
                              hipStream_t stream) {
    const void* x      = d_in[0];
    const void* pos    = d_in[1];
    const int*  ei     = (const int*)d_in[2];
    const int*  batch  = (const int*)d_in[3];
    const void* enc_w1 = d_in[4];
    const void* enc_b1 = d_in[5];
    const void* enc_w2 = d_in[6];
    const void* enc_b2 = d_in[7];
    const void* pool_w = d_in[8];
    const void* pool_b = d_in[9];
    const void* toz_w  = d_in[10];
    const void* toz_b  = d_in[11];
    const void* dec_w1 = d_in[12];
    const void* dec_b1 = d_in[13];
    const void* dec_w2 = d_in[14];
    const void* dec_b2 = d_in[15];

    float* ws = (float*)d_ws;
    float* hsum   = ws + WS_HSUM;
    float* pooled = ws + WS_POOL;
    int*   gfill  = (int*)(ws + WS_GFILL);
    float* s      = ws + WS_S;
    short* frags  = (short*)(ws + WS_FRAGS);
    int*   deg    = (int*)(ws + WS_DEG);
    unsigned* binned = (unsigned*)(ws + WS_BINNED);
    unsigned* edat   = (unsigned*)(ws + WS_EDAT);
    int*   flags  = (int*)(ws + WS_FLAGS);

    hipMemsetAsync(d_ws, 0, (size_t)WS_ZERO_CNT * 4, stream);
    prep_kernel<<<1, 64, 0, stream>>>(x, ei, enc_w1, enc_w2, flags, frags);

    int gbin = (N_EDGES + BIN_EPB - 1) / BIN_EPB;
    bin_kernel<<<gbin, 256, 0, stream>>>(ei, gfill, binned, flags);
    csr_kernel<<<NBUCKET, 1024, 0, stream>>>(gfill, binned, edat, deg);

    msg_agg_kernel<<<N_EDGES / 256, 256, 0, stream>>>(
        x, pos, edat, frags, enc_b1, enc_b2, hsum, flags);

    pool_softmax_kernel<<<NBUCKET, 256, 0, stream>>>(
        hsum, deg, batch, pool_w, pool_b, s, pooled, flags);
    dim3 dg((N_NODES + 255) / 256, N_GRAPHS);
    decode_kernel<<<dg, 256, 0, stream>>>(
        s, pooled, toz_w, toz_b, dec_w1, dec_b1, dec_w2, dec_b2, d_out, flags);
}

// Round 11
// 212.715 us; speedup vs baseline: 13.8100x; 1.0084x over previous
//
#include <hip/hip_runtime.h>
#include <hip/hip_bf16.h>

#define N_NODES 50000
#define N_EDGES 1600000
#define N_GRAPHS 16
#define K_SLOTS 8
#define LATENT 4
#define HID 32
#define NBUCKET 196      // ceil(N_NODES/256), bucket = dst>>8
#define BCAP 10240       // bucket capacity (mean 8163, sigma ~90 -> 22 sigma)
#define BIN_EPB 4096     // edges per bin block

typedef __hip_bfloat16 bf16;
typedef __attribute__((ext_vector_type(8))) short short8;
typedef __attribute__((ext_vector_type(4))) float f32x4;

// dtype-agnostic loads (flag is wave-uniform)
__device__ __forceinline__ float ldf(const void* p, long i, int isbf) {
    return isbf ? __bfloat162float(((const bf16*)p)[i]) : ((const float*)p)[i];
}
__device__ __forceinline__ int ldi(const int* p, long i, int is64) {
    return is64 ? p[2 * i] : p[i];
}
__device__ __forceinline__ short f2bs(float f) {
    bf16 h = __float2bfloat16(f);
    return *reinterpret_cast<short*>(&h);
}
__device__ __forceinline__ unsigned pk2(float a, float b) {
    __hip_bfloat162 h2 = __float22bfloat162_rn(make_float2(a, b));  // v_cvt_pk_bf16_f32 on gfx950
    return *reinterpret_cast<unsigned*>(&h2);
}
__device__ __forceinline__ float bs2f(unsigned s) {
    union { unsigned u; float f; } cv;
    cv.u = (s & 0xFFFFu) << 16;
    return cv.f;
}
__device__ __forceinline__ float fast_silu(float v) {
    return v * __builtin_amdgcn_rcpf(1.f + __expf(-v));
}

// ---- workspace layout (4-byte elements) ----
#define WS_POOL 0                                      // 4096 (ZERO via memset)
#define WS_GFILL 4096                                  // 256 (ZERO via memset)
#define WS_ZERO_CNT 4352
#define WS_HSUM 4352                                   // N*32 f32 (zeroed by csr_kernel)
#define WS_S    (WS_HSUM + N_NODES * HID)              // N*8
#define WS_FRAGS (WS_S + N_NODES * K_SLOTS)            // 1024 dwords (2048 shorts)
#define WS_DEG  (WS_FRAGS + 1024)                      // N (fully written by csr)
#define WS_BINNED (WS_DEG + N_NODES)                   // NBUCKET*BCAP
#define WS_EDAT (WS_BINNED + NBUCKET * BCAP)           // E uints (src | dst<<16)
#define WS_FLAGS (WS_EDAT + N_EDGES)                   // 2

// ---------------- prep: lane-parallel dtype detection + weight fragment build ----------------
__global__ void prep_kernel(const void* x, const int* ei,
                            const void* w1, const void* w2,
                            int* flags, short* frags)
{
    int t = threadIdx.x;   // 64
    unsigned short h = ((const unsigned short*)x)[2 * t];
    unsigned e = (h >> 7) & 0xFF;
    bool sane = ((h & 0x7FFF) == 0 || (e >= 100 && e <= 141));
    unsigned long long bs = __ballot(sane);
    int f0 = (__popcll(bs) >= 32) ? 1 : 0;     // 1: floats are bf16
    bool z = (ei[2 * t + 1] == 0);
    unsigned long long bz = __ballot(z);
    int f1 = (__popcll(bz) >= 60) ? 1 : 0;     // 1: ints are int64
    if (t == 0) { flags[0] = f0; flags[1] = f1; }

    int fbf = f0;
    int nl = t & 15, quad = (t >> 4) & 3;
#pragma unroll
    for (int j = 0; j < 8; j++) {
        int k = quad * 8 + j;
        frags[(0 * 64 + t) * 8 + j] = (k < 9) ? f2bs(ldf(w1, k * 32 + nl, fbf)) : (short)0;
        frags[(1 * 64 + t) * 8 + j] = (k < 9) ? f2bs(ldf(w1, k * 32 + 16 + nl, fbf)) : (short)0;
        frags[(2 * 64 + t) * 8 + j] = f2bs(ldf(w2, k * 32 + nl, fbf));
        frags[(3 * 64 + t) * 8 + j] = f2bs(ldf(w2, k * 32 + 16 + nl, fbf));
    }
}

// ---------------- pass 1: bin edges by dst>>8, block-local sort for coalesced write-out ----------------
__global__ __launch_bounds__(256) void bin_kernel(
    const int* __restrict__ ei, int* __restrict__ gfill,
    unsigned* __restrict__ binned, const int* __restrict__ flags)
{
    const int i64 = flags[1];
    __shared__ int cnt[NBUCKET];       // block histogram
    __shared__ int lbase[NBUCKET];     // local exclusive prefix
    __shared__ int lcur[NBUCKET];      // scatter cursor
    __shared__ int gbase[NBUCKET];     // reserved global start per bucket
    __shared__ int tmp[256];
    __shared__ unsigned sorted[BIN_EPB];   // 16 KB
    int t = threadIdx.x;
    for (int i = t; i < NBUCKET; i += 256) cnt[i] = 0;
    __syncthreads();

    long e0 = (long)blockIdx.x * BIN_EPB;
    unsigned pk[16];
    if (!i64) {
#pragma unroll
        for (int kk = 0; kk < 4; kk++) {
            long e = e0 + kk * 1024 + t * 4;
            if (e < N_EDGES) {
                int4 sv = *(const int4*)(ei + e);
                int4 dv = *(const int4*)(ei + N_EDGES + e);
                pk[kk * 4 + 0] = (unsigned)sv.x | ((unsigned)dv.x << 16);
                pk[kk * 4 + 1] = (unsigned)sv.y | ((unsigned)dv.y << 16);
                pk[kk * 4 + 2] = (unsigned)sv.z | ((unsigned)dv.z << 16);
                pk[kk * 4 + 3] = (unsigned)sv.w | ((unsigned)dv.w << 16);
                atomicAdd(&cnt[dv.x >> 8], 1);
                atomicAdd(&cnt[dv.y >> 8], 1);
                atomicAdd(&cnt[dv.z >> 8], 1);
                atomicAdd(&cnt[dv.w >> 8], 1);
            } else {
                pk[kk * 4 + 0] = pk[kk * 4 + 1] = pk[kk * 4 + 2] = pk[kk * 4 + 3] = 0xFFFFFFFFu;
            }
        }
    } else {
#pragma unroll
        for (int kk = 0; kk < 8; kk++) {
            long e = e0 + kk * 512 + t * 2;
            if (e < N_EDGES) {
                int4 sv = *(const int4*)(ei + 2 * e);
                int4 dv = *(const int4*)(ei + 2 * (N_EDGES + e));
                pk[kk * 2 + 0] = (unsigned)sv.x | ((unsigned)dv.x << 16);
                pk[kk * 2 + 1] = (unsigned)sv.z | ((unsigned)dv.z << 16);
                atomicAdd(&cnt[dv.x >> 8], 1);
                atomicAdd(&cnt[dv.z >> 8], 1);
            } else {
                pk[kk * 2 + 0] = pk[kk * 2 + 1] = 0xFFFFFFFFu;
            }
        }
    }
    __syncthreads();

    // local exclusive scan of cnt
    tmp[t] = (t < NBUCKET) ? cnt[t] : 0;
    __syncthreads();
    for (int s = 1; s < 256; s <<= 1) {
        int v = tmp[t] + ((t >= s) ? tmp[t - s] : 0);
        __syncthreads();
        tmp[t] = v;
        __syncthreads();
    }
    int total = tmp[255];
    if (t < NBUCKET) {
        int ex = tmp[t] - cnt[t];
        lbase[t] = ex;
        lcur[t] = ex;
        gbase[t] = atomicAdd(&gfill[t], cnt[t]);   // reserve global range
    }
    __syncthreads();

    // local scatter (sort by bucket)
#pragma unroll
    for (int k = 0; k < 16; k++) {
        if (pk[k] != 0xFFFFFFFFu) {
            int b = pk[k] >> 24;
            int p = atomicAdd(&lcur[b], 1);
            sorted[p] = pk[k];
        }
    }
    __syncthreads();

    // coalesced write-out: consecutive j within a bucket run -> consecutive global dwords
    for (int j = t; j < total; j += 256) {
        unsigned ed = sorted[j];
        int b = ed >> 24;
        binned[(long)b * BCAP + gbase[b] + (j - lbase[b])] = ed;
    }
}

// ---------------- pass 2: per-bucket counting sort (with inline bucket scan) + hsum zero ----------------
__global__ __launch_bounds__(1024) void csr_kernel(
    const int* __restrict__ gfill, const unsigned* __restrict__ binned,
    unsigned* __restrict__ edat, int* __restrict__ deg, float* __restrict__ hsum)
{
    __shared__ int gsm[256];
    __shared__ int lcnt[256], lcur[256], sm[256];
    int b = blockIdx.x, t = threadIdx.x;
    if (t < 256) gsm[t] = (t < NBUCKET) ? gfill[t] : 0;
    if (t < 256) lcnt[t] = 0;
    __syncthreads();
    for (int s = 1; s < 256; s <<= 1) {
        int v = 0;
        if (t < 256) v = gsm[t] + ((t >= s) ? gsm[t - s] : 0);
        __syncthreads();
        if (t < 256) gsm[t] = v;
        __syncthreads();
    }
    // zero this bucket's hsum rows (before msg_agg)
    {
        int nvalid = min(256, N_NODES - b * 256);
        if (nvalid > 0) {
            float4* hz = (float4*)(hsum + (size_t)b * 256 * HID);
            float4 z4 = make_float4(0.f, 0.f, 0.f, 0.f);
            for (int i = t; i < nvalid * 8; i += 1024) hz[i] = z4;
        }
    }
    int cnt = gfill[b];
    int base = gsm[b] - cnt;   // exclusive prefix
    const unsigned* bp = binned + (long)b * BCAP;
    for (int i = t; i < cnt; i += 1024)
        atomicAdd(&lcnt[(bp[i] >> 16) & 255], 1);
    __syncthreads();
    if (t < 256) sm[t] = lcnt[t];
    __syncthreads();
    for (int s = 1; s < 256; s <<= 1) {
        int v = 0;
        if (t < 256) v = sm[t] + ((t >= s) ? sm[t - s] : 0);
        __syncthreads();
        if (t < 256) sm[t] = v;
        __syncthreads();
    }
    if (t < 256) {
        lcur[t] = sm[t] - lcnt[t];
        int n = b * 256 + t;
        if (n < N_NODES) deg[n] = lcnt[t];
    }
    __syncthreads();
    for (int i = t; i < cnt; i += 1024) {
        unsigned pk = bp[i];
        int pos = base + atomicAdd(&lcur[(pk >> 16) & 255], 1);
        edat[pos] = pk;
    }
}

// ---------------- MFMA msg MLP + transposed segmented reduction ----------------
__global__ __launch_bounds__(256) void msg_agg_kernel(
    const void* __restrict__ x, const void* __restrict__ pos,
    const unsigned* __restrict__ edat, const short* __restrict__ frags,
    const void* __restrict__ b1, const void* __restrict__ b2,
    float* __restrict__ hsum, const int* __restrict__ flags)
{
    const int fbf = flags[0];
    __shared__ short buf[256 * 34];    // 17 KB: A1 (stride 34) -> A2 -> msgT (32 x stride 258)
    __shared__ int sdL[256];
    __shared__ int runstart[256];
    __shared__ int wcnt[4];

    int t = threadIdx.x;
    int lane = t & 63, wv = t >> 6;
    int nl = lane & 15, quad = lane >> 4;

    // weight B-fragments: precomputed, 4 coalesced 16B loads
    const short8 w1f0 = *(const short8*)&frags[(0 * 64 + lane) * 8];
    const short8 w1f1 = *(const short8*)&frags[(1 * 64 + lane) * 8];
    const short8 w2f0 = *(const short8*)&frags[(2 * 64 + lane) * 8];
    const short8 w2f1 = *(const short8*)&frags[(3 * 64 + lane) * 8];
    float b1c0 = ldf(b1, nl, fbf), b1c1 = ldf(b1, 16 + nl, fbf);
    float b2c0 = ldf(b2, nl, fbf), b2c1 = ldf(b2, 16 + nl, fbf);

    // ---- decode edge, gather inputs ----
    long i = (long)blockIdx.x * 256 + t;
    unsigned ed = edat[i];
    int src = (int)(ed & 0xFFFFu);
    int dst = (int)(ed >> 16);
    sdL[t] = dst;

    float in[9];
    if (fbf) {
        const unsigned* xb = (const unsigned*)x;
        unsigned d0 = xb[dst * 2], d1 = xb[dst * 2 + 1];
        unsigned s0 = xb[src * 2], s1 = xb[src * 2 + 1];
        in[0] = bs2f(d0); in[1] = bs2f(d0 >> 16);
        in[2] = bs2f(d1); in[3] = bs2f(d1 >> 16);
        in[4] = bs2f(s0); in[5] = bs2f(s0 >> 16);
        in[6] = bs2f(s1); in[7] = bs2f(s1 >> 16);
        const unsigned short* pp = (const unsigned short*)pos;
        float dx = bs2f(pp[3 * src + 0]) - bs2f(pp[3 * dst + 0]);
        float dy = bs2f(pp[3 * src + 1]) - bs2f(pp[3 * dst + 1]);
        float dz = bs2f(pp[3 * src + 2]) - bs2f(pp[3 * dst + 2]);
        in[8] = sqrtf(dx * dx + dy * dy + dz * dz);
    } else {
        float4 xd = ((const float4*)x)[dst];
        float4 xs = ((const float4*)x)[src];
        in[0] = xd.x; in[1] = xd.y; in[2] = xd.z; in[3] = xd.w;
        in[4] = xs.x; in[5] = xs.y; in[6] = xs.z; in[7] = xs.w;
        const float* pf = (const float*)pos;
        float dx = pf[3 * src + 0] - pf[3 * dst + 0];
        float dy = pf[3 * src + 1] - pf[3 * dst + 1];
        float dz = pf[3 * src + 2] - pf[3 * dst + 2];
        in[8] = sqrtf(dx * dx + dy * dy + dz * dz);
    }

    // ---- stage A1 (K=32; 5 packed data dwords + 11 zero dwords) ----
    {
        unsigned* rowp = (unsigned*)&buf[t * 34];
        rowp[0] = pk2(in[0], in[1]);
        rowp[1] = pk2(in[2], in[3]);
        rowp[2] = pk2(in[4], in[5]);
        rowp[3] = pk2(in[6], in[7]);
        rowp[4] = pk2(in[8], 0.f);
#pragma unroll
        for (int p = 5; p < 16; p++) rowp[p] = 0;
    }
    __syncthreads();

    int rb = wv * 64;
    short8 af[4];
#pragma unroll
    for (int mt = 0; mt < 4; mt++) {
        int row = rb + mt * 16 + nl;
        af[mt] = *(short8*)&buf[row * 34 + quad * 8];
    }
    __syncthreads();

    // ---- layer1 MFMA + silu -> A2 back into buf ----
    f32x4 zero = {0.f, 0.f, 0.f, 0.f};
#pragma unroll
    for (int mt = 0; mt < 4; mt++) {
        f32x4 c0 = __builtin_amdgcn_mfma_f32_16x16x32_bf16(af[mt], w1f0, zero, 0, 0, 0);
        f32x4 c1 = __builtin_amdgcn_mfma_f32_16x16x32_bf16(af[mt], w1f1, zero, 0, 0, 0);
#pragma unroll
        for (int r = 0; r < 4; r++) {
            int row = rb + mt * 16 + quad * 4 + r;
            buf[row * 34 + nl] = f2bs(fast_silu(c0[r] + b1c0));
            buf[row * 34 + 16 + nl] = f2bs(fast_silu(c1[r] + b1c1));
        }
    }
    __syncthreads();

    short8 a2f[4];
#pragma unroll
    for (int mt = 0; mt < 4; mt++) {
        int row = rb + mt * 16 + nl;
        a2f[mt] = *(short8*)&buf[row * 34 + quad * 8];
    }
    __syncthreads();

    // ---- layer2 MFMA -> TRANSPOSED msgT[c*258 + row], packed dword writes ----
    short* msgT = buf;   // 32*258 = 8256 <= 8704 shorts
#pragma unroll
    for (int mt = 0; mt < 4; mt++) {
        f32x4 d0 = __builtin_amdgcn_mfma_f32_16x16x32_bf16(a2f[mt], w2f0, zero, 0, 0, 0);
        f32x4 d1 = __builtin_amdgcn_mfma_f32_16x16x32_bf16(a2f[mt], w2f1, zero, 0, 0, 0);
        int ob = rb + mt * 16 + quad * 4;            // even -> dword aligned
        unsigned* c0p = (unsigned*)&msgT[nl * 258 + ob];
        unsigned* c1p = (unsigned*)&msgT[(nl + 16) * 258 + ob];
        c0p[0] = pk2(d0[0] + b2c0, d0[1] + b2c0);
        c0p[1] = pk2(d0[2] + b2c0, d0[3] + b2c0);
        c1p[0] = pk2(d1[0] + b2c1, d1[1] + b2c1);
        c1p[1] = pk2(d1[2] + b2c1, d1[3] + b2c1);
    }
    __syncthreads();

    // ---- run detection + segmented reduction (consecutive-address reads) ----
    bool head = (t == 0) || (sdL[t] != sdL[t - 1]);
    unsigned long long bal = __ballot(head);
    if (lane == 0) wcnt[wv] = __popcll(bal);
    __syncthreads();
    int nruns = wcnt[0] + wcnt[1] + wcnt[2] + wcnt[3];
    if (head) {
        int base = 0;
        for (int q = 0; q < wv; q++) base += wcnt[q];
        int myrun = base + __popcll(bal & (((unsigned long long)1 << lane) - 1ull));
        runstart[myrun] = t;
    }
    __syncthreads();

    int g = t >> 5, c = t & 31;
    const short* col = &msgT[c * 258];
    const unsigned* colu = (const unsigned*)col;
    for (int r = g; r < nruns; r += 8) {
        int s0 = runstart[r];
        int s1 = (r + 1 < nruns) ? runstart[r + 1] : 256;
        float acc = 0.f;
        int j = s0;
        if (j & 1) { acc += bs2f((unsigned)(unsigned short)col[j]); j++; }
        for (; j + 1 < s1; j += 2) {
            unsigned d = colu[j >> 1];
            acc += bs2f(d) + bs2f(d >> 16);
        }
        if (j < s1) acc += bs2f((unsigned)(unsigned short)col[j]);
        int node = sdL[s0];
        if (s0 == 0 || s1 == 256) atomicAdd(&hsum[(size_t)node * HID + c], acc);
        else hsum[(size_t)node * HID + c] = acc;
    }
}

// ---------------- fused normalize + pool softmax + soft pooling ----------------
__global__ __launch_bounds__(256) void pool_softmax_kernel(
    const float* __restrict__ hsum, const int* __restrict__ deg,
    const int* __restrict__ batch,
    const void* __restrict__ pw, const void* __restrict__ pb,
    float* __restrict__ s, float* __restrict__ pooled,
    const int* __restrict__ flags)
{
    const int fbf = flags[0], i64 = flags[1];
    __shared__ float spw[HID * K_SLOTS], spb[K_SLOTS];
    __shared__ float hL[256 * 33];   // padded stride 33
    __shared__ float sL[256 * 9];    // padded stride 9
    __shared__ float invL[256];
    __shared__ int gL[256];
    int t = threadIdx.x;
    int n0 = blockIdx.x * 256;
    spw[t] = ldf(pw, t, fbf);
    if (t < K_SLOTS) spb[t] = ldf(pb, t, fbf);
    {
        int n = n0 + t;
        gL[t] = ldi(batch, (n < N_NODES) ? n : (N_NODES - 1), i64);
        invL[t] = (n < N_NODES) ? __builtin_amdgcn_rcpf(fmaxf((float)deg[n], 1.f)) : 0.f;
    }
    __syncthreads();
    for (int i = t; i < 256 * HID; i += 256) {
        int row = i >> 5, col = i & 31;
        int n = n0 + row;
        hL[row * 33 + col] = (n < N_NODES) ? hsum[(size_t)n0 * HID + i] * invL[row] : 0.f;
    }
    __syncthreads();

    // softmax per node
    if (n0 + t < N_NODES) {
        float l[K_SLOTS];
#pragma unroll
        for (int k = 0; k < K_SLOTS; k++) l[k] = spb[k];
#pragma unroll
        for (int j = 0; j < HID; j++) {
            float v = hL[t * 33 + j];
#pragma unroll
            for (int k = 0; k < K_SLOTS; k++) l[k] = fmaf(v, spw[j * K_SLOTS + k], l[k]);
        }
        float mx = l[0];
#pragma unroll
        for (int k = 1; k < K_SLOTS; k++) mx = fmaxf(mx, l[k]);
        float sum = 0.f;
#pragma unroll
        for (int k = 0; k < K_SLOTS; k++) { l[k] = __expf(l[k] - mx); sum += l[k]; }
        float is = __builtin_amdgcn_rcpf(sum);
#pragma unroll
        for (int k = 0; k < K_SLOTS; k++) { l[k] *= is; sL[t * 9 + k] = l[k]; }
        float4 v0 = make_float4(l[0], l[1], l[2], l[3]);
        float4 v1 = make_float4(l[4], l[5], l[6], l[7]);
        float4* sp = (float4*)(s + (size_t)(n0 + t) * K_SLOTS);
        sp[0] = v0; sp[1] = v1;
    } else {
#pragma unroll
        for (int k = 0; k < K_SLOTS; k++) sL[t * 9 + k] = 0.f;
    }
    __syncthreads();

    // pooling: thread t owns (k,c)
    int k = t >> 5, c = t & 31;
    float acc = 0.f;
    int curg = gL[0];
    int lim = min(256, N_NODES - n0);
    for (int i = 0; i < lim; i++) {
        int g = gL[i];
        if (g != curg) {
            atomicAdd(&pooled[curg * 256 + t], acc);
            acc = 0.f;
            curg = g;
        }
        acc = fmaf(sL[i * 9 + k], hL[i * 33 + c], acc);
    }
    atomicAdd(&pooled[curg * 256 + t], acc);
}

// ---------------- decode (with fused z) ----------------
__global__ __launch_bounds__(256) void decode_kernel(
    const float* __restrict__ s, const float* __restrict__ pooled,
    const void* __restrict__ tw, const void* __restrict__ tb,
    const void* __restrict__ dw1, const void* __restrict__ db1,
    const void* __restrict__ dw2, const void* __restrict__ db2,
    void* __restrict__ out, const int* __restrict__ flags)
{
    const int fbf = flags[0];
    __shared__ float zb[K_SLOTS * LATENT];
    __shared__ float w1[LATENT * HID], b1s[HID], w2[HID * LATENT], b2s[LATENT];
    int b = blockIdx.y;
    int t = threadIdx.x;
    if (t < K_SLOTS * LATENT) {        // z = pooled @ toz_w + toz_b (inline)
        int k = t >> 2, d = t & 3;
        float acc = ldf(tb, d, fbf);
        for (int c = 0; c < HID; c++)
            acc = fmaf(pooled[b * 256 + k * 32 + c], ldf(tw, c * 4 + d, fbf), acc);
        zb[t] = acc;
    }
    if (t < LATENT * HID) w1[t] = ldf(dw1, t, fbf);
    else if (t < LATENT * HID + HID * LATENT) w2[t - LATENT * HID] = ldf(dw2, t - LATENT * HID, fbf);
    if (t < HID) b1s[t] = ldf(db1, t, fbf);
    if (t < LATENT) b2s[t] = ldf(db2, t, fbf);
    __syncthreads();

    int n = blockIdx.x * 256 + t;
    if (n >= N_NODES) return;
    float sv[K_SLOTS];
#pragma unroll
    for (int k = 0; k < K_SLOTS; k++) sv[k] = s[(size_t)n * K_SLOTS + k];
    float q[LATENT];
#pragma unroll
    for (int d = 0; d < LATENT; d++) {
        float a = 0.f;
#pragma unroll
        for (int k = 0; k < K_SLOTS; k++) a = fmaf(sv[k], zb[k * LATENT + d], a);
        q[d] = a;
    }
    float t1[HID];
#pragma unroll
    for (int j = 0; j < HID; j++) t1[j] = b1s[j];
#pragma unroll
    for (int d = 0; d < LATENT; d++) {
        float v = q[d];
#pragma unroll
        for (int j = 0; j < HID; j++) t1[j] = fmaf(v, w1[d * HID + j], t1[j]);
    }
#pragma unroll
    for (int j = 0; j < HID; j++) t1[j] = fast_silu(t1[j]);
    float o[LATENT];
#pragma unroll
    for (int d = 0; d < LATENT; d++) o[d] = b2s[d];
#pragma unroll
    for (int j = 0; j < HID; j++) {
        float v = t1[j];
#pragma unroll
        for (int d = 0; d < LATENT; d++) o[d] = fmaf(v, w2[j * LATENT + d], o[d]);
    }
    if (fbf) {
        union { bf16 h[4]; uint2 u; } pk;
#pragma unroll
        for (int d = 0; d < LATENT; d++) pk.h[d] = __float2bfloat16(o[d]);
        ((uint2*)out)[(size_t)b * N_NODES + n] = pk.u;
    } else {
        float4 v4 = make_float4(o[0], o[1], o[2], o[3]);
        ((float4*)out)[(size_t)b * N_NODES + n] = v4;
    }
}

extern "C" void kernel_launch(void* const* d_in, const int* in_sizes, int n_in,
                              void* d_out, int out_size, void* d_ws, size_t ws_size,
                              hipStream_t stream) {
    const void* x      = d_in[0];
    const void* pos    = d_in[1];
    const int*  ei     = (const int*)d_in[2];
    const int*  batch  = (const int*)d_in[3];
    const void* enc_w1 = d_in[4];
    const void* enc_b1 = d_in[5];
    const void* enc_w2 = d_in[6];
    const void* enc_b2 = d_in[7];
    const void* pool_w = d_in[8];
    const void* pool_b = d_in[9];
    const void* toz_w  = d_in[10];
    const void* toz_b  = d_in[11];
    const void* dec_w1 = d_in[12];
    const void* dec_b1 = d_in[13];
    const void* dec_w2 = d_in[14];
    const void* dec_b2 = d_in[15];

    float* ws = (float*)d_ws;
    float* pooled = ws + WS_POOL;
    int*   gfill  = (int*)(ws + WS_GFILL);
    float* hsum   = ws + WS_HSUM;
    float* s      = ws + WS_S;
    short* frags  = (short*)(ws + WS_FRAGS);
    int*   deg    = (int*)(ws + WS_DEG);
    unsigned* binned = (unsigned*)(ws + WS_BINNED);
    unsigned* edat   = (unsigned*)(ws + WS_EDAT);
    int*   flags  = (int*)(ws + WS_FLAGS);

    hipMemsetAsync(d_ws, 0, (size_t)WS_ZERO_CNT * 4, stream);
    prep_kernel<<<1, 64, 0, stream>>>(x, ei, enc_w1, enc_w2, flags, frags);

    int gbin = (N_EDGES + BIN_EPB - 1) / BIN_EPB;
    bin_kernel<<<gbin, 256, 0, stream>>>(ei, gfill, binned, flags);
    csr_kernel<<<NBUCKET, 1024, 0, stream>>>(gfill, binned, edat, deg, hsum);

    msg_agg_kernel<<<N_EDGES / 256, 256, 0, stream>>>(
        x, pos, edat, frags, enc_b1, enc_b2, hsum, flags);

    pool_softmax_kernel<<<NBUCKET, 256, 0, stream>>>(
        hsum, deg, batch, pool_w, pool_b, s, pooled, flags);
    dim3 dg((N_NODES + 255) / 256, N_GRAPHS);
    decode_kernel<<<dg, 256, 0, stream>>>(
        s, pooled, toz_w, toz_b, dec_w1, dec_b1, dec_w2, dec_b2, d_out, flags);
}

// Round 12
// 200.057 us; speedup vs baseline: 14.6838x; 1.0633x over previous
//
#include <hip/hip_runtime.h>
#include <hip/hip_bf16.h>

#define N_NODES 50000
#define N_EDGES 1600000
#define N_GRAPHS 16
#define K_SLOTS 8
#define LATENT 4
#define HID 32
#define NBUCKET 196      // ceil(N_NODES/256), bucket = dst>>8
#define BCAP 10240       // bucket capacity (mean 8163, sigma ~90 -> 22 sigma)
#define BIN_EPB 4096     // edges per bin block

typedef __hip_bfloat16 bf16;
typedef __attribute__((ext_vector_type(8))) short short8;
typedef __attribute__((ext_vector_type(4))) float f32x4;

// dtype-agnostic loads (flag is wave-uniform)
__device__ __forceinline__ float ldf(const void* p, long i, int isbf) {
    return isbf ? __bfloat162float(((const bf16*)p)[i]) : ((const float*)p)[i];
}
__device__ __forceinline__ int ldi(const int* p, long i, int is64) {
    return is64 ? p[2 * i] : p[i];
}
__device__ __forceinline__ short f2bs(float f) {
    bf16 h = __float2bfloat16(f);
    return *reinterpret_cast<short*>(&h);
}
__device__ __forceinline__ unsigned pk2(float a, float b) {
    __hip_bfloat162 h2 = __float22bfloat162_rn(make_float2(a, b));
    return *reinterpret_cast<unsigned*>(&h2);
}
__device__ __forceinline__ float bs2f(unsigned s) {
    union { unsigned u; float f; } cv;
    cv.u = (s & 0xFFFFu) << 16;
    return cv.f;
}
__device__ __forceinline__ float fast_silu(float v) {
    return v * __builtin_amdgcn_rcpf(1.f + __expf(-v));
}

// ---- workspace layout (4-byte elements) ----
#define WS_POOL 0                                      // 4096 (ZERO via memset)
#define WS_GFILL 4096                                  // 256 (ZERO via memset)
#define WS_ZERO_CNT 4352
#define WS_HSUM 4352                                   // N*32 f32 (zeroed by csr_kernel)
#define WS_S    (WS_HSUM + N_NODES * HID)              // N*8
#define WS_FRAGS (WS_S + N_NODES * K_SLOTS)            // 1024 dwords (2048 shorts)
#define WS_DEG  (WS_FRAGS + 1024)                      // N (fully written by csr)
#define WS_BINNED (WS_DEG + N_NODES)                   // NBUCKET*BCAP
#define WS_EDAT (WS_BINNED + NBUCKET * BCAP)           // E uints (src | dst<<16)
#define WS_FLAGS (WS_EDAT + N_EDGES)                   // 2

// ---------------- prep: lane-parallel dtype detection + weight fragment build ----------------
__global__ void prep_kernel(const void* x, const int* ei,
                            const void* w1, const void* w2,
                            int* flags, short* frags)
{
    int t = threadIdx.x;   // 64
    unsigned short h = ((const unsigned short*)x)[2 * t];
    unsigned e = (h >> 7) & 0xFF;
    bool sane = ((h & 0x7FFF) == 0 || (e >= 100 && e <= 141));
    unsigned long long bs = __ballot(sane);
    int f0 = (__popcll(bs) >= 32) ? 1 : 0;     // 1: floats are bf16
    bool z = (ei[2 * t + 1] == 0);
    unsigned long long bz = __ballot(z);
    int f1 = (__popcll(bz) >= 60) ? 1 : 0;     // 1: ints are int64
    if (t == 0) { flags[0] = f0; flags[1] = f1; }

    int fbf = f0;
    int nl = t & 15, quad = (t >> 4) & 3;
#pragma unroll
    for (int j = 0; j < 8; j++) {
        int k = quad * 8 + j;
        frags[(0 * 64 + t) * 8 + j] = (k < 9) ? f2bs(ldf(w1, k * 32 + nl, fbf)) : (short)0;
        frags[(1 * 64 + t) * 8 + j] = (k < 9) ? f2bs(ldf(w1, k * 32 + 16 + nl, fbf)) : (short)0;
        frags[(2 * 64 + t) * 8 + j] = f2bs(ldf(w2, k * 32 + nl, fbf));
        frags[(3 * 64 + t) * 8 + j] = f2bs(ldf(w2, k * 32 + 16 + nl, fbf));
    }
}

// ---------------- pass 1: bin edges by dst>>8, block-local sort, shfl scan ----------------
__global__ __launch_bounds__(256) void bin_kernel(
    const int* __restrict__ ei, int* __restrict__ gfill,
    unsigned* __restrict__ binned, const int* __restrict__ flags)
{
    const int i64 = flags[1];
    __shared__ int cnt[NBUCKET];
    __shared__ int lbase[NBUCKET];
    __shared__ int lcur[NBUCKET];
    __shared__ int gbase[NBUCKET];
    __shared__ int wsum[4];
    __shared__ unsigned sorted[BIN_EPB];   // 16 KB
    int t = threadIdx.x;
    for (int i = t; i < NBUCKET; i += 256) cnt[i] = 0;
    __syncthreads();

    long e0 = (long)blockIdx.x * BIN_EPB;
    unsigned pk[16];
    if (!i64) {
#pragma unroll
        for (int kk = 0; kk < 4; kk++) {
            long e = e0 + kk * 1024 + t * 4;
            if (e < N_EDGES) {
                int4 sv = *(const int4*)(ei + e);
                int4 dv = *(const int4*)(ei + N_EDGES + e);
                pk[kk * 4 + 0] = (unsigned)sv.x | ((unsigned)dv.x << 16);
                pk[kk * 4 + 1] = (unsigned)sv.y | ((unsigned)dv.y << 16);
                pk[kk * 4 + 2] = (unsigned)sv.z | ((unsigned)dv.z << 16);
                pk[kk * 4 + 3] = (unsigned)sv.w | ((unsigned)dv.w << 16);
                atomicAdd(&cnt[dv.x >> 8], 1);
                atomicAdd(&cnt[dv.y >> 8], 1);
                atomicAdd(&cnt[dv.z >> 8], 1);
                atomicAdd(&cnt[dv.w >> 8], 1);
            } else {
                pk[kk * 4 + 0] = pk[kk * 4 + 1] = pk[kk * 4 + 2] = pk[kk * 4 + 3] = 0xFFFFFFFFu;
            }
        }
    } else {
#pragma unroll
        for (int kk = 0; kk < 8; kk++) {
            long e = e0 + kk * 512 + t * 2;
            if (e < N_EDGES) {
                int4 sv = *(const int4*)(ei + 2 * e);
                int4 dv = *(const int4*)(ei + 2 * (N_EDGES + e));
                pk[kk * 2 + 0] = (unsigned)sv.x | ((unsigned)dv.x << 16);
                pk[kk * 2 + 1] = (unsigned)sv.z | ((unsigned)dv.z << 16);
                atomicAdd(&cnt[dv.x >> 8], 1);
                atomicAdd(&cnt[dv.z >> 8], 1);
            } else {
                pk[kk * 2 + 0] = pk[kk * 2 + 1] = 0xFFFFFFFFu;
            }
        }
    }
    __syncthreads();

    // shfl-based inclusive scan of cnt over 256 entries
    int cv = (t < NBUCKET) ? cnt[t] : 0;
    int lane = t & 63;
    int v = cv;
#pragma unroll
    for (int d = 1; d < 64; d <<= 1) {
        int u = __shfl_up(v, d);
        if (lane >= d) v += u;
    }
    if (lane == 63) wsum[t >> 6] = v;
    __syncthreads();
    int add = 0;
    for (int q = 0; q < (t >> 6); q++) add += wsum[q];
    int inc = v + add;
    int total = wsum[0] + wsum[1] + wsum[2] + wsum[3];
    if (t < NBUCKET) {
        int ex = inc - cv;
        lbase[t] = ex;
        lcur[t] = ex;
        gbase[t] = atomicAdd(&gfill[t], cv);
    }
    __syncthreads();

    // local scatter (sort by bucket)
#pragma unroll
    for (int k = 0; k < 16; k++) {
        if (pk[k] != 0xFFFFFFFFu) {
            int b = pk[k] >> 24;
            int p = atomicAdd(&lcur[b], 1);
            sorted[p] = pk[k];
        }
    }
    __syncthreads();

    // coalesced write-out
    for (int j = t; j < total; j += 256) {
        unsigned ed = sorted[j];
        int b = ed >> 24;
        binned[(long)b * BCAP + gbase[b] + (j - lbase[b])] = ed;
    }
}

// ---------------- pass 2: per-bucket counting sort, shfl scans + hsum zero ----------------
__global__ __launch_bounds__(1024) void csr_kernel(
    const int* __restrict__ gfill, const unsigned* __restrict__ binned,
    unsigned* __restrict__ edat, int* __restrict__ deg, float* __restrict__ hsum)
{
    __shared__ int red[16];
    __shared__ int lcnt[256], lcur[256];
    int b = blockIdx.x, t = threadIdx.x;
    int lane = t & 63;
    if (t < 256) lcnt[t] = 0;

    // base = sum(gfill[0..b-1]) via shfl reduce (waves >=4 contribute 0)
    int bv = (t < 256 && t < b && t < NBUCKET) ? gfill[t] : 0;
#pragma unroll
    for (int d = 32; d > 0; d >>= 1) bv += __shfl_down(bv, d);
    if (lane == 0) red[t >> 6] = bv;
    __syncthreads();
    int base = red[0] + red[1] + red[2] + red[3];

    // zero this bucket's hsum rows (before msg_agg)
    {
        int nvalid = min(256, N_NODES - b * 256);
        if (nvalid > 0) {
            float4* hz = (float4*)(hsum + (size_t)b * 256 * HID);
            float4 z4 = make_float4(0.f, 0.f, 0.f, 0.f);
            for (int i = t; i < nvalid * 8; i += 1024) hz[i] = z4;
        }
    }
    int cnt = gfill[b];
    const unsigned* bp = binned + (long)b * BCAP;
    __syncthreads();   // lcnt zero + red reuse guard
    for (int i = t; i < cnt; i += 1024)
        atomicAdd(&lcnt[(bp[i] >> 16) & 255], 1);
    __syncthreads();

    // shfl scan of lcnt over 256 (first 4 waves meaningful)
    int cv = (t < 256) ? lcnt[t] : 0;
    int v = cv;
#pragma unroll
    for (int d = 1; d < 64; d <<= 1) {
        int u = __shfl_up(v, d);
        if (lane >= d) v += u;
    }
    if (t < 256 && lane == 63) red[t >> 6] = v;
    __syncthreads();
    if (t < 256) {
        int add = 0;
        for (int q = 0; q < (t >> 6); q++) add += red[q];
        lcur[t] = v + add - cv;
        int n = b * 256 + t;
        if (n < N_NODES) deg[n] = cv;
    }
    __syncthreads();
    for (int i = t; i < cnt; i += 1024) {
        unsigned pk = bp[i];
        int pos = base + atomicAdd(&lcur[(pk >> 16) & 255], 1);
        edat[pos] = pk;
    }
}

// ---------------- MFMA msg MLP + transposed segmented reduction ----------------
__global__ __launch_bounds__(256) void msg_agg_kernel(
    const void* __restrict__ x, const void* __restrict__ pos,
    const unsigned* __restrict__ edat, const short* __restrict__ frags,
    const void* __restrict__ b1, const void* __restrict__ b2,
    float* __restrict__ hsum, const int* __restrict__ flags)
{
    const int fbf = flags[0];
    __shared__ short buf[256 * 34];    // 17 KB: A1 (stride 34) -> A2 -> msgT (32 x stride 258)
    __shared__ int sdL[256];
    __shared__ int runstart[256];
    __shared__ int wcnt[4];

    int t = threadIdx.x;
    int lane = t & 63, wv = t >> 6;
    int nl = lane & 15, quad = lane >> 4;

    const short8 w1f0 = *(const short8*)&frags[(0 * 64 + lane) * 8];
    const short8 w1f1 = *(const short8*)&frags[(1 * 64 + lane) * 8];
    const short8 w2f0 = *(const short8*)&frags[(2 * 64 + lane) * 8];
    const short8 w2f1 = *(const short8*)&frags[(3 * 64 + lane) * 8];
    float b1c0 = ldf(b1, nl, fbf), b1c1 = ldf(b1, 16 + nl, fbf);
    float b2c0 = ldf(b2, nl, fbf), b2c1 = ldf(b2, 16 + nl, fbf);

    long i = (long)blockIdx.x * 256 + t;
    unsigned ed = edat[i];
    int src = (int)(ed & 0xFFFFu);
    int dst = (int)(ed >> 16);
    sdL[t] = dst;

    float in[9];
    if (fbf) {
        const unsigned* xb = (const unsigned*)x;
        unsigned d0 = xb[dst * 2], d1 = xb[dst * 2 + 1];
        unsigned s0 = xb[src * 2], s1 = xb[src * 2 + 1];
        in[0] = bs2f(d0); in[1] = bs2f(d0 >> 16);
        in[2] = bs2f(d1); in[3] = bs2f(d1 >> 16);
        in[4] = bs2f(s0); in[5] = bs2f(s0 >> 16);
        in[6] = bs2f(s1); in[7] = bs2f(s1 >> 16);
        const unsigned short* pp = (const unsigned short*)pos;
        float dx = bs2f(pp[3 * src + 0]) - bs2f(pp[3 * dst + 0]);
        float dy = bs2f(pp[3 * src + 1]) - bs2f(pp[3 * dst + 1]);
        float dz = bs2f(pp[3 * src + 2]) - bs2f(pp[3 * dst + 2]);
        in[8] = sqrtf(dx * dx + dy * dy + dz * dz);
    } else {
        float4 xd = ((const float4*)x)[dst];
        float4 xs = ((const float4*)x)[src];
        in[0] = xd.x; in[1] = xd.y; in[2] = xd.z; in[3] = xd.w;
        in[4] = xs.x; in[5] = xs.y; in[6] = xs.z; in[7] = xs.w;
        const float* pf = (const float*)pos;
        float dx = pf[3 * src + 0] - pf[3 * dst + 0];
        float dy = pf[3 * src + 1] - pf[3 * dst + 1];
        float dz = pf[3 * src + 2] - pf[3 * dst + 2];
        in[8] = sqrtf(dx * dx + dy * dy + dz * dz);
    }

    {
        unsigned* rowp = (unsigned*)&buf[t * 34];
        rowp[0] = pk2(in[0], in[1]);
        rowp[1] = pk2(in[2], in[3]);
        rowp[2] = pk2(in[4], in[5]);
        rowp[3] = pk2(in[6], in[7]);
        rowp[4] = pk2(in[8], 0.f);
#pragma unroll
        for (int p = 5; p < 16; p++) rowp[p] = 0;
    }
    __syncthreads();

    int rb = wv * 64;
    short8 af[4];
#pragma unroll
    for (int mt = 0; mt < 4; mt++) {
        int row = rb + mt * 16 + nl;
        af[mt] = *(short8*)&buf[row * 34 + quad * 8];
    }
    __syncthreads();

    f32x4 zero = {0.f, 0.f, 0.f, 0.f};
#pragma unroll
    for (int mt = 0; mt < 4; mt++) {
        f32x4 c0 = __builtin_amdgcn_mfma_f32_16x16x32_bf16(af[mt], w1f0, zero, 0, 0, 0);
        f32x4 c1 = __builtin_amdgcn_mfma_f32_16x16x32_bf16(af[mt], w1f1, zero, 0, 0, 0);
#pragma unroll
        for (int r = 0; r < 4; r++) {
            int row = rb + mt * 16 + quad * 4 + r;
            buf[row * 34 + nl] = f2bs(fast_silu(c0[r] + b1c0));
            buf[row * 34 + 16 + nl] = f2bs(fast_silu(c1[r] + b1c1));
        }
    }
    __syncthreads();

    short8 a2f[4];
#pragma unroll
    for (int mt = 0; mt < 4; mt++) {
        int row = rb + mt * 16 + nl;
        a2f[mt] = *(short8*)&buf[row * 34 + quad * 8];
    }
    __syncthreads();

    short* msgT = buf;   // 32*258 = 8256 <= 8704 shorts
#pragma unroll
    for (int mt = 0; mt < 4; mt++) {
        f32x4 d0 = __builtin_amdgcn_mfma_f32_16x16x32_bf16(a2f[mt], w2f0, zero, 0, 0, 0);
        f32x4 d1 = __builtin_amdgcn_mfma_f32_16x16x32_bf16(a2f[mt], w2f1, zero, 0, 0, 0);
        int ob = rb + mt * 16 + quad * 4;
        unsigned* c0p = (unsigned*)&msgT[nl * 258 + ob];
        unsigned* c1p = (unsigned*)&msgT[(nl + 16) * 258 + ob];
        c0p[0] = pk2(d0[0] + b2c0, d0[1] + b2c0);
        c0p[1] = pk2(d0[2] + b2c0, d0[3] + b2c0);
        c1p[0] = pk2(d1[0] + b2c1, d1[1] + b2c1);
        c1p[1] = pk2(d1[2] + b2c1, d1[3] + b2c1);
    }
    __syncthreads();

    bool head = (t == 0) || (sdL[t] != sdL[t - 1]);
    unsigned long long bal = __ballot(head);
    if (lane == 0) wcnt[wv] = __popcll(bal);
    __syncthreads();
    int nruns = wcnt[0] + wcnt[1] + wcnt[2] + wcnt[3];
    if (head) {
        int base = 0;
        for (int q = 0; q < wv; q++) base += wcnt[q];
        int myrun = base + __popcll(bal & (((unsigned long long)1 << lane) - 1ull));
        runstart[myrun] = t;
    }
    __syncthreads();

    int g = t >> 5, c = t & 31;
    const short* col = &msgT[c * 258];
    const unsigned* colu = (const unsigned*)col;
    for (int r = g; r < nruns; r += 8) {
        int s0 = runstart[r];
        int s1 = (r + 1 < nruns) ? runstart[r + 1] : 256;
        float acc = 0.f;
        int j = s0;
        if (j & 1) { acc += bs2f((unsigned)(unsigned short)col[j]); j++; }
        for (; j + 1 < s1; j += 2) {
            unsigned d = colu[j >> 1];
            acc += bs2f(d) + bs2f(d >> 16);
        }
        if (j < s1) acc += bs2f((unsigned)(unsigned short)col[j]);
        int node = sdL[s0];
        if (s0 == 0 || s1 == 256) atomicAdd(&hsum[(size_t)node * HID + c], acc);
        else hsum[(size_t)node * HID + c] = acc;
    }
}

// ---------------- fused normalize + softmax + MFMA pooling ----------------
__global__ __launch_bounds__(256) void pool_softmax_kernel(
    const float* __restrict__ hsum, const int* __restrict__ deg,
    const int* __restrict__ batch,
    const void* __restrict__ pw, const void* __restrict__ pb,
    float* __restrict__ s, float* __restrict__ pooled,
    const int* __restrict__ flags)
{
    const int fbf = flags[0], i64 = flags[1];
    __shared__ float spw[HID * K_SLOTS], spb[K_SLOTS];
    __shared__ short hT[32 * 266];     // bf16 h^T, stride 266 (odd dwords)
    __shared__ short sT[16 * 266];     // bf16 s^T rows 0..7; rows 8..15 zero
    __shared__ float invL[256];
    __shared__ int gL[256];
    __shared__ int runstart[16];
    __shared__ int wcnt[4];
    int t = threadIdx.x;
    int lane = t & 63, wv = t >> 6;
    int n0 = blockIdx.x * 256;
    spw[t] = ldf(pw, t, fbf);
    if (t < K_SLOTS) spb[t] = ldf(pb, t, fbf);
    for (int i = t; i < 8 * 266; i += 256) sT[8 * 266 + i] = 0;   // zero A rows 8..15
    {
        int n = n0 + t;
        bool valid = n < N_NODES;
        gL[t] = ldi(batch, valid ? n : (N_NODES - 1), i64);
        invL[t] = valid ? __builtin_amdgcn_rcpf(fmaxf((float)deg[n], 1.f)) : 0.f;
    }
    __syncthreads();
    // load hsum coalesced, normalize, scatter into hT (bf16)
    for (int i = t; i < 256 * HID; i += 256) {
        int node = i >> 5, c = i & 31;
        float v = ((n0 + node) < N_NODES) ? hsum[(size_t)n0 * HID + i] * invL[node] : 0.f;
        hT[c * 266 + node] = f2bs(v);
    }
    __syncthreads();

    // softmax per node (reads h from hT)
    {
        bool valid = (n0 + t) < N_NODES;
        float l[K_SLOTS];
#pragma unroll
        for (int k = 0; k < K_SLOTS; k++) l[k] = spb[k];
#pragma unroll
        for (int j = 0; j < HID; j++) {
            float v = bs2f((unsigned)(unsigned short)hT[j * 266 + t]);
#pragma unroll
            for (int k = 0; k < K_SLOTS; k++) l[k] = fmaf(v, spw[j * K_SLOTS + k], l[k]);
        }
        float mx = l[0];
#pragma unroll
        for (int k = 1; k < K_SLOTS; k++) mx = fmaxf(mx, l[k]);
        float sum = 0.f;
#pragma unroll
        for (int k = 0; k < K_SLOTS; k++) { l[k] = __expf(l[k] - mx); sum += l[k]; }
        float is = __builtin_amdgcn_rcpf(sum);
#pragma unroll
        for (int k = 0; k < K_SLOTS; k++) l[k] *= is;
        if (valid) {
            float4* sp = (float4*)(s + (size_t)(n0 + t) * K_SLOTS);
            sp[0] = make_float4(l[0], l[1], l[2], l[3]);
            sp[1] = make_float4(l[4], l[5], l[6], l[7]);
        } else {
#pragma unroll
            for (int k = 0; k < K_SLOTS; k++) l[k] = 0.f;
        }
#pragma unroll
        for (int k = 0; k < K_SLOTS; k++) sT[k * 266 + t] = f2bs(l[k]);
    }
    // segment (graph-run) detection over sorted gL
    bool head = (t == 0) || (gL[t] != gL[t - 1]);
    unsigned long long bal = __ballot(head);
    if (lane == 0) wcnt[wv] = __popcll(bal);
    __syncthreads();
    int nruns = wcnt[0] + wcnt[1] + wcnt[2] + wcnt[3];
    if (head) {
        int base = 0;
        for (int q = 0; q < wv; q++) base += wcnt[q];
        runstart[base + __popcll(bal & (((unsigned long long)1 << lane) - 1ull))] = t;
    }
    __syncthreads();

    // MFMA pooling: D[slot][c] = sum_node s[node][slot]*h[node][c]
    int nl = lane & 15, quad = lane >> 4;
    int wlo = wv * 64, whi = wlo + 64;   // this wave's node range (ksteps 2wv,2wv+1)
    f32x4 zero = {0.f, 0.f, 0.f, 0.f};
    for (int r = 0; r < nruns; r++) {
        int lo = runstart[r];
        int hi = (r + 1 < nruns) ? runstart[r + 1] : 256;
        if (whi <= lo || wlo >= hi) continue;      // wave-uniform skip
        bool partial = (lo > wlo) || (hi < whi);
        f32x4 acc0 = zero, acc1 = zero;
#pragma unroll
        for (int kk = 0; kk < 2; kk++) {
            int base = (wv * 2 + kk) * 32 + quad * 8;
            short8 a = *(short8*)&sT[nl * 266 + base];
            if (partial) {
#pragma unroll
                for (int j = 0; j < 8; j++) {
                    int nd = base + j;
                    if (nd < lo || nd >= hi) a[j] = 0;
                }
            }
            short8 b0 = *(short8*)&hT[nl * 266 + base];
            short8 b1 = *(short8*)&hT[(nl + 16) * 266 + base];
            acc0 = __builtin_amdgcn_mfma_f32_16x16x32_bf16(a, b0, acc0, 0, 0, 0);
            acc1 = __builtin_amdgcn_mfma_f32_16x16x32_bf16(a, b1, acc1, 0, 0, 0);
        }
        if (quad < 2) {                     // rows (slots) 0..7 valid
            int g = gL[lo];
#pragma unroll
            for (int rr = 0; rr < 4; rr++) {
                int k = quad * 4 + rr;
                atomicAdd(&pooled[g * 256 + k * 32 + nl], acc0[rr]);
                atomicAdd(&pooled[g * 256 + k * 32 + 16 + nl], acc1[rr]);
            }
        }
    }
}

// ---------------- decode (with fused z) ----------------
__global__ __launch_bounds__(256) void decode_kernel(
    const float* __restrict__ s, const float* __restrict__ pooled,
    const void* __restrict__ tw, const void* __restrict__ tb,
    const void* __restrict__ dw1, const void* __restrict__ db1,
    const void* __restrict__ dw2, const void* __restrict__ db2,
    void* __restrict__ out, const int* __restrict__ flags)
{
    const int fbf = flags[0];
    __shared__ float zb[K_SLOTS * LATENT];
    __shared__ float w1[LATENT * HID], b1s[HID], w2[HID * LATENT], b2s[LATENT];
    int b = blockIdx.y;
    int t = threadIdx.x;
    if (t < K_SLOTS * LATENT) {
        int k = t >> 2, d = t & 3;
        float acc = ldf(tb, d, fbf);
        for (int c = 0; c < HID; c++)
            acc = fmaf(pooled[b * 256 + k * 32 + c], ldf(tw, c * 4 + d, fbf), acc);
        zb[t] = acc;
    }
    if (t < LATENT * HID) w1[t] = ldf(dw1, t, fbf);
    else if (t < LATENT * HID + HID * LATENT) w2[t - LATENT * HID] = ldf(dw2, t - LATENT * HID, fbf);
    if (t < HID) b1s[t] = ldf(db1, t, fbf);
    if (t < LATENT) b2s[t] = ldf(db2, t, fbf);
    __syncthreads();

    int n = blockIdx.x * 256 + t;
    if (n >= N_NODES) return;
    float sv[K_SLOTS];
#pragma unroll
    for (int k = 0; k < K_SLOTS; k++) sv[k] = s[(size_t)n * K_SLOTS + k];
    float q[LATENT];
#pragma unroll
    for (int d = 0; d < LATENT; d++) {
        float a = 0.f;
#pragma unroll
        for (int k = 0; k < K_SLOTS; k++) a = fmaf(sv[k], zb[k * LATENT + d], a);
        q[d] = a;
    }
    float t1[HID];
#pragma unroll
    for (int j = 0; j < HID; j++) t1[j] = b1s[j];
#pragma unroll
    for (int d = 0; d < LATENT; d++) {
        float v = q[d];
#pragma unroll
        for (int j = 0; j < HID; j++) t1[j] = fmaf(v, w1[d * HID + j], t1[j]);
    }
#pragma unroll
    for (int j = 0; j < HID; j++) t1[j] = fast_silu(t1[j]);
    float o[LATENT];
#pragma unroll
    for (int d = 0; d < LATENT; d++) o[d] = b2s[d];
#pragma unroll
    for (int j = 0; j < HID; j++) {
        float v = t1[j];
#pragma unroll
        for (int d = 0; d < LATENT; d++) o[d] = fmaf(v, w2[j * LATENT + d], o[d]);
    }
    if (fbf) {
        union { bf16 h[4]; uint2 u; } pk;
#pragma unroll
        for (int d = 0; d < LATENT; d++) pk.h[d] = __float2bfloat16(o[d]);
        ((uint2*)out)[(size_t)b * N_NODES + n] = pk.u;
    } else {
        float4 v4 = make_float4(o[0], o[1], o[2], o[3]);
        ((float4*)out)[(size_t)b * N_NODES + n] = v4;
    }
}

extern "C" void kernel_launch(void* const* d_in, const int* in_sizes, int n_in,
                              void* d_out, int out_size, void* d_ws, size_t ws_size,
                              hipStream_t stream) {
    const void* x      = d_in[0];
    const void* pos    = d_in[1];
    const int*  ei     = (const int*)d_in[2];
    const int*  batch  = (const int*)d_in[3];
    const void* enc_w1 = d_in[4];
    const void* enc_b1 = d_in[5];
    const void* enc_w2 = d_in[6];
    const void* enc_b2 = d_in[7];
    const void* pool_w = d_in[8];
    const void* pool_b = d_in[9];
    const void* toz_w  = d_in[10];
    const void* toz_b  = d_in[11];
    const void* dec_w1 = d_in[12];
    const void* dec_b1 = d_in[13];
    const void* dec_w2 = d_in[14];
    const void* dec_b2 = d_in[15];

    float* ws = (float*)d_ws;
    float* pooled = ws + WS_POOL;
    int*   gfill  = (int*)(ws + WS_GFILL);
    float* hsum   = ws + WS_HSUM;
    float* s      = ws + WS_S;
    short* frags  = (short*)(ws + WS_FRAGS);
    int*   deg    = (int*)(ws + WS_DEG);
    unsigned* binned = (unsigned*)(ws + WS_BINNED);
    unsigned* edat   = (unsigned*)(ws + WS_EDAT);
    int*   flags  = (int*)(ws + WS_FLAGS);

    hipMemsetAsync(d_ws, 0, (size_t)WS_ZERO_CNT * 4, stream);
    prep_kernel<<<1, 64, 0, stream>>>(x, ei, enc_w1, enc_w2, flags, frags);

    int gbin = (N_EDGES + BIN_EPB - 1) / BIN_EPB;
    bin_kernel<<<gbin, 256, 0, stream>>>(ei, gfill, binned, flags);
    csr_kernel<<<NBUCKET, 1024, 0, stream>>>(gfill, binned, edat, deg, hsum);

    msg_agg_kernel<<<N_EDGES / 256, 256, 0, stream>>>(
        x, pos, edat, frags, enc_b1, enc_b2, hsum, flags);

    pool_softmax_kernel<<<NBUCKET, 256, 0, stream>>>(
        hsum, deg, batch, pool_w, pool_b, s, pooled, flags);
    dim3 dg((N_NODES + 255) / 256, N_GRAPHS);
    decode_kernel<<<dg, 256, 0, stream>>>(
        s, pooled, toz_w, toz_b, dec_w1, dec_b1, dec_w2, dec_b2, d_out, flags);
}

// Round 13
// 197.751 us; speedup vs baseline: 14.8550x; 1.0117x over previous
//
#include <hip/hip_runtime.h>
#include <hip/hip_bf16.h>

#define N_NODES 50000
#define N_EDGES 1600000
#define N_GRAPHS 16
#define K_SLOTS 8
#define LATENT 4
#define HID 32
#define NBUCKET 196      // ceil(N_NODES/256), bucket = dst>>8
#define BCAP 10240       // bucket capacity (mean 8163, sigma ~90 -> 22 sigma)
#define BIN_EPB 4096     // edges per bin block
#define EBUF_CAP 8704    // csr LDS edge cache (bucket mean 8163; overflow falls back to global)

typedef __hip_bfloat16 bf16;
typedef __attribute__((ext_vector_type(8))) short short8;
typedef __attribute__((ext_vector_type(4))) float f32x4;

__device__ __forceinline__ float ldf(const void* p, long i, int isbf) {
    return isbf ? __bfloat162float(((const bf16*)p)[i]) : ((const float*)p)[i];
}
__device__ __forceinline__ int ldi(const int* p, long i, int is64) {
    return is64 ? p[2 * i] : p[i];
}
__device__ __forceinline__ short f2bs(float f) {
    bf16 h = __float2bfloat16(f);
    return *reinterpret_cast<short*>(&h);
}
__device__ __forceinline__ unsigned pk2(float a, float b) {
    __hip_bfloat162 h2 = __float22bfloat162_rn(make_float2(a, b));
    return *reinterpret_cast<unsigned*>(&h2);
}
__device__ __forceinline__ float bs2f(unsigned s) {
    union { unsigned u; float f; } cv;
    cv.u = (s & 0xFFFFu) << 16;
    return cv.f;
}
__device__ __forceinline__ float fast_silu(float v) {
    return v * __builtin_amdgcn_rcpf(1.f + __expf(-v));
}

// ---- workspace layout (4-byte elements) ----
#define WS_POOL 0                                      // 4096 (ZERO via memset)
#define WS_GFILL 4096                                  // 256 (ZERO via memset)
#define WS_ZERO_CNT 4352
#define WS_HSUM 4352                                   // N*32 f32 (zeroed by csr_kernel)
#define WS_S    (WS_HSUM + N_NODES * HID)              // N*8
#define WS_FRAGS (WS_S + N_NODES * K_SLOTS)            // 1024 dwords (2048 shorts)
#define WS_DEG  (WS_FRAGS + 1024)                      // N (fully written by csr)
#define WS_BINNED (WS_DEG + N_NODES)                   // NBUCKET*BCAP
#define WS_EDAT (WS_BINNED + NBUCKET * BCAP)           // E uints (src | dst<<16)
#define WS_FLAGS (WS_EDAT + N_EDGES)                   // 2

// ---------------- pass 1: self-detecting bin + (block 0) frag build ----------------
__global__ __launch_bounds__(256) void bin_kernel(
    const void* __restrict__ x, const int* __restrict__ ei,
    const void* __restrict__ w1, const void* __restrict__ w2,
    int* __restrict__ gfill, unsigned* __restrict__ binned,
    int* __restrict__ flags, short* __restrict__ frags)
{
    __shared__ int cnt[NBUCKET];
    __shared__ int lbase[NBUCKET];
    __shared__ int lcur[NBUCKET];
    __shared__ int gbase[NBUCKET];
    __shared__ int wsum[4];
    __shared__ int sflags[2];
    __shared__ unsigned sorted[BIN_EPB];   // 16 KB
    int t = threadIdx.x;
    // wave-0 lane-parallel dtype detection (no dependency on a prep kernel)
    if (t < 64) {
        unsigned short h = ((const unsigned short*)x)[2 * t];
        unsigned e = (h >> 7) & 0xFF;
        bool sane = ((h & 0x7FFF) == 0 || (e >= 100 && e <= 141));
        unsigned long long bs = __ballot(sane);
        bool z = (ei[2 * t + 1] == 0);
        unsigned long long bz = __ballot(z);
        if (t == 0) {
            sflags[0] = (__popcll(bs) >= 32) ? 1 : 0;   // floats are bf16
            sflags[1] = (__popcll(bz) >= 60) ? 1 : 0;   // ints are int64
        }
    }
    for (int i = t; i < NBUCKET; i += 256) cnt[i] = 0;
    __syncthreads();
    const int i64 = sflags[1];
    if (blockIdx.x == 0 && t == 0) { flags[0] = sflags[0]; flags[1] = i64; }

    long e0 = (long)blockIdx.x * BIN_EPB;
    unsigned pk[16];
    if (!i64) {
#pragma unroll
        for (int kk = 0; kk < 4; kk++) {
            long e = e0 + kk * 1024 + t * 4;
            if (e < N_EDGES) {
                int4 sv = *(const int4*)(ei + e);
                int4 dv = *(const int4*)(ei + N_EDGES + e);
                pk[kk * 4 + 0] = (unsigned)sv.x | ((unsigned)dv.x << 16);
                pk[kk * 4 + 1] = (unsigned)sv.y | ((unsigned)dv.y << 16);
                pk[kk * 4 + 2] = (unsigned)sv.z | ((unsigned)dv.z << 16);
                pk[kk * 4 + 3] = (unsigned)sv.w | ((unsigned)dv.w << 16);
                atomicAdd(&cnt[dv.x >> 8], 1);
                atomicAdd(&cnt[dv.y >> 8], 1);
                atomicAdd(&cnt[dv.z >> 8], 1);
                atomicAdd(&cnt[dv.w >> 8], 1);
            } else {
                pk[kk * 4 + 0] = pk[kk * 4 + 1] = pk[kk * 4 + 2] = pk[kk * 4 + 3] = 0xFFFFFFFFu;
            }
        }
    } else {
#pragma unroll
        for (int kk = 0; kk < 8; kk++) {
            long e = e0 + kk * 512 + t * 2;
            if (e < N_EDGES) {
                int4 sv = *(const int4*)(ei + 2 * e);
                int4 dv = *(const int4*)(ei + 2 * (N_EDGES + e));
                pk[kk * 2 + 0] = (unsigned)sv.x | ((unsigned)dv.x << 16);
                pk[kk * 2 + 1] = (unsigned)sv.z | ((unsigned)dv.z << 16);
                atomicAdd(&cnt[dv.x >> 8], 1);
                atomicAdd(&cnt[dv.z >> 8], 1);
            } else {
                pk[kk * 2 + 0] = pk[kk * 2 + 1] = 0xFFFFFFFFu;
            }
        }
    }
    __syncthreads();

    // shfl-based inclusive scan of cnt over 256 entries
    int cv = (t < NBUCKET) ? cnt[t] : 0;
    int lane = t & 63;
    int v = cv;
#pragma unroll
    for (int d = 1; d < 64; d <<= 1) {
        int u = __shfl_up(v, d);
        if (lane >= d) v += u;
    }
    if (lane == 63) wsum[t >> 6] = v;
    __syncthreads();
    int add = 0;
    for (int q = 0; q < (t >> 6); q++) add += wsum[q];
    int inc = v + add;
    int total = wsum[0] + wsum[1] + wsum[2] + wsum[3];
    if (t < NBUCKET) {
        int ex = inc - cv;
        lbase[t] = ex;
        lcur[t] = ex;
        gbase[t] = atomicAdd(&gfill[t], cv);
    }
    __syncthreads();

#pragma unroll
    for (int k = 0; k < 16; k++) {
        if (pk[k] != 0xFFFFFFFFu) {
            int b = pk[k] >> 24;
            int p = atomicAdd(&lcur[b], 1);
            sorted[p] = pk[k];
        }
    }
    __syncthreads();

    for (int j = t; j < total; j += 256) {
        unsigned ed = sorted[j];
        int b = ed >> 24;
        binned[(long)b * BCAP + gbase[b] + (j - lbase[b])] = ed;
    }

    // block 0, wave 0: build MFMA weight B-fragments (consumed 2 kernels later)
    if (blockIdx.x == 0 && t < 64) {
        int fbf = sflags[0];
        int nl = t & 15, quad = (t >> 4) & 3;
#pragma unroll
        for (int j = 0; j < 8; j++) {
            int k = quad * 8 + j;
            frags[(0 * 64 + t) * 8 + j] = (k < 9) ? f2bs(ldf(w1, k * 32 + nl, fbf)) : (short)0;
            frags[(1 * 64 + t) * 8 + j] = (k < 9) ? f2bs(ldf(w1, k * 32 + 16 + nl, fbf)) : (short)0;
            frags[(2 * 64 + t) * 8 + j] = f2bs(ldf(w2, k * 32 + nl, fbf));
            frags[(3 * 64 + t) * 8 + j] = f2bs(ldf(w2, k * 32 + 16 + nl, fbf));
        }
    }
}

// ---------------- pass 2: per-bucket counting sort, single global pass + LDS cache ----------------
__global__ __launch_bounds__(1024) void csr_kernel(
    const int* __restrict__ gfill, const unsigned* __restrict__ binned,
    unsigned* __restrict__ edat, int* __restrict__ deg, float* __restrict__ hsum)
{
    __shared__ unsigned ebuf[EBUF_CAP];   // 34 KB bucket cache
    __shared__ int red[16];
    __shared__ int lcnt[256], lcur[256];
    int b = blockIdx.x, t = threadIdx.x;
    int lane = t & 63;
    if (t < 256) lcnt[t] = 0;

    // base = sum(gfill[0..b-1]) via shfl reduce
    int bv = (t < 256 && t < b && t < NBUCKET) ? gfill[t] : 0;
#pragma unroll
    for (int d = 32; d > 0; d >>= 1) bv += __shfl_down(bv, d);
    if (lane == 0) red[t >> 6] = bv;
    __syncthreads();
    int base = red[0] + red[1] + red[2] + red[3];

    // zero this bucket's hsum rows (before msg_agg)
    {
        int nvalid = min(256, N_NODES - b * 256);
        if (nvalid > 0) {
            float4* hz = (float4*)(hsum + (size_t)b * 256 * HID);
            float4 z4 = make_float4(0.f, 0.f, 0.f, 0.f);
            for (int i = t; i < nvalid * 8; i += 1024) hz[i] = z4;
        }
    }
    int cnt = gfill[b];
    const unsigned* bp = binned + (long)b * BCAP;
    __syncthreads();   // lcnt zero + red reuse guard
    for (int i = t; i < cnt; i += 1024) {
        unsigned v = bp[i];
        if (i < EBUF_CAP) ebuf[i] = v;
        atomicAdd(&lcnt[(v >> 16) & 255], 1);
    }
    __syncthreads();

    // shfl scan of lcnt over 256
    int cv = (t < 256) ? lcnt[t] : 0;
    int v = cv;
#pragma unroll
    for (int d = 1; d < 64; d <<= 1) {
        int u = __shfl_up(v, d);
        if (lane >= d) v += u;
    }
    if (t < 256 && lane == 63) red[t >> 6] = v;
    __syncthreads();
    if (t < 256) {
        int add = 0;
        for (int q = 0; q < (t >> 6); q++) add += red[q];
        lcur[t] = v + add - cv;
        int n = b * 256 + t;
        if (n < N_NODES) deg[n] = cv;
    }
    __syncthreads();
    for (int i = t; i < cnt; i += 1024) {
        unsigned pk = (i < EBUF_CAP) ? ebuf[i] : bp[i];
        int pos = base + atomicAdd(&lcur[(pk >> 16) & 255], 1);
        edat[pos] = pk;
    }
}

// ---------------- MFMA msg MLP + transposed segmented reduction ----------------
__global__ __launch_bounds__(256) void msg_agg_kernel(
    const void* __restrict__ x, const void* __restrict__ pos,
    const unsigned* __restrict__ edat, const short* __restrict__ frags,
    const void* __restrict__ b1, const void* __restrict__ b2,
    float* __restrict__ hsum, const int* __restrict__ flags)
{
    const int fbf = flags[0];
    __shared__ short buf[256 * 34];    // 17 KB: A1 (stride 34) -> A2 -> msgT (32 x stride 258)
    __shared__ int sdL[256];
    __shared__ int runstart[256];
    __shared__ int wcnt[4];

    int t = threadIdx.x;
    int lane = t & 63, wv = t >> 6;
    int nl = lane & 15, quad = lane >> 4;

    const short8 w1f0 = *(const short8*)&frags[(0 * 64 + lane) * 8];
    const short8 w1f1 = *(const short8*)&frags[(1 * 64 + lane) * 8];
    const short8 w2f0 = *(const short8*)&frags[(2 * 64 + lane) * 8];
    const short8 w2f1 = *(const short8*)&frags[(3 * 64 + lane) * 8];
    float b1c0 = ldf(b1, nl, fbf), b1c1 = ldf(b1, 16 + nl, fbf);
    float b2c0 = ldf(b2, nl, fbf), b2c1 = ldf(b2, 16 + nl, fbf);

    long i = (long)blockIdx.x * 256 + t;
    unsigned ed = edat[i];
    int src = (int)(ed & 0xFFFFu);
    int dst = (int)(ed >> 16);
    sdL[t] = dst;

    float in[9];
    if (fbf) {
        const unsigned* xb = (const unsigned*)x;
        unsigned d0 = xb[dst * 2], d1 = xb[dst * 2 + 1];
        unsigned s0 = xb[src * 2], s1 = xb[src * 2 + 1];
        in[0] = bs2f(d0); in[1] = bs2f(d0 >> 16);
        in[2] = bs2f(d1); in[3] = bs2f(d1 >> 16);
        in[4] = bs2f(s0); in[5] = bs2f(s0 >> 16);
        in[6] = bs2f(s1); in[7] = bs2f(s1 >> 16);
        const unsigned short* pp = (const unsigned short*)pos;
        float dx = bs2f(pp[3 * src + 0]) - bs2f(pp[3 * dst + 0]);
        float dy = bs2f(pp[3 * src + 1]) - bs2f(pp[3 * dst + 1]);
        float dz = bs2f(pp[3 * src + 2]) - bs2f(pp[3 * dst + 2]);
        in[8] = sqrtf(dx * dx + dy * dy + dz * dz);
    } else {
        float4 xd = ((const float4*)x)[dst];
        float4 xs = ((const float4*)x)[src];
        in[0] = xd.x; in[1] = xd.y; in[2] = xd.z; in[3] = xd.w;
        in[4] = xs.x; in[5] = xs.y; in[6] = xs.z; in[7] = xs.w;
        const float* pf = (const float*)pos;
        float dx = pf[3 * src + 0] - pf[3 * dst + 0];
        float dy = pf[3 * src + 1] - pf[3 * dst + 1];
        float dz = pf[3 * src + 2] - pf[3 * dst + 2];
        in[8] = sqrtf(dx * dx + dy * dy + dz * dz);
    }

    {
        unsigned* rowp = (unsigned*)&buf[t * 34];
        rowp[0] = pk2(in[0], in[1]);
        rowp[1] = pk2(in[2], in[3]);
        rowp[2] = pk2(in[4], in[5]);
        rowp[3] = pk2(in[6], in[7]);
        rowp[4] = pk2(in[8], 0.f);
#pragma unroll
        for (int p = 5; p < 16; p++) rowp[p] = 0;
    }
    __syncthreads();

    int rb = wv * 64;
    short8 af[4];
#pragma unroll
    for (int mt = 0; mt < 4; mt++) {
        int row = rb + mt * 16 + nl;
        af[mt] = *(short8*)&buf[row * 34 + quad * 8];
    }
    __syncthreads();

    f32x4 zero = {0.f, 0.f, 0.f, 0.f};
#pragma unroll
    for (int mt = 0; mt < 4; mt++) {
        f32x4 c0 = __builtin_amdgcn_mfma_f32_16x16x32_bf16(af[mt], w1f0, zero, 0, 0, 0);
        f32x4 c1 = __builtin_amdgcn_mfma_f32_16x16x32_bf16(af[mt], w1f1, zero, 0, 0, 0);
#pragma unroll
        for (int r = 0; r < 4; r++) {
            int row = rb + mt * 16 + quad * 4 + r;
            buf[row * 34 + nl] = f2bs(fast_silu(c0[r] + b1c0));
            buf[row * 34 + 16 + nl] = f2bs(fast_silu(c1[r] + b1c1));
        }
    }
    __syncthreads();

    short8 a2f[4];
#pragma unroll
    for (int mt = 0; mt < 4; mt++) {
        int row = rb + mt * 16 + nl;
        a2f[mt] = *(short8*)&buf[row * 34 + quad * 8];
    }
    __syncthreads();

    short* msgT = buf;   // 32*258 = 8256 <= 8704 shorts
#pragma unroll
    for (int mt = 0; mt < 4; mt++) {
        f32x4 d0 = __builtin_amdgcn_mfma_f32_16x16x32_bf16(a2f[mt], w2f0, zero, 0, 0, 0);
        f32x4 d1 = __builtin_amdgcn_mfma_f32_16x16x32_bf16(a2f[mt], w2f1, zero, 0, 0, 0);
        int ob = rb + mt * 16 + quad * 4;
        unsigned* c0p = (unsigned*)&msgT[nl * 258 + ob];
        unsigned* c1p = (unsigned*)&msgT[(nl + 16) * 258 + ob];
        c0p[0] = pk2(d0[0] + b2c0, d0[1] + b2c0);
        c0p[1] = pk2(d0[2] + b2c0, d0[3] + b2c0);
        c1p[0] = pk2(d1[0] + b2c1, d1[1] + b2c1);
        c1p[1] = pk2(d1[2] + b2c1, d1[3] + b2c1);
    }
    __syncthreads();

    bool head = (t == 0) || (sdL[t] != sdL[t - 1]);
    unsigned long long bal = __ballot(head);
    if (lane == 0) wcnt[wv] = __popcll(bal);
    __syncthreads();
    int nruns = wcnt[0] + wcnt[1] + wcnt[2] + wcnt[3];
    if (head) {
        int base = 0;
        for (int q = 0; q < wv; q++) base += wcnt[q];
        int myrun = base + __popcll(bal & (((unsigned long long)1 << lane) - 1ull));
        runstart[myrun] = t;
    }
    __syncthreads();

    int g = t >> 5, c = t & 31;
    const short* col = &msgT[c * 258];
    const unsigned* colu = (const unsigned*)col;
    for (int r = g; r < nruns; r += 8) {
        int s0 = runstart[r];
        int s1 = (r + 1 < nruns) ? runstart[r + 1] : 256;
        float acc = 0.f;
        int j = s0;
        if (j & 1) { acc += bs2f((unsigned)(unsigned short)col[j]); j++; }
        for (; j + 1 < s1; j += 2) {
            unsigned d = colu[j >> 1];
            acc += bs2f(d) + bs2f(d >> 16);
        }
        if (j < s1) acc += bs2f((unsigned)(unsigned short)col[j]);
        int node = sdL[s0];
        if (s0 == 0 || s1 == 256) atomicAdd(&hsum[(size_t)node * HID + c], acc);
        else hsum[(size_t)node * HID + c] = acc;
    }
}

// ---------------- fused normalize + softmax + MFMA pooling ----------------
__global__ __launch_bounds__(256) void pool_softmax_kernel(
    const float* __restrict__ hsum, const int* __restrict__ deg,
    const int* __restrict__ batch,
    const void* __restrict__ pw, const void* __restrict__ pb,
    float* __restrict__ s, float* __restrict__ pooled,
    const int* __restrict__ flags)
{
    const int fbf = flags[0], i64 = flags[1];
    __shared__ float spw[HID * K_SLOTS], spb[K_SLOTS];
    __shared__ short hT[32 * 266];
    __shared__ short sT[16 * 266];
    __shared__ float invL[256];
    __shared__ int gL[256];
    __shared__ int runstart[16];
    __shared__ int wcnt[4];
    int t = threadIdx.x;
    int lane = t & 63, wv = t >> 6;
    int n0 = blockIdx.x * 256;
    spw[t] = ldf(pw, t, fbf);
    if (t < K_SLOTS) spb[t] = ldf(pb, t, fbf);
    for (int i = t; i < 8 * 266; i += 256) sT[8 * 266 + i] = 0;
    {
        int n = n0 + t;
        bool valid = n < N_NODES;
        gL[t] = ldi(batch, valid ? n : (N_NODES - 1), i64);
        invL[t] = valid ? __builtin_amdgcn_rcpf(fmaxf((float)deg[n], 1.f)) : 0.f;
    }
    __syncthreads();
    for (int i = t; i < 256 * HID; i += 256) {
        int node = i >> 5, c = i & 31;
        float v = ((n0 + node) < N_NODES) ? hsum[(size_t)n0 * HID + i] * invL[node] : 0.f;
        hT[c * 266 + node] = f2bs(v);
    }
    __syncthreads();

    {
        bool valid = (n0 + t) < N_NODES;
        float l[K_SLOTS];
#pragma unroll
        for (int k = 0; k < K_SLOTS; k++) l[k] = spb[k];
#pragma unroll
        for (int j = 0; j < HID; j++) {
            float v = bs2f((unsigned)(unsigned short)hT[j * 266 + t]);
#pragma unroll
            for (int k = 0; k < K_SLOTS; k++) l[k] = fmaf(v, spw[j * K_SLOTS + k], l[k]);
        }
        float mx = l[0];
#pragma unroll
        for (int k = 1; k < K_SLOTS; k++) mx = fmaxf(mx, l[k]);
        float sum = 0.f;
#pragma unroll
        for (int k = 0; k < K_SLOTS; k++) { l[k] = __expf(l[k] - mx); sum += l[k]; }
        float is = __builtin_amdgcn_rcpf(sum);
#pragma unroll
        for (int k = 0; k < K_SLOTS; k++) l[k] *= is;
        if (valid) {
            float4* sp = (float4*)(s + (size_t)(n0 + t) * K_SLOTS);
            sp[0] = make_float4(l[0], l[1], l[2], l[3]);
            sp[1] = make_float4(l[4], l[5], l[6], l[7]);
        } else {
#pragma unroll
            for (int k = 0; k < K_SLOTS; k++) l[k] = 0.f;
        }
#pragma unroll
        for (int k = 0; k < K_SLOTS; k++) sT[k * 266 + t] = f2bs(l[k]);
    }
    bool head = (t == 0) || (gL[t] != gL[t - 1]);
    unsigned long long bal = __ballot(head);
    if (lane == 0) wcnt[wv] = __popcll(bal);
    __syncthreads();
    int nruns = wcnt[0] + wcnt[1] + wcnt[2] + wcnt[3];
    if (head) {
        int base = 0;
        for (int q = 0; q < wv; q++) base += wcnt[q];
        runstart[base + __popcll(bal & (((unsigned long long)1 << lane) - 1ull))] = t;
    }
    __syncthreads();

    int nl = lane & 15, quad = lane >> 4;
    int wlo = wv * 64, whi = wlo + 64;
    f32x4 zero = {0.f, 0.f, 0.f, 0.f};
    for (int r = 0; r < nruns; r++) {
        int lo = runstart[r];
        int hi = (r + 1 < nruns) ? runstart[r + 1] : 256;
        if (whi <= lo || wlo >= hi) continue;
        bool partial = (lo > wlo) || (hi < whi);
        f32x4 acc0 = zero, acc1 = zero;
#pragma unroll
        for (int kk = 0; kk < 2; kk++) {
            int base = (wv * 2 + kk) * 32 + quad * 8;
            short8 a = *(short8*)&sT[nl * 266 + base];
            if (partial) {
#pragma unroll
                for (int j = 0; j < 8; j++) {
                    int nd = base + j;
                    if (nd < lo || nd >= hi) a[j] = 0;
                }
            }
            short8 b0 = *(short8*)&hT[nl * 266 + base];
            short8 b1 = *(short8*)&hT[(nl + 16) * 266 + base];
            acc0 = __builtin_amdgcn_mfma_f32_16x16x32_bf16(a, b0, acc0, 0, 0, 0);
            acc1 = __builtin_amdgcn_mfma_f32_16x16x32_bf16(a, b1, acc1, 0, 0, 0);
        }
        if (quad < 2) {
            int g = gL[lo];
#pragma unroll
            for (int rr = 0; rr < 4; rr++) {
                int k = quad * 4 + rr;
                atomicAdd(&pooled[g * 256 + k * 32 + nl], acc0[rr]);
                atomicAdd(&pooled[g * 256 + k * 32 + 16 + nl], acc1[rr]);
            }
        }
    }
}

// ---------------- decode (with fused z) ----------------
__global__ __launch_bounds__(256) void decode_kernel(
    const float* __restrict__ s, const float* __restrict__ pooled,
    const void* __restrict__ tw, const void* __restrict__ tb,
    const void* __restrict__ dw1, const void* __restrict__ db1,
    const void* __restrict__ dw2, const void* __restrict__ db2,
    void* __restrict__ out, const int* __restrict__ flags)
{
    const int fbf = flags[0];
    __shared__ float zb[K_SLOTS * LATENT];
    __shared__ float w1[LATENT * HID], b1s[HID], w2[HID * LATENT], b2s[LATENT];
    int b = blockIdx.y;
    int t = threadIdx.x;
    if (t < K_SLOTS * LATENT) {
        int k = t >> 2, d = t & 3;
        float acc = ldf(tb, d, fbf);
        for (int c = 0; c < HID; c++)
            acc = fmaf(pooled[b * 256 + k * 32 + c], ldf(tw, c * 4 + d, fbf), acc);
        zb[t] = acc;
    }
    if (t < LATENT * HID) w1[t] = ldf(dw1, t, fbf);
    else if (t < LATENT * HID + HID * LATENT) w2[t - LATENT * HID] = ldf(dw2, t - LATENT * HID, fbf);
    if (t < HID) b1s[t] = ldf(db1, t, fbf);
    if (t < LATENT) b2s[t] = ldf(db2, t, fbf);
    __syncthreads();

    int n = blockIdx.x * 256 + t;
    if (n >= N_NODES) return;
    const float4* sp = (const float4*)(s + (size_t)n * K_SLOTS);
    float4 s01 = sp[0], s23 = sp[1];
    float sv[K_SLOTS] = {s01.x, s01.y, s01.z, s01.w, s23.x, s23.y, s23.z, s23.w};
    float q[LATENT];
#pragma unroll
    for (int d = 0; d < LATENT; d++) {
        float a = 0.f;
#pragma unroll
        for (int k = 0; k < K_SLOTS; k++) a = fmaf(sv[k], zb[k * LATENT + d], a);
        q[d] = a;
    }
    float t1[HID];
#pragma unroll
    for (int j = 0; j < HID; j++) t1[j] = b1s[j];
#pragma unroll
    for (int d = 0; d < LATENT; d++) {
        float v = q[d];
#pragma unroll
        for (int j = 0; j < HID; j++) t1[j] = fmaf(v, w1[d * HID + j], t1[j]);
    }
#pragma unroll
    for (int j = 0; j < HID; j++) t1[j] = fast_silu(t1[j]);
    float o[LATENT];
#pragma unroll
    for (int d = 0; d < LATENT; d++) o[d] = b2s[d];
#pragma unroll
    for (int j = 0; j < HID; j++) {
        float v = t1[j];
#pragma unroll
        for (int d = 0; d < LATENT; d++) o[d] = fmaf(v, w2[j * LATENT + d], o[d]);
    }
    if (fbf) {
        union { bf16 h[4]; uint2 u; } pk;
#pragma unroll
        for (int d = 0; d < LATENT; d++) pk.h[d] = __float2bfloat16(o[d]);
        ((uint2*)out)[(size_t)b * N_NODES + n] = pk.u;
    } else {
        float4 v4 = make_float4(o[0], o[1], o[2], o[3]);
        ((float4*)out)[(size_t)b * N_NODES + n] = v4;
    }
}

extern "C" void kernel_launch(void* const* d_in, const int* in_sizes, int n_in,
                              void* d_out, int out_size, void* d_ws, size_t ws_size,
                              hipStream_t stream) {
    const void* x      = d_in[0];
    const void* pos    = d_in[1];
    const int*  ei     = (const int*)d_in[2];
    const int*  batch  = (const int*)d_in[3];
    const void* enc_w1 = d_in[4];
    const void* enc_b1 = d_in[5];
    const void* enc_w2 = d_in[6];
    const void* enc_b2 = d_in[7];
    const void* pool_w = d_in[8];
    const void* pool_b = d_in[9];
    const void* toz_w  = d_in[10];
    const void* toz_b  = d_in[11];
    const void* dec_w1 = d_in[12];
    const void* dec_b1 = d_in[13];
    const void* dec_w2 = d_in[14];
    const void* dec_b2 = d_in[15];

    float* ws = (float*)d_ws;
    float* pooled = ws + WS_POOL;
    int*   gfill  = (int*)(ws + WS_GFILL);
    float* hsum   = ws + WS_HSUM;
    float* s      = ws + WS_S;
    short* frags  = (short*)(ws + WS_FRAGS);
    int*   deg    = (int*)(ws + WS_DEG);
    unsigned* binned = (unsigned*)(ws + WS_BINNED);
    unsigned* edat   = (unsigned*)(ws + WS_EDAT);
    int*   flags  = (int*)(ws + WS_FLAGS);

    hipMemsetAsync(d_ws, 0, (size_t)WS_ZERO_CNT * 4, stream);

    int gbin = (N_EDGES + BIN_EPB - 1) / BIN_EPB;
    bin_kernel<<<gbin, 256, 0, stream>>>(x, ei, enc_w1, enc_w2, gfill, binned, flags, frags);
    csr_kernel<<<NBUCKET, 1024, 0, stream>>>(gfill, binned, edat, deg, hsum);

    msg_agg_kernel<<<N_EDGES / 256, 256, 0, stream>>>(
        x, pos, edat, frags, enc_b1, enc_b2, hsum, flags);

    pool_softmax_kernel<<<NBUCKET, 256, 0, stream>>>(
        hsum, deg, batch, pool_w, pool_b, s, pooled, flags);
    dim3 dg((N_NODES + 255) / 256, N_GRAPHS);
    decode_kernel<<<dg, 256, 0, stream>>>(
        s, pooled, toz_w, toz_b, dec_w1, dec_b1, dec_w2, dec_b2, d_out, flags);
}